// Round 1
// baseline (4802.880 us; speedup 1.0000x reference)
//
#include <hip/hip_runtime.h>
#include <math.h>

// ---------------------------------------------------------------------------
// Model_24180665876772: FEDformer-style variate-token encoder on MI355X.
// Round 1: fp32 correctness baseline. Fourier block is collapsed to
// GEMMs against precomputed DFT tables (only 64 low modes survive).
// ---------------------------------------------------------------------------

#define TM 64
#define TN 64
#define TK 16

enum { EPI_NONE = 0, EPI_BIAS_COL, EPI_BIAS_ROW, EPI_BIAS_COL_RES, EPI_GELU, EPI_RES, EPI_TRANS_ADD };

__device__ __forceinline__ float gelu_exact(float v) {
    return 0.5f * v * (1.0f + erff(v * 0.70710678118654752f));
}

// Generic tiled fp32 GEMM. C[m,n] = sum_k A(m,k)*B(k,n) (+ epilogue)
// TA: A stored [K,M] (A(m,k)=A[k*lda+m]); TB: B stored [N,K] (B(k,n)=B[n*ldb+k])
template<bool TA, bool TB, int EPI>
__global__ __launch_bounds__(256)
void gemm_k(const float* __restrict__ A, const float* __restrict__ B,
            const float* __restrict__ bias, const float* __restrict__ Res,
            float* __restrict__ C,
            int M, int N, int K,
            int lda, int ldb, int ldc, int ldres,
            long sA, long sB, long sC, long sRes)
{
    const int bz = blockIdx.z;
    A += (long)bz * sA;
    B += (long)bz * sB;
    C += (long)bz * sC;
    const float* R = Res ? Res + (long)bz * sRes : nullptr;
    const int m0 = blockIdx.y * TM, n0 = blockIdx.x * TN;

    __shared__ float As[TK][TM + 1];
    __shared__ float Bs[TK][TN + 1];

    const int tid = threadIdx.x;
    const int tx = tid & 15, ty = tid >> 4;
    float acc[4][4] = {};

    for (int k0 = 0; k0 < K; k0 += TK) {
        if (!TA) {
            // A[m,k] row-major: thread reads 4 consecutive k
            int ml = tid >> 2, kl = (tid & 3) << 2;
            int gm = m0 + ml;
            const float* p = A + (long)gm * lda + (k0 + kl);
            float x0 = 0.f, x1 = 0.f, x2 = 0.f, x3 = 0.f;
            if (gm < M) { x0 = p[0]; x1 = p[1]; x2 = p[2]; x3 = p[3]; }
            As[kl + 0][ml] = x0; As[kl + 1][ml] = x1;
            As[kl + 2][ml] = x2; As[kl + 3][ml] = x3;
        } else {
            // A[k,m]: thread reads 4 consecutive m
            int kl = tid >> 4, ml = (tid & 15) << 2;
            int gm = m0 + ml;
            const float* p = A + (long)(k0 + kl) * lda + gm;
            As[kl][ml + 0] = (gm + 0 < M) ? p[0] : 0.f;
            As[kl][ml + 1] = (gm + 1 < M) ? p[1] : 0.f;
            As[kl][ml + 2] = (gm + 2 < M) ? p[2] : 0.f;
            As[kl][ml + 3] = (gm + 3 < M) ? p[3] : 0.f;
        }
        if (!TB) {
            // B[k,n]: thread reads 4 consecutive n
            int kl = tid >> 4, nl = (tid & 15) << 2;
            int gn = n0 + nl;
            const float* p = B + (long)(k0 + kl) * ldb + gn;
            Bs[kl][nl + 0] = (gn + 0 < N) ? p[0] : 0.f;
            Bs[kl][nl + 1] = (gn + 1 < N) ? p[1] : 0.f;
            Bs[kl][nl + 2] = (gn + 2 < N) ? p[2] : 0.f;
            Bs[kl][nl + 3] = (gn + 3 < N) ? p[3] : 0.f;
        } else {
            // B[n,k]: thread reads 4 consecutive k
            int nl = tid >> 2, kl = (tid & 3) << 2;
            int gn = n0 + nl;
            const float* p = B + (long)gn * ldb + (k0 + kl);
            float x0 = 0.f, x1 = 0.f, x2 = 0.f, x3 = 0.f;
            if (gn < N) { x0 = p[0]; x1 = p[1]; x2 = p[2]; x3 = p[3]; }
            Bs[kl + 0][nl] = x0; Bs[kl + 1][nl] = x1;
            Bs[kl + 2][nl] = x2; Bs[kl + 3][nl] = x3;
        }
        __syncthreads();
        #pragma unroll
        for (int kk = 0; kk < TK; ++kk) {
            float a[4], b[4];
            #pragma unroll
            for (int i = 0; i < 4; ++i) a[i] = As[kk][ty * 4 + i];
            #pragma unroll
            for (int j = 0; j < 4; ++j) b[j] = Bs[kk][tx * 4 + j];
            #pragma unroll
            for (int i = 0; i < 4; ++i)
                #pragma unroll
                for (int j = 0; j < 4; ++j)
                    acc[i][j] = fmaf(a[i], b[j], acc[i][j]);
        }
        __syncthreads();
    }

    #pragma unroll
    for (int i = 0; i < 4; ++i) {
        int gm = m0 + ty * 4 + i;
        if (gm >= M) continue;
        #pragma unroll
        for (int j = 0; j < 4; ++j) {
            int gn = n0 + tx * 4 + j;
            if (gn >= N) continue;
            float v = acc[i][j];
            if (EPI == EPI_BIAS_COL)      v += bias[gn];
            else if (EPI == EPI_BIAS_ROW) v += bias[gm];
            else if (EPI == EPI_BIAS_COL_RES) v += bias[gn] + R[(long)gm * ldres + gn];
            else if (EPI == EPI_GELU)     v = gelu_exact(v);
            else if (EPI == EPI_RES)      v += R[(long)gm * ldres + gn];
            if (EPI == EPI_TRANS_ADD) {
                // head: out[b, p=gn, t] += v + b_head[p]; gm = b*512 + t
                v += bias[gn];
                int bb = gm >> 9, t = gm & 511;
                C[(long)bb * (96 * 512) + (long)gn * 512 + t] += v;
            } else {
                C[(long)gm * ldc + gn] = v;
            }
        }
    }
}

// series_decomp: moving average (k=25, edge-replicated) over axis 1 of [B,512,512].
// S = X - mean; optionally Tr = mean.
__global__ __launch_bounds__(256)
void decomp_k(const float* __restrict__ X, float* __restrict__ S,
              float* __restrict__ Tr, int total)
{
    int idx = blockIdx.x * 256 + threadIdx.x;
    if (idx >= total) return;
    int c = idx & 511;
    int r = (idx >> 9) & 511;
    long base = ((long)(idx >> 18)) << 18;   // b * 262144
    float s = 0.f;
    #pragma unroll
    for (int j = -12; j <= 12; ++j) {
        int rr = r + j;
        rr = rr < 0 ? 0 : (rr > 511 ? 511 : rr);
        s += X[base + ((long)rr << 9) + c];
    }
    float mean = s * (1.f / 25.f);
    S[idx] = X[idx] - mean;
    if (Tr) Tr[idx] = mean;
}

// DFT tables. TF: [n=512][mp=128]  (mp<64: cos(2pi m n/512); mp>=64: -sin)
// TI: [mp=128][n=512] irfft coefs: row m<64: m==0 ? 1/512 : (2/512)cos;
//                                  row 64+m: m==0 ? 0 : -(2/512)sin
__global__ __launch_bounds__(256)
void init_tables_k(float* __restrict__ TF, float* __restrict__ TI)
{
    int t = blockIdx.x * 256 + threadIdx.x;   // 0..131071
    const float w = 6.283185307179586f / 512.f;
    if (t < 65536) {
        int n = t >> 7, mp = t & 127;
        int m = mp & 63;
        int ph = (m * n) & 511;
        float ang = ph * w;
        TF[t] = (mp < 64) ? cosf(ang) : -sinf(ang);
    } else {
        int u = t - 65536;
        int mp = u >> 9, n = u & 511;
        int m = mp & 63;
        int ph = (m * n) & 511;
        float ang = ph * w;
        float v;
        if (mp < 64) v = (m == 0) ? (1.f / 512.f) : (2.f / 512.f) * cosf(ang);
        else         v = (m == 0) ? 0.f : -(2.f / 512.f) * sinf(ang);
        TI[u] = v;
    }
}

// out_sel[b,(h,o),m'] = sum_i xft[b,(h,i),m'] * fw[h,i,o,m]  (complex)
// XFT/OS layout: [B, 512, 128] (cols 0..63 real, 64..127 imag)
__global__ __launch_bounds__(256)
void mode_mix_k(const float* __restrict__ XFT, const float* __restrict__ FR,
                const float* __restrict__ FI, float* __restrict__ OS)
{
    int b = blockIdx.x >> 3, h = blockIdx.x & 7;
    __shared__ float xr[64][65];
    __shared__ float xi[64][65];
    const float* xbase = XFT + ((long)b * 512 + h * 64) * 128;
    for (int t = threadIdx.x; t < 64 * 64; t += 256) {
        int i = t >> 6, m = t & 63;
        xr[i][m] = xbase[i * 128 + m];
        xi[i][m] = xbase[i * 128 + 64 + m];
    }
    __syncthreads();
    int m = threadIdx.x & 63;
    int osub = threadIdx.x >> 6;   // 0..3
    const float* frh = FR + (long)h * 64 * 64 * 64;
    const float* fih = FI + (long)h * 64 * 64 * 64;
    float* obase = OS + ((long)b * 512 + h * 64) * 128;
    for (int oo = 0; oo < 64; oo += 4) {
        int o = oo + osub;
        float ar = 0.f, ai = 0.f;
        for (int i = 0; i < 64; ++i) {
            float fr = frh[((long)i * 64 + o) * 64 + m];
            float fi = fih[((long)i * 64 + o) * 64 + m];
            float vr = xr[i][m], vi = xi[i][m];
            ar += vr * fr - vi * fi;
            ai += vr * fi + vi * fr;
        }
        obase[(long)o * 128 + m] = ar;
        obase[(long)o * 128 + 64 + m] = ai;
    }
}

// my_layernorm part 1: per-row LN over D=512. One wave per row.
__global__ __launch_bounds__(256)
void ln_rows_k(const float* __restrict__ X, const float* __restrict__ g,
               const float* __restrict__ bta, float* __restrict__ Y)
{
    int wave = threadIdx.x >> 6, lane = threadIdx.x & 63;
    long row = (long)blockIdx.x * 4 + wave;   // 16384 rows
    const float* x = X + row * 512;
    float s = 0.f, ss = 0.f;
    for (int d = lane; d < 512; d += 64) { float v = x[d]; s += v; ss += v * v; }
    #pragma unroll
    for (int o = 32; o; o >>= 1) { s += __shfl_xor(s, o); ss += __shfl_xor(ss, o); }
    float mu = s * (1.f / 512.f);
    float var = ss * (1.f / 512.f) - mu * mu;
    float inv = rsqrtf(var + 1e-5f);
    float* y = Y + row * 512;
    for (int d = lane; d < 512; d += 64)
        y[d] = (x[d] - mu) * inv * g[d] + bta[d];
}

// my_layernorm part 2: subtract per-(b,d) mean over 512 tokens, in place.
__global__ __launch_bounds__(64)
void colmean_sub_k(float* __restrict__ Y)
{
    int b = blockIdx.x, dg = blockIdx.y;
    int d = dg * 64 + threadIdx.x;
    float* p = Y + (long)b * 262144 + d;
    float s = 0.f;
    for (int t = 0; t < 512; ++t) s += p[(long)t << 9];
    float mean = s * (1.f / 512.f);
    for (int t = 0; t < 512; ++t) p[(long)t << 9] -= mean;
}

extern "C" void kernel_launch(void* const* d_in, const int* in_sizes, int n_in,
                              void* d_out, int out_size, void* d_ws, size_t ws_size,
                              hipStream_t stream)
{
    const float* x_enc   = (const float*)d_in[0];
    const float* W_trend = (const float*)d_in[4];
    const float* b_trend = (const float*)d_in[5];
    const float* W_emb   = (const float*)d_in[6];
    const float* b_emb   = (const float*)d_in[7];
    const float* Wq      = (const float*)d_in[8];
    const float* bq      = (const float*)d_in[9];
    // d_in[10..13] = Wk,bk,Wv,bv: unused by the reference (dead code)
    const float* fw_r    = (const float*)d_in[14];
    const float* fw_i    = (const float*)d_in[15];
    const float* Wo      = (const float*)d_in[16];
    const float* bo      = (const float*)d_in[17];
    const float* W1      = (const float*)d_in[18];
    const float* W2      = (const float*)d_in[19];
    const float* ln_g    = (const float*)d_in[20];
    const float* ln_b    = (const float*)d_in[21];
    const float* W_head  = (const float*)d_in[22];
    const float* b_head  = (const float*)d_in[23];
    float* out = (float*)d_out;
    float* ws  = (float*)d_ws;

    const long F = 8388608;           // 8.4M floats = one [B,512,512] buffer
    float* bufA = ws;                 // trend, then FFN gelu chunk
    float* bufB = ws + F;             // seasonal, then post-decomp x
    float* X    = ws + 2 * F;         // encoder state
    float* T1   = ws + 3 * F;         // q / xt / ffn-out / ln-out
    float* XFT  = ws + 4 * F;         // [B,512,128]
    float* OSEL = XFT + 2097152;      // [B,512,128]
    float* TFt  = OSEL + 2097152;     // [512,128]
    float* TIt  = TFt + 65536;        // [128,512]

    dim3 blk(256);

    init_tables_k<<<dim3(512), blk, 0, stream>>>(TFt, TIt);

    // series_decomp(x_enc): bufB = seasonal, bufA = trend
    decomp_k<<<dim3(32768), blk, 0, stream>>>(x_enc, bufB, bufA, 8388608);

    // trend_out -> d_out:  C[b,p,n] = sum_l W_trend[l,p]*trend[b,l,n] + b_trend[p]
    gemm_k<true, false, EPI_BIAS_ROW><<<dim3(8, 2, 32), blk, 0, stream>>>(
        W_trend, bufA, b_trend, nullptr, out,
        96, 512, 512, 96, 512, 512, 0,
        0L, 262144L, 49152L, 0L);

    // embedding: X[b,n,d] = sum_l seasonal[b,l,n]*W_emb[l,d] + b_emb[d]
    gemm_k<true, false, EPI_BIAS_COL><<<dim3(8, 8, 32), blk, 0, stream>>>(
        bufB, W_emb, b_emb, nullptr, X,
        512, 512, 512, 512, 512, 512, 0,
        262144L, 0L, 262144L, 0L);

    for (int l = 0; l < 2; ++l) {
        const float* Wq_l = Wq + (long)l * 262144;
        const float* bq_l = bq + (long)l * 512;
        const float* Wo_l = Wo + (long)l * 262144;
        const float* bo_l = bo + (long)l * 512;
        const float* W1_l = W1 + (long)l * 2048 * 512;
        const float* W2_l = W2 + (long)l * 512 * 2048;
        const float* fr_l = fw_r + (long)l * 2097152;
        const float* fi_l = fw_i + (long)l * 2097152;

        // q = X @ Wq + bq  -> T1 [B*512, 512]
        gemm_k<false, false, EPI_BIAS_COL><<<dim3(8, 256, 1), blk, 0, stream>>>(
            X, Wq_l, bq_l, nullptr, T1,
            16384, 512, 512, 512, 512, 512, 0, 0L, 0L, 0L, 0L);

        // forward DFT (64 low modes): XFT[b,c,m'] = sum_n q[b,n,c]*TF[n,m']
        gemm_k<true, false, EPI_NONE><<<dim3(2, 8, 32), blk, 0, stream>>>(
            T1, TFt, nullptr, nullptr, XFT,
            512, 128, 512, 512, 128, 128, 0,
            262144L, 0L, 65536L, 0L);

        // complex per-mode channel mixing
        mode_mix_k<<<dim3(256), blk, 0, stream>>>(XFT, fr_l, fi_l, OSEL);

        // inverse DFT: T1[b,c,n] = sum_m' OSEL[b,c,m']*TI[m',n]
        // T1 viewed [B, N, D] is exactly the (raw-reshape) attention output.
        gemm_k<false, false, EPI_NONE><<<dim3(8, 256, 1), blk, 0, stream>>>(
            OSEL, TIt, nullptr, nullptr, T1,
            16384, 512, 128, 128, 512, 512, 0, 0L, 0L, 0L, 0L);

        // X = X + (T1 @ Wo + bo)   (in-place residual epilogue)
        gemm_k<false, false, EPI_BIAS_COL_RES><<<dim3(8, 256, 1), blk, 0, stream>>>(
            T1, Wo_l, bo_l, X, X,
            16384, 512, 512, 512, 512, 512, 512, 0L, 0L, 0L, 0L);

        // decomp over tokens -> bufB
        decomp_k<<<dim3(32768), blk, 0, stream>>>(X, bufB, nullptr, 8388608);

        // FFN in 4 row-chunks of 4096
        for (int rc = 0; rc < 4; ++rc) {
            const float* xin = bufB + (long)rc * 4096 * 512;
            float* yout = T1 + (long)rc * 4096 * 512;
            // g = gelu(x @ W1^T)
            gemm_k<false, true, EPI_GELU><<<dim3(32, 64, 1), blk, 0, stream>>>(
                xin, W1_l, nullptr, nullptr, bufA,
                4096, 2048, 512, 512, 512, 2048, 0, 0L, 0L, 0L, 0L);
            // y = g @ W2^T + x
            gemm_k<false, true, EPI_RES><<<dim3(8, 64, 1), blk, 0, stream>>>(
                bufA, W2_l, nullptr, xin, yout,
                4096, 512, 2048, 2048, 2048, 512, 512, 0L, 0L, 0L, 0L);
        }

        // decomp -> X (next layer input)
        decomp_k<<<dim3(32768), blk, 0, stream>>>(T1, X, nullptr, 8388608);
    }

    // my_layernorm
    ln_rows_k<<<dim3(4096), blk, 0, stream>>>(X, ln_g, ln_b, T1);
    colmean_sub_k<<<dim3(32, 8), dim3(64), 0, stream>>>(T1);

    // head: out[b,p,t] += T1[b,t,:] @ W_head[:,p] + b_head[p]
    gemm_k<false, false, EPI_TRANS_ADD><<<dim3(2, 256, 1), blk, 0, stream>>>(
        T1, W_head, b_head, nullptr, out,
        16384, 96, 512, 512, 96, 0, 0, 0L, 0L, 0L, 0L);
}

// Round 2
// 1187.760 us; speedup vs baseline: 4.0436x; 4.0436x over previous
//
#include <hip/hip_runtime.h>
#include <math.h>

// ---------------------------------------------------------------------------
// Model_24180665876772  Round 2: bf16 MFMA for all large GEMMs (m97 structure:
// 128x128 tile, BK=32, global_load_lds w16, 16x16x32 bf16 MFMA).
// ---------------------------------------------------------------------------

typedef unsigned short ushort_t;
typedef unsigned int uint_t;
using bf16x8_t = __attribute__((ext_vector_type(8))) short;
using f32x4_t  = __attribute__((ext_vector_type(4))) float;
using u16x8_t  = __attribute__((ext_vector_type(8))) unsigned short;

__device__ __forceinline__ unsigned short f2b(float x) {
    union { float f; uint_t u; } c; c.f = x;
    uint_t r = c.u + 0x7fffu + ((c.u >> 16) & 1u);   // RNE
    return (unsigned short)(r >> 16);
}
__device__ __forceinline__ float b2f(unsigned short h) {
    union { uint_t u; float f; } c; c.u = ((uint_t)h) << 16; return c.f;
}
__device__ __forceinline__ float gelu_exact(float v) {
    return 0.5f * v * (1.0f + erff(v * 0.70710678118654752f));
}

#define GCAST(p) ((const __attribute__((address_space(1))) void*)(p))
#define LCAST(p) ((__attribute__((address_space(3))) void*)(p))

// ------------------------- bf16 MFMA GEMM ---------------------------------
// C[m,n] = sum_k A[m,k]*B[n,k]  (A: [M,K] row-major bf16, B: [N,K] row-major bf16)
// 128x128 tile, BK=32, 4 waves of 64x64, global_load_lds staging.
enum { ME_F32 = 0, ME_BF16, ME_BIASROW_BF16, ME_BIASCOL_F32,
       ME_BIASCOL_ACC_F32, ME_GELU_BF16, ME_RES_F32 };

template<int EPI>
__global__ __launch_bounds__(256)
void mgemm_k(const ushort_t* __restrict__ A, const ushort_t* __restrict__ B,
             const float* __restrict__ bias, const float* __restrict__ Res,
             void* __restrict__ Cv,
             int M, int N, int K, int ldc, int ldres,
             long sA, long sB, long sC, long sRes)
{
    const int bz = blockIdx.z;
    A += bz * sA;
    B += bz * sB;
    const int m0 = blockIdx.y * 128, n0 = blockIdx.x * 128;

    __shared__ __align__(16) ushort_t As[128 * 32];
    __shared__ __align__(16) ushort_t Bs[128 * 32];

    const int tid = threadIdx.x;
    const int wave = tid >> 6, lane = tid & 63;
    const int wr = wave >> 1, wc = wave & 1;

    f32x4_t acc[4][4] = {};

    const int srow = (lane >> 2);          // 0..15 within a 16-row segment
    const int skof = (lane & 3) * 8;       // 0,8,16,24 (bf16 elems)
    const int seg  = wave * 2;             // each wave stages segs {seg, seg+1}

    for (int k0 = 0; k0 < K; k0 += 32) {
        const ushort_t* ga = A + (long)(m0 + seg * 16 + srow) * K + k0 + skof;
        const ushort_t* gb = B + (long)(n0 + seg * 16 + srow) * K + k0 + skof;
        __builtin_amdgcn_global_load_lds(GCAST(ga),                 LCAST(As + seg * 512),       16, 0, 0);
        __builtin_amdgcn_global_load_lds(GCAST(ga + (long)16 * K),  LCAST(As + seg * 512 + 512), 16, 0, 0);
        __builtin_amdgcn_global_load_lds(GCAST(gb),                 LCAST(Bs + seg * 512),       16, 0, 0);
        __builtin_amdgcn_global_load_lds(GCAST(gb + (long)16 * K),  LCAST(Bs + seg * 512 + 512), 16, 0, 0);
        __syncthreads();

        const int kg = (lane >> 4) * 8;
        bf16x8_t a[4], b[4];
        #pragma unroll
        for (int i = 0; i < 4; ++i)
            a[i] = *(const bf16x8_t*)&As[(wr * 64 + i * 16 + (lane & 15)) * 32 + kg];
        #pragma unroll
        for (int j = 0; j < 4; ++j)
            b[j] = *(const bf16x8_t*)&Bs[(wc * 64 + j * 16 + (lane & 15)) * 32 + kg];
        #pragma unroll
        for (int i = 0; i < 4; ++i)
            #pragma unroll
            for (int j = 0; j < 4; ++j)
                acc[i][j] = __builtin_amdgcn_mfma_f32_16x16x32_bf16(a[i], b[j], acc[i][j], 0, 0, 0);
        __syncthreads();
    }

    float*    Cf = (float*)Cv + bz * sC;
    ushort_t* Cb = (ushort_t*)Cv + bz * sC;
    const float* R = Res ? Res + bz * sRes : nullptr;

    #pragma unroll
    for (int i = 0; i < 4; ++i) {
        #pragma unroll
        for (int j = 0; j < 4; ++j) {
            #pragma unroll
            for (int r = 0; r < 4; ++r) {
                int gm = m0 + wr * 64 + i * 16 + (lane >> 4) * 4 + r;
                int gn = n0 + wc * 64 + j * 16 + (lane & 15);
                float v = acc[i][j][r];
                long idx = (long)gm * ldc + gn;
                if (EPI == ME_F32)               Cf[idx] = v;
                else if (EPI == ME_BF16)         Cb[idx] = f2b(v);
                else if (EPI == ME_BIASROW_BF16) Cb[idx] = f2b(v + bias[gm]);
                else if (EPI == ME_BIASCOL_F32)  Cf[idx] = v + bias[gn];
                else if (EPI == ME_BIASCOL_ACC_F32) Cf[idx] += v + bias[gn];
                else if (EPI == ME_GELU_BF16)    Cb[idx] = f2b(gelu_exact(v));
                else if (EPI == ME_RES_F32)      Cf[idx] = v + R[(long)gm * ldres + gn];
            }
        }
    }
}

// ------------------------- fp32 tiled GEMM (small stuff) -------------------
#define TM 64
#define TN 64
#define TK 16
enum { EPI_NONE = 0, EPI_BIAS_COL, EPI_BIAS_ROW, EPI_BIAS_COL_RES, EPI_GELU, EPI_RES, EPI_TRANS_ADD };

template<bool TA, bool TB, int EPI>
__global__ __launch_bounds__(256)
void gemm_k(const float* __restrict__ A, const float* __restrict__ B,
            const float* __restrict__ bias, const float* __restrict__ Res,
            float* __restrict__ C,
            int M, int N, int K,
            int lda, int ldb, int ldc, int ldres,
            long sA, long sB, long sC, long sRes)
{
    const int bz = blockIdx.z;
    A += (long)bz * sA;
    B += (long)bz * sB;
    C += (long)bz * sC;
    const float* R = Res ? Res + (long)bz * sRes : nullptr;
    const int m0 = blockIdx.y * TM, n0 = blockIdx.x * TN;

    __shared__ float As[TK][TM + 1];
    __shared__ float Bs[TK][TN + 1];

    const int tid = threadIdx.x;
    const int tx = tid & 15, ty = tid >> 4;
    float acc[4][4] = {};

    for (int k0 = 0; k0 < K; k0 += TK) {
        if (!TA) {
            int ml = tid >> 2, kl = (tid & 3) << 2;
            int gm = m0 + ml;
            const float* p = A + (long)gm * lda + (k0 + kl);
            float x0 = 0.f, x1 = 0.f, x2 = 0.f, x3 = 0.f;
            if (gm < M) { x0 = p[0]; x1 = p[1]; x2 = p[2]; x3 = p[3]; }
            As[kl + 0][ml] = x0; As[kl + 1][ml] = x1;
            As[kl + 2][ml] = x2; As[kl + 3][ml] = x3;
        } else {
            int kl = tid >> 4, ml = (tid & 15) << 2;
            int gm = m0 + ml;
            const float* p = A + (long)(k0 + kl) * lda + gm;
            As[kl][ml + 0] = (gm + 0 < M) ? p[0] : 0.f;
            As[kl][ml + 1] = (gm + 1 < M) ? p[1] : 0.f;
            As[kl][ml + 2] = (gm + 2 < M) ? p[2] : 0.f;
            As[kl][ml + 3] = (gm + 3 < M) ? p[3] : 0.f;
        }
        if (!TB) {
            int kl = tid >> 4, nl = (tid & 15) << 2;
            int gn = n0 + nl;
            const float* p = B + (long)(k0 + kl) * ldb + gn;
            Bs[kl][nl + 0] = (gn + 0 < N) ? p[0] : 0.f;
            Bs[kl][nl + 1] = (gn + 1 < N) ? p[1] : 0.f;
            Bs[kl][nl + 2] = (gn + 2 < N) ? p[2] : 0.f;
            Bs[kl][nl + 3] = (gn + 3 < N) ? p[3] : 0.f;
        } else {
            int nl = tid >> 2, kl = (tid & 3) << 2;
            int gn = n0 + nl;
            const float* p = B + (long)gn * ldb + (k0 + kl);
            float x0 = 0.f, x1 = 0.f, x2 = 0.f, x3 = 0.f;
            if (gn < N) { x0 = p[0]; x1 = p[1]; x2 = p[2]; x3 = p[3]; }
            Bs[kl + 0][nl] = x0; Bs[kl + 1][nl] = x1;
            Bs[kl + 2][nl] = x2; Bs[kl + 3][nl] = x3;
        }
        __syncthreads();
        #pragma unroll
        for (int kk = 0; kk < TK; ++kk) {
            float a[4], b[4];
            #pragma unroll
            for (int i = 0; i < 4; ++i) a[i] = As[kk][ty * 4 + i];
            #pragma unroll
            for (int j = 0; j < 4; ++j) b[j] = Bs[kk][tx * 4 + j];
            #pragma unroll
            for (int i = 0; i < 4; ++i)
                #pragma unroll
                for (int j = 0; j < 4; ++j)
                    acc[i][j] = fmaf(a[i], b[j], acc[i][j]);
        }
        __syncthreads();
    }

    #pragma unroll
    for (int i = 0; i < 4; ++i) {
        int gm = m0 + ty * 4 + i;
        if (gm >= M) continue;
        #pragma unroll
        for (int j = 0; j < 4; ++j) {
            int gn = n0 + tx * 4 + j;
            if (gn >= N) continue;
            float v = acc[i][j];
            if (EPI == EPI_BIAS_COL)      v += bias[gn];
            else if (EPI == EPI_BIAS_ROW) v += bias[gm];
            else if (EPI == EPI_BIAS_COL_RES) v += bias[gn] + R[(long)gm * ldres + gn];
            else if (EPI == EPI_GELU)     v = gelu_exact(v);
            else if (EPI == EPI_RES)      v += R[(long)gm * ldres + gn];
            if (EPI == EPI_TRANS_ADD) {
                v += bias[gn];
                int bb = gm >> 9, t = gm & 511;
                C[(long)bb * (96 * 512) + (long)gn * 512 + t] += v;
            } else {
                C[(long)gm * ldc + gn] = v;
            }
        }
    }
}

// -------------------- series_decomp (25-tap moving avg) --------------------
__global__ __launch_bounds__(256)
void decomp_k(const float* __restrict__ X, float* __restrict__ S,
              float* __restrict__ Tr, int total)
{
    int idx = blockIdx.x * 256 + threadIdx.x;
    if (idx >= total) return;
    int c = idx & 511;
    int r = (idx >> 9) & 511;
    long base = ((long)(idx >> 18)) << 18;
    float s = 0.f;
    #pragma unroll
    for (int j = -12; j <= 12; ++j) {
        int rr = r + j;
        rr = rr < 0 ? 0 : (rr > 511 ? 511 : rr);
        s += X[base + ((long)rr << 9) + c];
    }
    float mean = s * (1.f / 25.f);
    S[idx] = X[idx] - mean;
    if (Tr) Tr[idx] = mean;
}

// ----------------------- bf16 DFT tables ([N,K] layouts) -------------------
// TFb [128 rows mp][512 n]:  mp<64: cos(2pi m n/512); mp>=64: -sin
// TIb [512 rows n][128 mp]:  mp<64: m==0?1/512:(2/512)cos; else m==0?0:-(2/512)sin
__global__ __launch_bounds__(256)
void init_tables_k(ushort_t* __restrict__ TFb, ushort_t* __restrict__ TIb)
{
    int t = blockIdx.x * 256 + threadIdx.x;   // 0..131071
    const float w = 6.283185307179586f / 512.f;
    if (t < 65536) {
        int mp = t >> 9, n = t & 511;
        int m = mp & 63;
        float ang = ((m * n) & 511) * w;
        TFb[t] = f2b((mp < 64) ? cosf(ang) : -sinf(ang));
    } else {
        int u = t - 65536;
        int n = u >> 7, mp = u & 127;
        int m = mp & 63;
        float ang = ((m * n) & 511) * w;
        float v;
        if (mp < 64) v = (m == 0) ? (1.f / 512.f) : (2.f / 512.f) * cosf(ang);
        else         v = (m == 0) ? 0.f : -(2.f / 512.f) * sinf(ang);
        TIb[u] = f2b(v);
    }
}

// ----------------------- fp32 -> bf16 convert ------------------------------
__global__ __launch_bounds__(256)
void f2b_k(const float* __restrict__ X, ushort_t* __restrict__ Y, long n)
{
    long i = ((long)blockIdx.x * 256 + threadIdx.x) * 8;
    if (i >= n) return;
    const float4* xp = (const float4*)(X + i);
    float4 v0 = xp[0], v1 = xp[1];
    u16x8_t o;
    o[0] = f2b(v0.x); o[1] = f2b(v0.y); o[2] = f2b(v0.z); o[3] = f2b(v0.w);
    o[4] = f2b(v1.x); o[5] = f2b(v1.y); o[6] = f2b(v1.z); o[7] = f2b(v1.w);
    *(u16x8_t*)(Y + i) = o;
}

// ----------------- fp32 [R,C] -> bf16 transposed [C,R] ---------------------
__global__ __launch_bounds__(256)
void trans_b_k(const float* __restrict__ X, ushort_t* __restrict__ Y,
               int R, int C, long sX, long sY)
{
    __shared__ float t[32][33];
    X += (long)blockIdx.z * sX;
    Y += (long)blockIdx.z * sY;
    int r0 = blockIdx.y * 32, c0 = blockIdx.x * 32;
    int tx = threadIdx.x & 31, ty = threadIdx.x >> 5;   // ty 0..7
    #pragma unroll
    for (int i = ty; i < 32; i += 8)
        t[i][tx] = X[(long)(r0 + i) * C + c0 + tx];
    __syncthreads();
    #pragma unroll
    for (int i = ty; i < 32; i += 8)
        Y[(long)(c0 + i) * R + r0 + tx] = f2b(t[tx][i]);
}

// ------------------- complex per-mode channel mixing -----------------------
// XFT [B,512,128] fp32 (cols 0..63 re, 64..127 im) -> OSELb bf16 same layout
__global__ __launch_bounds__(256)
void mode_mix_k(const float* __restrict__ XFT, const float* __restrict__ FR,
                const float* __restrict__ FI, ushort_t* __restrict__ OS)
{
    int b = blockIdx.x >> 3, h = blockIdx.x & 7;
    __shared__ float xr[64][65];
    __shared__ float xi[64][65];
    const float* xbase = XFT + ((long)b * 512 + h * 64) * 128;
    for (int t = threadIdx.x; t < 64 * 64; t += 256) {
        int i = t >> 6, m = t & 63;
        xr[i][m] = xbase[i * 128 + m];
        xi[i][m] = xbase[i * 128 + 64 + m];
    }
    __syncthreads();
    int m = threadIdx.x & 63;
    int osub = threadIdx.x >> 6;
    const float* frh = FR + (long)h * 64 * 64 * 64;
    const float* fih = FI + (long)h * 64 * 64 * 64;
    ushort_t* obase = OS + ((long)b * 512 + h * 64) * 128;
    for (int oo = 0; oo < 64; oo += 4) {
        int o = oo + osub;
        float ar = 0.f, ai = 0.f;
        for (int i = 0; i < 64; ++i) {
            float fr = frh[((long)i * 64 + o) * 64 + m];
            float fi = fih[((long)i * 64 + o) * 64 + m];
            float vr = xr[i][m], vi = xi[i][m];
            ar += vr * fr - vi * fi;
            ai += vr * fi + vi * fr;
        }
        obase[(long)o * 128 + m] = f2b(ar);
        obase[(long)o * 128 + 64 + m] = f2b(ai);
    }
}

// ------------------------------ layernorm ----------------------------------
__global__ __launch_bounds__(256)
void ln_rows_k(const float* __restrict__ X, const float* __restrict__ g,
               const float* __restrict__ bta, float* __restrict__ Y)
{
    int wave = threadIdx.x >> 6, lane = threadIdx.x & 63;
    long row = (long)blockIdx.x * 4 + wave;
    const float* x = X + row * 512;
    float s = 0.f, ss = 0.f;
    for (int d = lane; d < 512; d += 64) { float v = x[d]; s += v; ss += v * v; }
    #pragma unroll
    for (int o = 32; o; o >>= 1) { s += __shfl_xor(s, o); ss += __shfl_xor(ss, o); }
    float mu = s * (1.f / 512.f);
    float var = ss * (1.f / 512.f) - mu * mu;
    float inv = rsqrtf(var + 1e-5f);
    float* y = Y + row * 512;
    for (int d = lane; d < 512; d += 64)
        y[d] = (x[d] - mu) * inv * g[d] + bta[d];
}

__global__ __launch_bounds__(64)
void colmean_sub_k(float* __restrict__ Y)
{
    int b = blockIdx.x, dg = blockIdx.y;
    int d = dg * 64 + threadIdx.x;
    float* p = Y + (long)b * 262144 + d;
    float s = 0.f;
    for (int t = 0; t < 512; ++t) s += p[(long)t << 9];
    float mean = s * (1.f / 512.f);
    for (int t = 0; t < 512; ++t) p[(long)t << 9] -= mean;
}

// ===========================================================================
extern "C" void kernel_launch(void* const* d_in, const int* in_sizes, int n_in,
                              void* d_out, int out_size, void* d_ws, size_t ws_size,
                              hipStream_t stream)
{
    const float* x_enc   = (const float*)d_in[0];
    const float* W_trend = (const float*)d_in[4];
    const float* b_trend = (const float*)d_in[5];
    const float* W_emb   = (const float*)d_in[6];
    const float* b_emb   = (const float*)d_in[7];
    const float* Wq      = (const float*)d_in[8];
    const float* bq      = (const float*)d_in[9];
    const float* fw_r    = (const float*)d_in[14];
    const float* fw_i    = (const float*)d_in[15];
    const float* Wo      = (const float*)d_in[16];
    const float* bo      = (const float*)d_in[17];
    const float* W1      = (const float*)d_in[18];
    const float* W2      = (const float*)d_in[19];
    const float* ln_g    = (const float*)d_in[20];
    const float* ln_b    = (const float*)d_in[21];
    const float* W_head  = (const float*)d_in[22];
    const float* b_head  = (const float*)d_in[23];
    float* out = (float*)d_out;
    float* ws  = (float*)d_ws;

    const long F = 8388608;
    float* bufA = ws;                 // trend fp32; later FFN gelu chunk (bf16, 8192x2048)
    float* bufB = ws + F;             // seasonal / post-decomp x (fp32)
    float* X    = ws + 2 * F;         // encoder state fp32
    float* T1   = ws + 3 * F;         // FFN out / LN out fp32; overlays below:
    float*    XFT   = T1;                               // [B,512,128] fp32 (8MB)
    ushort_t* OSELb = (ushort_t*)(T1 + 2097152);        // [B,512,128] bf16 (4MB)
    ushort_t* xtb   = (ushort_t*)(T1 + 3145728);        // [16384,512] bf16 (16MB)
    ushort_t* qT    = (ushort_t*)(ws + 4 * F);          // [B,512,512] bf16 (16MB); also seasonalT
    ushort_t* xb    = qT + 8388608;                     // [16384,512] bf16 (16MB)
    ushort_t* WembT = (ushort_t*)(ws + 5 * F);          // [512,512]
    ushort_t* WTq   = WembT + 262144;
    ushort_t* WTo   = WTq + 262144;
    ushort_t* W1b   = WTo + 262144;                     // [2048,512]
    ushort_t* W2b   = W1b + 1048576;                    // [512,2048]
    ushort_t* TFb   = W2b + 1048576;                    // [128,512]
    ushort_t* TIb   = TFb + 65536;                      // [512,128]
    ushort_t* gb    = (ushort_t*)bufA;                  // [8192,2048] bf16 chunk

    dim3 blk(256);

    init_tables_k<<<dim3(512), blk, 0, stream>>>(TFb, TIb);

    // decomp(x_enc): bufB = seasonal, bufA = trend
    decomp_k<<<dim3(32768), blk, 0, stream>>>(x_enc, bufB, bufA, 8388608);

    // trend_out (fp32): out[b,p,n] = sum_l W_trend[l,p]*trend[b,l,n] + b_trend[p]
    gemm_k<true, false, EPI_BIAS_ROW><<<dim3(8, 2, 32), blk, 0, stream>>>(
        W_trend, bufA, b_trend, nullptr, out,
        96, 512, 512, 96, 512, 512, 0, 0L, 262144L, 49152L, 0L);

    // seasonalT bf16 [b,n,l]  (overlays qT slot)
    trans_b_k<<<dim3(16, 16, 32), blk, 0, stream>>>(bufB, qT, 512, 512, 262144L, 262144L);
    // W_embT bf16 [d,l]
    trans_b_k<<<dim3(16, 16, 1), blk, 0, stream>>>(W_emb, WembT, 512, 512, 0L, 0L);

    // X[b,n,d] = seasonalT[b,n,:] . WembT[d,:] + b_emb[d]
    mgemm_k<ME_BIASCOL_F32><<<dim3(4, 4, 32), blk, 0, stream>>>(
        qT, WembT, b_emb, nullptr, X,
        512, 512, 512, 512, 0, 262144L, 0L, 262144L, 0L);

    for (int l = 0; l < 2; ++l) {
        const float* Wq_l = Wq + (long)l * 262144;
        const float* bq_l = bq + (long)l * 512;
        const float* Wo_l = Wo + (long)l * 262144;
        const float* bo_l = bo + (long)l * 512;
        const float* W1_l = W1 + (long)l * 1048576;
        const float* W2_l = W2 + (long)l * 1048576;
        const float* fr_l = fw_r + (long)l * 2097152;
        const float* fi_l = fw_i + (long)l * 2097152;

        // weight prep
        trans_b_k<<<dim3(16, 16, 1), blk, 0, stream>>>(Wq_l, WTq, 512, 512, 0L, 0L);
        trans_b_k<<<dim3(16, 16, 1), blk, 0, stream>>>(Wo_l, WTo, 512, 512, 0L, 0L);
        f2b_k<<<dim3(512), blk, 0, stream>>>(W1_l, W1b, 1048576L);
        f2b_k<<<dim3(512), blk, 0, stream>>>(W2_l, W2b, 1048576L);
        // X -> bf16
        f2b_k<<<dim3(4096), blk, 0, stream>>>(X, xb, 8388608L);

        // qT[b,c,n] = WTq[c,:] . X[b,n,:] + bq[c]   (row bias)
        mgemm_k<ME_BIASROW_BF16><<<dim3(4, 4, 32), blk, 0, stream>>>(
            WTq, xb, bq_l, nullptr, qT,
            512, 512, 512, 512, 0, 0L, 262144L, 262144L, 0L);

        // XFT[b,c,mp] = qT[b,c,:] . TFb[mp,:]
        mgemm_k<ME_F32><<<dim3(1, 4, 32), blk, 0, stream>>>(
            qT, TFb, nullptr, nullptr, XFT,
            512, 128, 512, 128, 0, 262144L, 0L, 65536L, 0L);

        // complex mode mixing -> OSELb (bf16)
        mode_mix_k<<<dim3(256), blk, 0, stream>>>(XFT, fr_l, fi_l, OSELb);

        // xtb[(b,c),n] = OSELb[(b,c),:] . TIb[n,:]
        mgemm_k<ME_BF16><<<dim3(4, 128, 1), blk, 0, stream>>>(
            OSELb, TIb, nullptr, nullptr, xtb,
            16384, 512, 128, 512, 0, 0L, 0L, 0L, 0L);

        // X += xtb . WTo^T + bo
        mgemm_k<ME_BIASCOL_ACC_F32><<<dim3(4, 128, 1), blk, 0, stream>>>(
            xtb, WTo, bo_l, nullptr, X,
            16384, 512, 512, 512, 0, 0L, 0L, 0L, 0L);

        // decomp -> bufB
        decomp_k<<<dim3(32768), blk, 0, stream>>>(X, bufB, nullptr, 8388608);
        // bufB -> bf16
        f2b_k<<<dim3(4096), blk, 0, stream>>>(bufB, xb, 8388608L);

        // FFN in 2 chunks of M=8192
        for (int rc = 0; rc < 2; ++rc) {
            const ushort_t* xin_b = xb + (long)rc * 8192 * 512;
            const float*    xin_f = bufB + (long)rc * 8192 * 512;
            float*          yout  = T1 + (long)rc * 8192 * 512;
            // g = gelu(x @ W1^T) -> bf16
            mgemm_k<ME_GELU_BF16><<<dim3(16, 64, 1), blk, 0, stream>>>(
                xin_b, W1b, nullptr, nullptr, gb,
                8192, 2048, 512, 2048, 0, 0L, 0L, 0L, 0L);
            // y = g @ W2^T + x
            mgemm_k<ME_RES_F32><<<dim3(4, 64, 1), blk, 0, stream>>>(
                gb, W2b, nullptr, xin_f, yout,
                8192, 512, 2048, 512, 512, 0L, 0L, 0L, 0L);
        }

        // decomp -> X
        decomp_k<<<dim3(32768), blk, 0, stream>>>(T1, X, nullptr, 8388608);
    }

    // my_layernorm
    ln_rows_k<<<dim3(4096), blk, 0, stream>>>(X, ln_g, ln_b, T1);
    colmean_sub_k<<<dim3(32, 8), dim3(64), 0, stream>>>(T1);

    // head (fp32): out[b,p,t] += T1[b,t,:] @ W_head[:,p] + b_head[p]
    gemm_k<false, false, EPI_TRANS_ADD><<<dim3(2, 256, 1), blk, 0, stream>>>(
        T1, W_head, b_head, nullptr, out,
        16384, 96, 512, 512, 96, 0, 0, 0L, 0L, 0L, 0L);
}

// Round 3
// 943.140 us; speedup vs baseline: 5.0924x; 1.2594x over previous
//
#include <hip/hip_runtime.h>
#include <math.h>

// ---------------------------------------------------------------------------
// Model_24180665876772  Round 3: all-MFMA. mode_mix -> batched MFMA GEMM,
// trend/head -> MFMA, sliding-window decomp with fused bf16 output.
// ---------------------------------------------------------------------------

typedef unsigned short ushort_t;
typedef unsigned int uint_t;
using bf16x8_t = __attribute__((ext_vector_type(8))) short;
using f32x4_t  = __attribute__((ext_vector_type(4))) float;
using u16x8_t  = __attribute__((ext_vector_type(8))) unsigned short;

__device__ __forceinline__ unsigned short f2b(float x) {
    union { float f; uint_t u; } c; c.f = x;
    uint_t r = c.u + 0x7fffu + ((c.u >> 16) & 1u);   // RNE
    return (unsigned short)(r >> 16);
}
__device__ __forceinline__ float gelu_exact(float v) {
    return 0.5f * v * (1.0f + erff(v * 0.70710678118654752f));
}

#define GCAST(p) ((const __attribute__((address_space(1))) void*)(p))
#define LCAST(p) ((__attribute__((address_space(3))) void*)(p))

// ------------------------- bf16 MFMA GEMM ---------------------------------
// C[m,n] = sum_k A[m,k]*B[n,k]  (A: [M,K] bf16 row-major, B: [N,K] bf16 row-major)
// 128x128 tile, BK=32, 4 waves of 64x64, global_load_lds staging (m97 structure).
enum { ME_F32 = 0, ME_BF16, ME_BIASROW_BF16, ME_BIASCOL_DUAL,
       ME_BIASCOL_ACC_F32, ME_GELU_BF16, ME_RES_F32, ME_TREND };

template<int EPI>
__global__ __launch_bounds__(256)
void mgemm_k(const ushort_t* __restrict__ A, const ushort_t* __restrict__ B,
             const float* __restrict__ bias, const float* __restrict__ Res,
             void* __restrict__ Cv, ushort_t* __restrict__ C2,
             int M, int N, int K, int ldc, int ldres,
             long sA, long sB, long sC, long sRes)
{
    const int bz = blockIdx.z;
    A += bz * sA;
    B += bz * sB;
    const int m0 = blockIdx.y * 128, n0 = blockIdx.x * 128;

    __shared__ __align__(16) ushort_t As[128 * 32];
    __shared__ __align__(16) ushort_t Bs[128 * 32];

    const int tid = threadIdx.x;
    const int wave = tid >> 6, lane = tid & 63;
    const int wr = wave >> 1, wc = wave & 1;

    f32x4_t acc[4][4] = {};

    const int srow = (lane >> 2);
    const int skof = (lane & 3) * 8;
    const int seg  = wave * 2;

    for (int k0 = 0; k0 < K; k0 += 32) {
        const ushort_t* ga = A + (long)(m0 + seg * 16 + srow) * K + k0 + skof;
        const ushort_t* gb = B + (long)(n0 + seg * 16 + srow) * K + k0 + skof;
        __builtin_amdgcn_global_load_lds(GCAST(ga),                 LCAST(As + seg * 512),       16, 0, 0);
        __builtin_amdgcn_global_load_lds(GCAST(ga + (long)16 * K),  LCAST(As + seg * 512 + 512), 16, 0, 0);
        __builtin_amdgcn_global_load_lds(GCAST(gb),                 LCAST(Bs + seg * 512),       16, 0, 0);
        __builtin_amdgcn_global_load_lds(GCAST(gb + (long)16 * K),  LCAST(Bs + seg * 512 + 512), 16, 0, 0);
        __syncthreads();

        const int kg = (lane >> 4) * 8;
        bf16x8_t a[4], b[4];
        #pragma unroll
        for (int i = 0; i < 4; ++i)
            a[i] = *(const bf16x8_t*)&As[(wr * 64 + i * 16 + (lane & 15)) * 32 + kg];
        #pragma unroll
        for (int j = 0; j < 4; ++j)
            b[j] = *(const bf16x8_t*)&Bs[(wc * 64 + j * 16 + (lane & 15)) * 32 + kg];
        #pragma unroll
        for (int i = 0; i < 4; ++i)
            #pragma unroll
            for (int j = 0; j < 4; ++j)
                acc[i][j] = __builtin_amdgcn_mfma_f32_16x16x32_bf16(a[i], b[j], acc[i][j], 0, 0, 0);
        __syncthreads();
    }

    float*    Cf  = (float*)Cv + bz * sC;
    ushort_t* Cb  = (ushort_t*)Cv + bz * sC;
    ushort_t* Cb2 = C2 ? C2 + bz * sC : nullptr;
    const float* R = Res ? Res + bz * sRes : nullptr;

    #pragma unroll
    for (int i = 0; i < 4; ++i) {
        #pragma unroll
        for (int j = 0; j < 4; ++j) {
            #pragma unroll
            for (int r = 0; r < 4; ++r) {
                int gm = m0 + wr * 64 + i * 16 + (lane >> 4) * 4 + r;
                int gn = n0 + wc * 64 + j * 16 + (lane & 15);
                float v = acc[i][j][r];
                long idx = (long)gm * ldc + gn;
                if (EPI == ME_F32)               Cf[idx] = v;
                else if (EPI == ME_BF16)         Cb[idx] = f2b(v);
                else if (EPI == ME_BIASROW_BF16) Cb[idx] = f2b(v + bias[gm]);
                else if (EPI == ME_BIASCOL_DUAL) {
                    float vv = v + bias[gn];
                    Cf[idx] = vv; Cb2[idx] = f2b(vv);
                }
                else if (EPI == ME_BIASCOL_ACC_F32) Cf[idx] += v + bias[gn];
                else if (EPI == ME_GELU_BF16)    Cb[idx] = f2b(gelu_exact(v));
                else if (EPI == ME_RES_F32)      Cf[idx] = v + R[(long)gm * ldres + gn];
                else if (EPI == ME_TREND) { if (gm < 96) Cf[idx] = v + bias[gm]; }
            }
        }
    }
}

// ---------------- batched complex mode-mix MFMA (per h,m) ------------------
// block = (h*64+m): OS[b, n2] = sum_k2 A2[h][m][b][k2] * B2[h][m][n2][k2]
// A2: [8][64][32][128] bf16, B2: [8][64][128][128] bf16
// scatter-store to OSELb[(b*512 + h*64 + o)*128 + ri*64 + m]
__global__ __launch_bounds__(256)
void fmix_k(const ushort_t* __restrict__ A2, const ushort_t* __restrict__ B2,
            ushort_t* __restrict__ OS)
{
    const int hm = blockIdx.x;
    const int h = hm >> 6, m = hm & 63;
    __shared__ __align__(16) ushort_t As[32 * 128];
    __shared__ __align__(16) ushort_t Bs[128 * 128];

    const int tid = threadIdx.x;
    const int w = tid >> 6, lane = tid & 63;

    const ushort_t* Ag = A2 + (long)hm * 4096;
    const ushort_t* Bg = B2 + (long)hm * 16384;
    #pragma unroll
    for (int r = 0; r < 2; ++r)
        __builtin_amdgcn_global_load_lds(GCAST(Ag + w * 1024 + r * 512 + lane * 8),
                                         LCAST(As + w * 1024 + r * 512), 16, 0, 0);
    #pragma unroll
    for (int r = 0; r < 8; ++r)
        __builtin_amdgcn_global_load_lds(GCAST(Bg + w * 4096 + r * 512 + lane * 8),
                                         LCAST(Bs + w * 4096 + r * 512), 16, 0, 0);
    __syncthreads();

    f32x4_t acc[2][2] = {};
    const int kg = (lane >> 4) * 8;
    #pragma unroll
    for (int kk = 0; kk < 4; ++kk) {
        bf16x8_t a[2], b[2];
        #pragma unroll
        for (int i = 0; i < 2; ++i)
            a[i] = *(const bf16x8_t*)&As[(i * 16 + (lane & 15)) * 128 + kk * 32 + kg];
        #pragma unroll
        for (int j = 0; j < 2; ++j)
            b[j] = *(const bf16x8_t*)&Bs[(w * 32 + j * 16 + (lane & 15)) * 128 + kk * 32 + kg];
        #pragma unroll
        for (int i = 0; i < 2; ++i)
            #pragma unroll
            for (int j = 0; j < 2; ++j)
                acc[i][j] = __builtin_amdgcn_mfma_f32_16x16x32_bf16(a[i], b[j], acc[i][j], 0, 0, 0);
    }

    #pragma unroll
    for (int i = 0; i < 2; ++i) {
        #pragma unroll
        for (int j = 0; j < 2; ++j) {
            #pragma unroll
            for (int r = 0; r < 4; ++r) {
                int b = i * 16 + (lane >> 4) * 4 + r;
                int n2 = w * 32 + j * 16 + (lane & 15);
                int o = n2 & 63, ri = n2 >> 6;
                OS[((long)b * 512 + h * 64 + o) * 128 + ri * 64 + m] = f2b(acc[i][j][r]);
            }
        }
    }
}

// B2 prep: block per (h,o). Fr/Fi [h][i][o][m] f32 -> B2[h][m][n2][k2] bf16
__global__ __launch_bounds__(256)
void bprep_k(const float* __restrict__ FR, const float* __restrict__ FI,
             ushort_t* __restrict__ B2)
{
    const int bx = blockIdx.x;
    const int h = bx >> 6, o = bx & 63;
    __shared__ float fr_s[64][65];
    __shared__ float fi_s[64][65];
    for (int e = threadIdx.x; e < 4096; e += 256) {
        int i = e >> 6, m = e & 63;
        long src = ((long)(h * 64 + i) * 64 + o) * 64 + m;
        fr_s[i][m] = FR[src];
        fi_s[i][m] = FI[src];
    }
    __syncthreads();
    const int m = threadIdx.x & 63;
    const int kq = threadIdx.x >> 6;
    ushort_t* b0 = B2 + ((long)(h * 64 + m) * 128 + o) * 128;        // n2 = o (real)
    ushort_t* b1 = B2 + ((long)(h * 64 + m) * 128 + o + 64) * 128;   // n2 = o+64 (imag)
    for (int kk = 0; kk < 32; ++kk) {
        int k2 = kq * 32 + kk;
        int ik = k2 & 63, hi = k2 >> 6;
        float fr = fr_s[ik][m], fi = fi_s[ik][m];
        b0[k2] = f2b(hi ? -fi : fr);
        b1[k2] = f2b(hi ?  fr : fi);
    }
}

// A2 prep: block per (b,h). XFT [b][c=h*64+i][mp] f32 -> A2[h][m][b][k2] bf16
__global__ __launch_bounds__(256)
void aprep_k(const float* __restrict__ XFT, ushort_t* __restrict__ A2)
{
    const int bx = blockIdx.x;
    const int b = bx >> 3, h = bx & 7;
    __shared__ float xs[64][129];
    for (int e = threadIdx.x; e < 8192; e += 256) {
        int i = e >> 7, mp = e & 127;
        xs[i][mp] = XFT[((long)b * 512 + h * 64 + i) * 128 + mp];
    }
    __syncthreads();
    const int m = threadIdx.x & 63;
    const int kq = threadIdx.x >> 6;
    ushort_t* dst = A2 + ((long)(h * 64 + m) * 32 + b) * 128;
    for (int kk = 0; kk < 32; ++kk) {
        int k2 = kq * 32 + kk;
        int i = k2 & 63, ri = k2 >> 6;
        dst[k2] = f2b(xs[i][ri * 64 + m]);
    }
}

// ------------- sliding-window series_decomp (k=25), dual output ------------
__global__ __launch_bounds__(256)
void decomp2_k(const float* __restrict__ X, float* __restrict__ S,
               ushort_t* __restrict__ Sb, float* __restrict__ Tr)
{
    const int id = blockIdx.x;
    const int ch = id & 1, rc = (id >> 1) & 31, b = id >> 6;
    const int c = ch * 256 + threadIdx.x;
    const int r0 = rc * 16;
    const long base = ((long)b << 18) + c;
    float s = 0.f;
    #pragma unroll
    for (int j = -12; j <= 12; ++j) {
        int rr = r0 + j; rr = rr < 0 ? 0 : (rr > 511 ? 511 : rr);
        s += X[base + ((long)rr << 9)];
    }
    for (int rr = 0; rr < 16; ++rr) {
        int r = r0 + rr;
        float mean = s * (1.f / 25.f);
        long idx = base + ((long)r << 9);
        float x = X[idx];
        if (S)  S[idx] = x - mean;
        if (Sb) Sb[idx] = f2b(x - mean);
        if (Tr) Tr[idx] = mean;
        int rp = r + 13; rp = rp > 511 ? 511 : rp;
        int rm = r - 12; rm = rm < 0 ? 0 : rm;
        s += X[base + ((long)rp << 9)] - X[base + ((long)rm << 9)];
    }
}

// ----------------------- bf16 DFT tables ([N,K] layouts) -------------------
__global__ __launch_bounds__(256)
void init_tables_k(ushort_t* __restrict__ TFb, ushort_t* __restrict__ TIb)
{
    int t = blockIdx.x * 256 + threadIdx.x;   // 0..131071
    const float w = 6.283185307179586f / 512.f;
    if (t < 65536) {
        int mp = t >> 9, n = t & 511;
        int m = mp & 63;
        float ang = ((m * n) & 511) * w;
        TFb[t] = f2b((mp < 64) ? cosf(ang) : -sinf(ang));
    } else {
        int u = t - 65536;
        int n = u >> 7, mp = u & 127;
        int m = mp & 63;
        float ang = ((m * n) & 511) * w;
        float v;
        if (mp < 64) v = (m == 0) ? (1.f / 512.f) : (2.f / 512.f) * cosf(ang);
        else         v = (m == 0) ? 0.f : -(2.f / 512.f) * sinf(ang);
        TIb[u] = f2b(v);
    }
}

// ----------------------- fp32 -> bf16 convert (weights) --------------------
__global__ __launch_bounds__(256)
void f2b_k(const float* __restrict__ X, ushort_t* __restrict__ Y, long n)
{
    long i = ((long)blockIdx.x * 256 + threadIdx.x) * 8;
    if (i >= n) return;
    const float4* xp = (const float4*)(X + i);
    float4 v0 = xp[0], v1 = xp[1];
    u16x8_t o;
    o[0] = f2b(v0.x); o[1] = f2b(v0.y); o[2] = f2b(v0.z); o[3] = f2b(v0.w);
    o[4] = f2b(v1.x); o[5] = f2b(v1.y); o[6] = f2b(v1.z); o[7] = f2b(v1.w);
    *(u16x8_t*)(Y + i) = o;
}

// ----------------- fp32 [R,C] -> bf16 transposed [C,R] ---------------------
__global__ __launch_bounds__(256)
void trans_b_k(const float* __restrict__ X, ushort_t* __restrict__ Y,
               int R, int C, long sX, long sY)
{
    __shared__ float t[32][33];
    X += (long)blockIdx.z * sX;
    Y += (long)blockIdx.z * sY;
    int r0 = blockIdx.y * 32, c0 = blockIdx.x * 32;
    int tx = threadIdx.x & 31, ty = threadIdx.x >> 5;
    #pragma unroll
    for (int i = ty; i < 32; i += 8)
        t[i][tx] = X[(long)(r0 + i) * C + c0 + tx];
    __syncthreads();
    #pragma unroll
    for (int i = ty; i < 32; i += 8)
        Y[(long)(c0 + i) * R + r0 + tx] = f2b(t[tx][i]);
}

// ------------------------------ layernorm ----------------------------------
__global__ __launch_bounds__(256)
void ln_rows_k(const float* __restrict__ X, const float* __restrict__ g,
               const float* __restrict__ bta, float* __restrict__ Y)
{
    int wave = threadIdx.x >> 6, lane = threadIdx.x & 63;
    long row = (long)blockIdx.x * 4 + wave;
    const float* x = X + row * 512;
    float s = 0.f, ss = 0.f;
    for (int d = lane; d < 512; d += 64) { float v = x[d]; s += v; ss += v * v; }
    #pragma unroll
    for (int o = 32; o; o >>= 1) { s += __shfl_xor(s, o); ss += __shfl_xor(ss, o); }
    float mu = s * (1.f / 512.f);
    float var = ss * (1.f / 512.f) - mu * mu;
    float inv = rsqrtf(var + 1e-5f);
    float* y = Y + row * 512;
    for (int d = lane; d < 512; d += 64)
        y[d] = (x[d] - mu) * inv * g[d] + bta[d];
}

// subtract per-(b,d) seq-mean, emit bf16
__global__ __launch_bounds__(64)
void colmean_b16_k(const float* __restrict__ Y, ushort_t* __restrict__ O)
{
    int b = blockIdx.x, dg = blockIdx.y;
    int d = dg * 64 + threadIdx.x;
    long base = (long)b * 262144 + d;
    float s = 0.f;
    for (int t = 0; t < 512; ++t) s += Y[base + ((long)t << 9)];
    float mean = s * (1.f / 512.f);
    for (int t = 0; t < 512; ++t)
        O[base + ((long)t << 9)] = f2b(Y[base + ((long)t << 9)] - mean);
}

// head transpose-add: out[b,p,t] += Thead[(b*512+t)*128+p] + b_head[p]
__global__ __launch_bounds__(256)
void headadd_k(const float* __restrict__ Th, const float* __restrict__ bh,
               float* __restrict__ out)
{
    const int id = blockIdx.x;          // b*16 + tc
    const int b = id >> 4, t0 = (id & 15) * 32;
    __shared__ float tile[32][100];
    for (int e = threadIdx.x; e < 32 * 96; e += 256) {
        int tl = e / 96, p = e - tl * 96;
        tile[tl][p] = Th[((long)(b * 512 + t0 + tl)) * 128 + p];
    }
    __syncthreads();
    for (int e = threadIdx.x; e < 96 * 32; e += 256) {
        int p = e >> 5, tl = e & 31;
        out[(long)b * 49152 + p * 512 + t0 + tl] += tile[tl][p] + bh[p];
    }
}

// ===========================================================================
extern "C" void kernel_launch(void* const* d_in, const int* in_sizes, int n_in,
                              void* d_out, int out_size, void* d_ws, size_t ws_size,
                              hipStream_t stream)
{
    const float* x_enc   = (const float*)d_in[0];
    const float* W_trend = (const float*)d_in[4];
    const float* b_trend = (const float*)d_in[5];
    const float* W_emb   = (const float*)d_in[6];
    const float* b_emb   = (const float*)d_in[7];
    const float* Wq      = (const float*)d_in[8];
    const float* bq      = (const float*)d_in[9];
    const float* fw_r    = (const float*)d_in[14];
    const float* fw_i    = (const float*)d_in[15];
    const float* Wo      = (const float*)d_in[16];
    const float* bo      = (const float*)d_in[17];
    const float* W1      = (const float*)d_in[18];
    const float* W2      = (const float*)d_in[19];
    const float* ln_g    = (const float*)d_in[20];
    const float* ln_b    = (const float*)d_in[21];
    const float* W_head  = (const float*)d_in[22];
    const float* b_head  = (const float*)d_in[23];
    float* out = (float*)d_out;
    float* ws  = (float*)d_ws;

    const long F = 8388608;
    float* bufA = ws;                 // trend f32 / B2 bf16 / gelu bf16 / Thead f32
    float* bufB = ws + F;             // seasonal / decomp-S f32
    float* X    = ws + 2 * F;         // encoder state f32
    float* T1   = ws + 3 * F;         // FFN out f32; attention-phase overlays:
    float*    XFT   = T1;                               // [B,512,128] f32
    ushort_t* A2    = (ushort_t*)(T1 + 2097152);        // [8][64][32][128] bf16
    ushort_t* OSELb = (ushort_t*)(T1 + 3145728);        // [B,512,128] bf16
    ushort_t* xtb   = (ushort_t*)(T1 + 4194304);        // [16384,512] bf16
    ushort_t* qT    = (ushort_t*)(ws + 4 * F);          // [B,512,512] bf16 (trendT/seasonalT/qT)
    ushort_t* xb    = qT + 8388608;                     // [16384,512] bf16
    float* wblk = ws + 5 * F;
    ushort_t* WembT  = (ushort_t*)wblk;                 // [512,512]
    ushort_t* WTq    = WembT + 262144;
    ushort_t* WTo    = WTq + 262144;
    ushort_t* W1b    = WTo + 262144;                    // [2048,512]
    ushort_t* W2b    = W1b + 1048576;                   // [512,2048]
    ushort_t* TFb    = W2b + 1048576;                   // [128,512]
    ushort_t* TIb    = TFb + 65536;                     // [512,128]
    ushort_t* WtT    = TIb + 65536;                     // [128,512] rows<96 valid
    ushort_t* WheadT = WtT + 65536;                     // [128,512] rows<96 valid
    ushort_t* B2     = (ushort_t*)bufA;                 // [8][64][128][128] bf16
    float*    Thead  = bufA;                            // [16384,128] f32

    dim3 blk(256);

    init_tables_k<<<dim3(512), blk, 0, stream>>>(TFb, TIb);

    // decomp(x_enc): bufB = seasonal f32, bufA = trend f32
    decomp2_k<<<dim3(2048), blk, 0, stream>>>(x_enc, bufB, nullptr, bufA);

    // one-time weight transposes
    trans_b_k<<<dim3(3, 16, 1), blk, 0, stream>>>(W_trend, WtT, 512, 96, 0L, 0L);
    trans_b_k<<<dim3(3, 16, 1), blk, 0, stream>>>(W_head, WheadT, 512, 96, 0L, 0L);
    trans_b_k<<<dim3(16, 16, 1), blk, 0, stream>>>(W_emb, WembT, 512, 512, 0L, 0L);

    // trendT bf16 [b,n,l] into qT slot, then trend head: out = WtT . trendT^T
    trans_b_k<<<dim3(16, 16, 32), blk, 0, stream>>>(bufA, qT, 512, 512, 262144L, 262144L);
    mgemm_k<ME_TREND><<<dim3(4, 1, 32), blk, 0, stream>>>(
        WtT, qT, b_trend, nullptr, out, nullptr,
        128, 512, 512, 512, 0, 0L, 262144L, 49152L, 0L);

    // seasonalT bf16 into qT slot; embedding -> X f32 + xb bf16
    trans_b_k<<<dim3(16, 16, 32), blk, 0, stream>>>(bufB, qT, 512, 512, 262144L, 262144L);
    mgemm_k<ME_BIASCOL_DUAL><<<dim3(4, 4, 32), blk, 0, stream>>>(
        qT, WembT, b_emb, nullptr, X, xb,
        512, 512, 512, 512, 0, 262144L, 0L, 262144L, 0L);

    for (int l = 0; l < 2; ++l) {
        const float* Wq_l = Wq + (long)l * 262144;
        const float* bq_l = bq + (long)l * 512;
        const float* Wo_l = Wo + (long)l * 262144;
        const float* bo_l = bo + (long)l * 512;
        const float* W1_l = W1 + (long)l * 1048576;
        const float* W2_l = W2 + (long)l * 1048576;
        const float* fr_l = fw_r + (long)l * 2097152;
        const float* fi_l = fw_i + (long)l * 2097152;

        // weight prep
        trans_b_k<<<dim3(16, 16, 1), blk, 0, stream>>>(Wq_l, WTq, 512, 512, 0L, 0L);
        trans_b_k<<<dim3(16, 16, 1), blk, 0, stream>>>(Wo_l, WTo, 512, 512, 0L, 0L);
        f2b_k<<<dim3(512), blk, 0, stream>>>(W1_l, W1b, 1048576L);
        f2b_k<<<dim3(512), blk, 0, stream>>>(W2_l, W2b, 1048576L);
        bprep_k<<<dim3(512), blk, 0, stream>>>(fr_l, fi_l, B2);

        // qT[b,c,n] = WTq[c,:] . X[b,n,:] + bq[c]
        mgemm_k<ME_BIASROW_BF16><<<dim3(4, 4, 32), blk, 0, stream>>>(
            WTq, xb, bq_l, nullptr, qT, nullptr,
            512, 512, 512, 512, 0, 0L, 262144L, 262144L, 0L);

        // XFT[b,c,mp] = qT[b,c,:] . TFb[mp,:]
        mgemm_k<ME_F32><<<dim3(1, 4, 32), blk, 0, stream>>>(
            qT, TFb, nullptr, nullptr, XFT, nullptr,
            512, 128, 512, 128, 0, 262144L, 0L, 65536L, 0L);

        // complex mode mixing via batched MFMA
        aprep_k<<<dim3(256), blk, 0, stream>>>(XFT, A2);
        fmix_k<<<dim3(512), blk, 0, stream>>>(A2, B2, OSELb);

        // xtb[(b,c),n] = OSELb[(b,c),:] . TIb[n,:]
        mgemm_k<ME_BF16><<<dim3(4, 128, 1), blk, 0, stream>>>(
            OSELb, TIb, nullptr, nullptr, xtb, nullptr,
            16384, 512, 128, 512, 0, 0L, 0L, 0L, 0L);

        // X += xtb . WTo^T + bo
        mgemm_k<ME_BIASCOL_ACC_F32><<<dim3(4, 128, 1), blk, 0, stream>>>(
            xtb, WTo, bo_l, nullptr, X, nullptr,
            16384, 512, 512, 512, 0, 0L, 0L, 0L, 0L);

        // decomp -> bufB f32 + xb bf16
        decomp2_k<<<dim3(2048), blk, 0, stream>>>(X, bufB, xb, nullptr);

        // FFN in 2 chunks of M=8192
        for (int rc = 0; rc < 2; ++rc) {
            const ushort_t* xin_b = xb + (long)rc * 4194304;
            const float*    xin_f = bufB + (long)rc * 4194304;
            float*          yout  = T1 + (long)rc * 4194304;
            ushort_t*       gb    = (ushort_t*)bufA;
            mgemm_k<ME_GELU_BF16><<<dim3(16, 64, 1), blk, 0, stream>>>(
                xin_b, W1b, nullptr, nullptr, gb, nullptr,
                8192, 2048, 512, 2048, 0, 0L, 0L, 0L, 0L);
            mgemm_k<ME_RES_F32><<<dim3(4, 64, 1), blk, 0, stream>>>(
                gb, W2b, nullptr, xin_f, yout, nullptr,
                8192, 512, 2048, 512, 512, 0L, 0L, 0L, 0L);
        }

        // decomp -> X f32 + xb bf16 (next layer / LN input)
        decomp2_k<<<dim3(2048), blk, 0, stream>>>(T1, X, xb, nullptr);
    }

    // my_layernorm: rows -> T1 f32, then seq-mean subtract -> xb bf16
    ln_rows_k<<<dim3(4096), blk, 0, stream>>>(X, ln_g, ln_b, T1);
    colmean_b16_k<<<dim3(32, 8), dim3(64), 0, stream>>>(T1, xb);

    // head: Thead[(b,t),p] = xb . WheadT^T  (cols>=96 garbage, masked later)
    mgemm_k<ME_F32><<<dim3(1, 128, 1), blk, 0, stream>>>(
        xb, WheadT, nullptr, nullptr, Thead, nullptr,
        16384, 128, 512, 128, 0, 0L, 0L, 0L, 0L);

    // out[b,p,t] += Thead + b_head
    headadd_k<<<dim3(512), blk, 0, stream>>>(Thead, b_head, out);
}

// Round 4
// 781.073 us; speedup vs baseline: 6.1491x; 1.2075x over previous
//
#include <hip/hip_runtime.h>
#include <math.h>

// ---------------------------------------------------------------------------
// Model_24180665876772  Round 4: TLP fix. mgemm -> 8 waves/block (512 thr),
// FFN unchunked (full M=16384), workspace re-layout so the 67MB gelu buffer
// overlays dead attention scratch.
// ---------------------------------------------------------------------------

typedef unsigned short ushort_t;
typedef unsigned int uint_t;
using bf16x8_t = __attribute__((ext_vector_type(8))) short;
using f32x4_t  = __attribute__((ext_vector_type(4))) float;
using u16x8_t  = __attribute__((ext_vector_type(8))) unsigned short;

__device__ __forceinline__ unsigned short f2b(float x) {
    union { float f; uint_t u; } c; c.f = x;
    uint_t r = c.u + 0x7fffu + ((c.u >> 16) & 1u);   // RNE
    return (unsigned short)(r >> 16);
}
__device__ __forceinline__ float gelu_exact(float v) {
    return 0.5f * v * (1.0f + erff(v * 0.70710678118654752f));
}

#define GCAST(p) ((const __attribute__((address_space(1))) void*)(p))
#define LCAST(p) ((__attribute__((address_space(3))) void*)(p))

// ------------------------- bf16 MFMA GEMM ---------------------------------
// C[m,n] = sum_k A[m,k]*B[n,k]  (A: [M,K] bf16 row-major, B: [N,K] bf16 row-major)
// 128x128 tile, BK=32, 8 waves of 32x64 each, global_load_lds staging.
enum { ME_F32 = 0, ME_BF16, ME_BIASROW_BF16, ME_BIASCOL_DUAL,
       ME_BIASCOL_ACC_F32, ME_GELU_BF16, ME_RES_F32, ME_TREND };

template<int EPI>
__global__ __launch_bounds__(512)
void mgemm_k(const ushort_t* __restrict__ A, const ushort_t* __restrict__ B,
             const float* __restrict__ bias, const float* __restrict__ Res,
             void* __restrict__ Cv, ushort_t* __restrict__ C2,
             int M, int N, int K, int ldc, int ldres,
             long sA, long sB, long sC, long sRes)
{
    const int bz = blockIdx.z;
    A += bz * sA;
    B += bz * sB;
    const int m0 = blockIdx.y * 128, n0 = blockIdx.x * 128;

    __shared__ __align__(16) ushort_t As[128 * 32];
    __shared__ __align__(16) ushort_t Bs[128 * 32];

    const int tid = threadIdx.x;
    const int wave = tid >> 6, lane = tid & 63;
    const int wr = wave >> 1, wc = wave & 1;   // wr 0..3 (rows), wc 0..1 (cols)

    f32x4_t acc[2][4] = {};

    const int srow = tid >> 2;           // 0..127 (tile row staged by this thread)
    const int skof = (tid & 3) * 8;      // k-offset in bf16 elems

    for (int k0 = 0; k0 < K; k0 += 32) {
        const ushort_t* ga = A + (long)(m0 + srow) * K + k0 + skof;
        const ushort_t* gb = B + (long)(n0 + srow) * K + k0 + skof;
        // wave-uniform LDS base; HW scatters lane*16B
        __builtin_amdgcn_global_load_lds(GCAST(ga), LCAST(As + wave * 512), 16, 0, 0);
        __builtin_amdgcn_global_load_lds(GCAST(gb), LCAST(Bs + wave * 512), 16, 0, 0);
        __syncthreads();

        const int kg = (lane >> 4) * 8;
        bf16x8_t a[2], b[4];
        #pragma unroll
        for (int i = 0; i < 2; ++i)
            a[i] = *(const bf16x8_t*)&As[(wr * 32 + i * 16 + (lane & 15)) * 32 + kg];
        #pragma unroll
        for (int j = 0; j < 4; ++j)
            b[j] = *(const bf16x8_t*)&Bs[(wc * 64 + j * 16 + (lane & 15)) * 32 + kg];
        #pragma unroll
        for (int i = 0; i < 2; ++i)
            #pragma unroll
            for (int j = 0; j < 4; ++j)
                acc[i][j] = __builtin_amdgcn_mfma_f32_16x16x32_bf16(a[i], b[j], acc[i][j], 0, 0, 0);
        __syncthreads();
    }

    float*    Cf  = (float*)Cv + bz * sC;
    ushort_t* Cb  = (ushort_t*)Cv + bz * sC;
    ushort_t* Cb2 = C2 ? C2 + bz * sC : nullptr;
    const float* R = Res ? Res + bz * sRes : nullptr;

    #pragma unroll
    for (int i = 0; i < 2; ++i) {
        #pragma unroll
        for (int j = 0; j < 4; ++j) {
            #pragma unroll
            for (int r = 0; r < 4; ++r) {
                int gm = m0 + wr * 32 + i * 16 + (lane >> 4) * 4 + r;
                int gn = n0 + wc * 64 + j * 16 + (lane & 15);
                float v = acc[i][j][r];
                long idx = (long)gm * ldc + gn;
                if (EPI == ME_F32)               Cf[idx] = v;
                else if (EPI == ME_BF16)         Cb[idx] = f2b(v);
                else if (EPI == ME_BIASROW_BF16) Cb[idx] = f2b(v + bias[gm]);
                else if (EPI == ME_BIASCOL_DUAL) {
                    float vv = v + bias[gn];
                    Cf[idx] = vv; Cb2[idx] = f2b(vv);
                }
                else if (EPI == ME_BIASCOL_ACC_F32) Cf[idx] += v + bias[gn];
                else if (EPI == ME_GELU_BF16)    Cb[idx] = f2b(gelu_exact(v));
                else if (EPI == ME_RES_F32)      Cf[idx] = v + R[(long)gm * ldres + gn];
                else if (EPI == ME_TREND) { if (gm < 96) Cf[idx] = v + bias[gm]; }
            }
        }
    }
}

// ---------------- batched complex mode-mix MFMA (per h,m) ------------------
__global__ __launch_bounds__(256)
void fmix_k(const ushort_t* __restrict__ A2, const ushort_t* __restrict__ B2,
            ushort_t* __restrict__ OS)
{
    const int hm = blockIdx.x;
    const int h = hm >> 6, m = hm & 63;
    __shared__ __align__(16) ushort_t As[32 * 128];
    __shared__ __align__(16) ushort_t Bs[128 * 128];

    const int tid = threadIdx.x;
    const int w = tid >> 6, lane = tid & 63;

    const ushort_t* Ag = A2 + (long)hm * 4096;
    const ushort_t* Bg = B2 + (long)hm * 16384;
    #pragma unroll
    for (int r = 0; r < 2; ++r)
        __builtin_amdgcn_global_load_lds(GCAST(Ag + w * 1024 + r * 512 + lane * 8),
                                         LCAST(As + w * 1024 + r * 512), 16, 0, 0);
    #pragma unroll
    for (int r = 0; r < 8; ++r)
        __builtin_amdgcn_global_load_lds(GCAST(Bg + w * 4096 + r * 512 + lane * 8),
                                         LCAST(Bs + w * 4096 + r * 512), 16, 0, 0);
    __syncthreads();

    f32x4_t acc[2][2] = {};
    const int kg = (lane >> 4) * 8;
    #pragma unroll
    for (int kk = 0; kk < 4; ++kk) {
        bf16x8_t a[2], b[2];
        #pragma unroll
        for (int i = 0; i < 2; ++i)
            a[i] = *(const bf16x8_t*)&As[(i * 16 + (lane & 15)) * 128 + kk * 32 + kg];
        #pragma unroll
        for (int j = 0; j < 2; ++j)
            b[j] = *(const bf16x8_t*)&Bs[(w * 32 + j * 16 + (lane & 15)) * 128 + kk * 32 + kg];
        #pragma unroll
        for (int i = 0; i < 2; ++i)
            #pragma unroll
            for (int j = 0; j < 2; ++j)
                acc[i][j] = __builtin_amdgcn_mfma_f32_16x16x32_bf16(a[i], b[j], acc[i][j], 0, 0, 0);
    }

    #pragma unroll
    for (int i = 0; i < 2; ++i) {
        #pragma unroll
        for (int j = 0; j < 2; ++j) {
            #pragma unroll
            for (int r = 0; r < 4; ++r) {
                int b = i * 16 + (lane >> 4) * 4 + r;
                int n2 = w * 32 + j * 16 + (lane & 15);
                int o = n2 & 63, ri = n2 >> 6;
                OS[((long)b * 512 + h * 64 + o) * 128 + ri * 64 + m] = f2b(acc[i][j][r]);
            }
        }
    }
}

// B2 prep: block per (h,o). Fr/Fi [h][i][o][m] f32 -> B2[h][m][n2][k2] bf16
__global__ __launch_bounds__(256)
void bprep_k(const float* __restrict__ FR, const float* __restrict__ FI,
             ushort_t* __restrict__ B2)
{
    const int bx = blockIdx.x;
    const int h = bx >> 6, o = bx & 63;
    __shared__ float fr_s[64][65];
    __shared__ float fi_s[64][65];
    for (int e = threadIdx.x; e < 4096; e += 256) {
        int i = e >> 6, m = e & 63;
        long src = ((long)(h * 64 + i) * 64 + o) * 64 + m;
        fr_s[i][m] = FR[src];
        fi_s[i][m] = FI[src];
    }
    __syncthreads();
    const int m = threadIdx.x & 63;
    const int kq = threadIdx.x >> 6;
    ushort_t* b0 = B2 + ((long)(h * 64 + m) * 128 + o) * 128;
    ushort_t* b1 = B2 + ((long)(h * 64 + m) * 128 + o + 64) * 128;
    for (int kk = 0; kk < 32; ++kk) {
        int k2 = kq * 32 + kk;
        int ik = k2 & 63, hi = k2 >> 6;
        float fr = fr_s[ik][m], fi = fi_s[ik][m];
        b0[k2] = f2b(hi ? -fi : fr);
        b1[k2] = f2b(hi ?  fr : fi);
    }
}

// A2 prep: block per (b,h). XFT [b][c=h*64+i][mp] f32 -> A2[h][m][b][k2] bf16
__global__ __launch_bounds__(256)
void aprep_k(const float* __restrict__ XFT, ushort_t* __restrict__ A2)
{
    const int bx = blockIdx.x;
    const int b = bx >> 3, h = bx & 7;
    __shared__ float xs[64][129];
    for (int e = threadIdx.x; e < 8192; e += 256) {
        int i = e >> 7, mp = e & 127;
        xs[i][mp] = XFT[((long)b * 512 + h * 64 + i) * 128 + mp];
    }
    __syncthreads();
    const int m = threadIdx.x & 63;
    const int kq = threadIdx.x >> 6;
    ushort_t* dst = A2 + ((long)(h * 64 + m) * 32 + b) * 128;
    for (int kk = 0; kk < 32; ++kk) {
        int k2 = kq * 32 + kk;
        int i = k2 & 63, ri = k2 >> 6;
        dst[k2] = f2b(xs[i][ri * 64 + m]);
    }
}

// ------------- sliding-window series_decomp (k=25), dual output ------------
__global__ __launch_bounds__(256)
void decomp2_k(const float* __restrict__ X, float* __restrict__ S,
               ushort_t* __restrict__ Sb, float* __restrict__ Tr)
{
    const int id = blockIdx.x;
    const int ch = id & 1, rc = (id >> 1) & 31, b = id >> 6;
    const int c = ch * 256 + threadIdx.x;
    const int r0 = rc * 16;
    const long base = ((long)b << 18) + c;
    float s = 0.f;
    #pragma unroll
    for (int j = -12; j <= 12; ++j) {
        int rr = r0 + j; rr = rr < 0 ? 0 : (rr > 511 ? 511 : rr);
        s += X[base + ((long)rr << 9)];
    }
    for (int rr = 0; rr < 16; ++rr) {
        int r = r0 + rr;
        float mean = s * (1.f / 25.f);
        long idx = base + ((long)r << 9);
        float x = X[idx];
        if (S)  S[idx] = x - mean;
        if (Sb) Sb[idx] = f2b(x - mean);
        if (Tr) Tr[idx] = mean;
        int rp = r + 13; rp = rp > 511 ? 511 : rp;
        int rm = r - 12; rm = rm < 0 ? 0 : rm;
        s += X[base + ((long)rp << 9)] - X[base + ((long)rm << 9)];
    }
}

// ----------------------- bf16 DFT tables ([N,K] layouts) -------------------
__global__ __launch_bounds__(256)
void init_tables_k(ushort_t* __restrict__ TFb, ushort_t* __restrict__ TIb)
{
    int t = blockIdx.x * 256 + threadIdx.x;   // 0..131071
    const float w = 6.283185307179586f / 512.f;
    if (t < 65536) {
        int mp = t >> 9, n = t & 511;
        int m = mp & 63;
        float ang = ((m * n) & 511) * w;
        TFb[t] = f2b((mp < 64) ? cosf(ang) : -sinf(ang));
    } else {
        int u = t - 65536;
        int n = u >> 7, mp = u & 127;
        int m = mp & 63;
        float ang = ((m * n) & 511) * w;
        float v;
        if (mp < 64) v = (m == 0) ? (1.f / 512.f) : (2.f / 512.f) * cosf(ang);
        else         v = (m == 0) ? 0.f : -(2.f / 512.f) * sinf(ang);
        TIb[u] = f2b(v);
    }
}

// ----------------------- fp32 -> bf16 convert (weights) --------------------
__global__ __launch_bounds__(256)
void f2b_k(const float* __restrict__ X, ushort_t* __restrict__ Y, long n)
{
    long i = ((long)blockIdx.x * 256 + threadIdx.x) * 8;
    if (i >= n) return;
    const float4* xp = (const float4*)(X + i);
    float4 v0 = xp[0], v1 = xp[1];
    u16x8_t o;
    o[0] = f2b(v0.x); o[1] = f2b(v0.y); o[2] = f2b(v0.z); o[3] = f2b(v0.w);
    o[4] = f2b(v1.x); o[5] = f2b(v1.y); o[6] = f2b(v1.z); o[7] = f2b(v1.w);
    *(u16x8_t*)(Y + i) = o;
}

// ----------------- fp32 [R,C] -> bf16 transposed [C,R] ---------------------
__global__ __launch_bounds__(256)
void trans_b_k(const float* __restrict__ X, ushort_t* __restrict__ Y,
               int R, int C, long sX, long sY)
{
    __shared__ float t[32][33];
    X += (long)blockIdx.z * sX;
    Y += (long)blockIdx.z * sY;
    int r0 = blockIdx.y * 32, c0 = blockIdx.x * 32;
    int tx = threadIdx.x & 31, ty = threadIdx.x >> 5;
    #pragma unroll
    for (int i = ty; i < 32; i += 8)
        t[i][tx] = X[(long)(r0 + i) * C + c0 + tx];
    __syncthreads();
    #pragma unroll
    for (int i = ty; i < 32; i += 8)
        Y[(long)(c0 + i) * R + r0 + tx] = f2b(t[tx][i]);
}

// ------------------------------ layernorm ----------------------------------
__global__ __launch_bounds__(256)
void ln_rows_k(const float* __restrict__ X, const float* __restrict__ g,
               const float* __restrict__ bta, float* __restrict__ Y)
{
    int wave = threadIdx.x >> 6, lane = threadIdx.x & 63;
    long row = (long)blockIdx.x * 4 + wave;
    const float* x = X + row * 512;
    float s = 0.f, ss = 0.f;
    for (int d = lane; d < 512; d += 64) { float v = x[d]; s += v; ss += v * v; }
    #pragma unroll
    for (int o = 32; o; o >>= 1) { s += __shfl_xor(s, o); ss += __shfl_xor(ss, o); }
    float mu = s * (1.f / 512.f);
    float var = ss * (1.f / 512.f) - mu * mu;
    float inv = rsqrtf(var + 1e-5f);
    float* y = Y + row * 512;
    for (int d = lane; d < 512; d += 64)
        y[d] = (x[d] - mu) * inv * g[d] + bta[d];
}

// subtract per-(b,d) seq-mean, emit bf16
__global__ __launch_bounds__(64)
void colmean_b16_k(const float* __restrict__ Y, ushort_t* __restrict__ O)
{
    int b = blockIdx.x, dg = blockIdx.y;
    int d = dg * 64 + threadIdx.x;
    long base = (long)b * 262144 + d;
    float s = 0.f;
    for (int t = 0; t < 512; ++t) s += Y[base + ((long)t << 9)];
    float mean = s * (1.f / 512.f);
    for (int t = 0; t < 512; ++t)
        O[base + ((long)t << 9)] = f2b(Y[base + ((long)t << 9)] - mean);
}

// head transpose-add: out[b,p,t] += Thead[(b*512+t)*128+p] + b_head[p]
__global__ __launch_bounds__(256)
void headadd_k(const float* __restrict__ Th, const float* __restrict__ bh,
               float* __restrict__ out)
{
    const int id = blockIdx.x;          // b*16 + tc
    const int b = id >> 4, t0 = (id & 15) * 32;
    __shared__ float tile[32][100];
    for (int e = threadIdx.x; e < 32 * 96; e += 256) {
        int tl = e / 96, p = e - tl * 96;
        tile[tl][p] = Th[((long)(b * 512 + t0 + tl)) * 128 + p];
    }
    __syncthreads();
    for (int e = threadIdx.x; e < 96 * 32; e += 256) {
        int p = e >> 5, tl = e & 31;
        out[(long)b * 49152 + p * 512 + t0 + tl] += tile[tl][p] + bh[p];
    }
}

// ===========================================================================
extern "C" void kernel_launch(void* const* d_in, const int* in_sizes, int n_in,
                              void* d_out, int out_size, void* d_ws, size_t ws_size,
                              hipStream_t stream)
{
    const float* x_enc   = (const float*)d_in[0];
    const float* W_trend = (const float*)d_in[4];
    const float* b_trend = (const float*)d_in[5];
    const float* W_emb   = (const float*)d_in[6];
    const float* b_emb   = (const float*)d_in[7];
    const float* Wq      = (const float*)d_in[8];
    const float* bq      = (const float*)d_in[9];
    const float* fw_r    = (const float*)d_in[14];
    const float* fw_i    = (const float*)d_in[15];
    const float* Wo      = (const float*)d_in[16];
    const float* bo      = (const float*)d_in[17];
    const float* W1      = (const float*)d_in[18];
    const float* W2      = (const float*)d_in[19];
    const float* ln_g    = (const float*)d_in[20];
    const float* ln_b    = (const float*)d_in[21];
    const float* W_head  = (const float*)d_in[22];
    const float* b_head  = (const float*)d_in[23];
    float* out = (float*)d_out;
    float* ws  = (float*)d_ws;

    const long F = 8388608;
    // Workspace layout:
    // [0 .. 2F)   G: attn scratch / trend f32 / gelu bf16 (16384x2048) / Thead
    // [2F..3F)    bufB f32 (seasonal / decomp S)
    // [3F..4F)    X f32 (encoder state)
    // [4F..5F)    T1 f32 (FFN out / LN out)
    // [5F..6F)    qT bf16 (8.4M) + xb bf16 (8.4M)
    // [6F..)      weights bf16
    float* G    = ws;
    float* bufB = ws + 2 * F;
    float* X    = ws + 3 * F;
    float* T1   = ws + 4 * F;
    ushort_t* qT = (ushort_t*)(ws + 5 * F);
    ushort_t* xb = qT + 8388608;

    // attn-phase overlays in G
    float*    XFT   = G;                               // 2.1M f32
    ushort_t* A2    = (ushort_t*)(G + 2097152);        // 2.1M us
    ushort_t* OSELb = (ushort_t*)(G + 3145728);        // 2.1M us
    ushort_t* xtb   = (ushort_t*)(G + 4194304);        // 8.4M us
    ushort_t* B2    = (ushort_t*)(G + 8388608);        // 8.4M us
    float*    trend = G;                               // start-phase
    float*    Thead = G;                               // end-phase
    ushort_t* gb    = (ushort_t*)G;                    // FFN-phase [16384,2048]

    ushort_t* WembT  = (ushort_t*)(ws + 6 * F);        // [512,512]
    ushort_t* WTq    = WembT + 262144;
    ushort_t* WTo    = WTq + 262144;
    ushort_t* W1b    = WTo + 262144;                   // [2048,512]
    ushort_t* W2b    = W1b + 1048576;                  // [512,2048]
    ushort_t* TFb    = W2b + 1048576;                  // [128,512]
    ushort_t* TIb    = TFb + 65536;                    // [512,128]
    ushort_t* WtT    = TIb + 65536;                    // [128,512] rows<96 valid
    ushort_t* WheadT = WtT + 65536;                    // [128,512] rows<96 valid

    dim3 blk(256), blk5(512);

    init_tables_k<<<dim3(512), blk, 0, stream>>>(TFb, TIb);

    // decomp(x_enc): bufB = seasonal f32, G = trend f32
    decomp2_k<<<dim3(2048), blk, 0, stream>>>(x_enc, bufB, nullptr, trend);

    // one-time weight transposes
    trans_b_k<<<dim3(3, 16, 1), blk, 0, stream>>>(W_trend, WtT, 512, 96, 0L, 0L);
    trans_b_k<<<dim3(3, 16, 1), blk, 0, stream>>>(W_head, WheadT, 512, 96, 0L, 0L);
    trans_b_k<<<dim3(16, 16, 1), blk, 0, stream>>>(W_emb, WembT, 512, 512, 0L, 0L);

    // trendT bf16 [b,n,l] into qT slot, then trend head GEMM
    trans_b_k<<<dim3(16, 16, 32), blk, 0, stream>>>(trend, qT, 512, 512, 262144L, 262144L);
    mgemm_k<ME_TREND><<<dim3(4, 1, 32), blk5, 0, stream>>>(
        WtT, qT, b_trend, nullptr, out, nullptr,
        128, 512, 512, 512, 0, 0L, 262144L, 49152L, 0L);

    // seasonalT bf16 into qT slot; embedding -> X f32 + xb bf16
    trans_b_k<<<dim3(16, 16, 32), blk, 0, stream>>>(bufB, qT, 512, 512, 262144L, 262144L);
    mgemm_k<ME_BIASCOL_DUAL><<<dim3(4, 4, 32), blk5, 0, stream>>>(
        qT, WembT, b_emb, nullptr, X, xb,
        512, 512, 512, 512, 0, 262144L, 0L, 262144L, 0L);

    for (int l = 0; l < 2; ++l) {
        const float* Wq_l = Wq + (long)l * 262144;
        const float* bq_l = bq + (long)l * 512;
        const float* Wo_l = Wo + (long)l * 262144;
        const float* bo_l = bo + (long)l * 512;
        const float* W1_l = W1 + (long)l * 1048576;
        const float* W2_l = W2 + (long)l * 1048576;
        const float* fr_l = fw_r + (long)l * 2097152;
        const float* fi_l = fw_i + (long)l * 2097152;

        // weight prep
        trans_b_k<<<dim3(16, 16, 1), blk, 0, stream>>>(Wq_l, WTq, 512, 512, 0L, 0L);
        trans_b_k<<<dim3(16, 16, 1), blk, 0, stream>>>(Wo_l, WTo, 512, 512, 0L, 0L);
        f2b_k<<<dim3(512), blk, 0, stream>>>(W1_l, W1b, 1048576L);
        f2b_k<<<dim3(512), blk, 0, stream>>>(W2_l, W2b, 1048576L);
        bprep_k<<<dim3(512), blk, 0, stream>>>(fr_l, fi_l, B2);

        // qT[b,c,n] = WTq[c,:] . X[b,n,:] + bq[c]
        mgemm_k<ME_BIASROW_BF16><<<dim3(4, 4, 32), blk5, 0, stream>>>(
            WTq, xb, bq_l, nullptr, qT, nullptr,
            512, 512, 512, 512, 0, 0L, 262144L, 262144L, 0L);

        // XFT[b,c,mp] = qT[b,c,:] . TFb[mp,:]
        mgemm_k<ME_F32><<<dim3(1, 4, 32), blk5, 0, stream>>>(
            qT, TFb, nullptr, nullptr, XFT, nullptr,
            512, 128, 512, 128, 0, 262144L, 0L, 65536L, 0L);

        // complex mode mixing via batched MFMA
        aprep_k<<<dim3(256), blk, 0, stream>>>(XFT, A2);
        fmix_k<<<dim3(512), blk, 0, stream>>>(A2, B2, OSELb);

        // xtb[(b,c),n] = OSELb[(b,c),:] . TIb[n,:]
        mgemm_k<ME_BF16><<<dim3(4, 128, 1), blk5, 0, stream>>>(
            OSELb, TIb, nullptr, nullptr, xtb, nullptr,
            16384, 512, 128, 512, 0, 0L, 0L, 0L, 0L);

        // X += xtb . WTo^T + bo
        mgemm_k<ME_BIASCOL_ACC_F32><<<dim3(4, 128, 1), blk5, 0, stream>>>(
            xtb, WTo, bo_l, nullptr, X, nullptr,
            16384, 512, 512, 512, 0, 0L, 0L, 0L, 0L);

        // decomp -> bufB f32 + xb bf16
        decomp2_k<<<dim3(2048), blk, 0, stream>>>(X, bufB, xb, nullptr);

        // FFN, full M=16384 (gb overlays attn scratch in G)
        mgemm_k<ME_GELU_BF16><<<dim3(16, 128, 1), blk5, 0, stream>>>(
            xb, W1b, nullptr, nullptr, gb, nullptr,
            16384, 2048, 512, 2048, 0, 0L, 0L, 0L, 0L);
        mgemm_k<ME_RES_F32><<<dim3(4, 128, 1), blk5, 0, stream>>>(
            gb, W2b, nullptr, bufB, T1, nullptr,
            16384, 512, 2048, 512, 512, 0L, 0L, 0L, 0L);

        // decomp -> X f32 + xb bf16 (next layer / LN input)
        decomp2_k<<<dim3(2048), blk, 0, stream>>>(T1, X, xb, nullptr);
    }

    // my_layernorm: rows -> T1 f32, then seq-mean subtract -> xb bf16
    ln_rows_k<<<dim3(4096), blk, 0, stream>>>(X, ln_g, ln_b, T1);
    colmean_b16_k<<<dim3(32, 8), dim3(64), 0, stream>>>(T1, xb);

    // head: Thead[(b,t),p] = xb . WheadT^T  (cols>=96 garbage, masked later)
    mgemm_k<ME_F32><<<dim3(1, 128, 1), blk5, 0, stream>>>(
        xb, WheadT, nullptr, nullptr, Thead, nullptr,
        16384, 128, 512, 128, 0, 0L, 0L, 0L, 0L);

    // out[b,p,t] += Thead + b_head
    headadd_k<<<dim3(512), blk, 0, stream>>>(Thead, b_head, out);
}

// Round 5
// 751.552 us; speedup vs baseline: 6.3906x; 1.0393x over previous
//
#include <hip/hip_runtime.h>
#include <math.h>

// ---------------------------------------------------------------------------
// Model_24180665876772  Round 5: 2-phase double-buffered mgemm (one barrier
// per K-step, load latency hidden under MFMA) + XCD-aware block swizzle.
// ---------------------------------------------------------------------------

typedef unsigned short ushort_t;
typedef unsigned int uint_t;
using bf16x8_t = __attribute__((ext_vector_type(8))) short;
using f32x4_t  = __attribute__((ext_vector_type(4))) float;
using u16x8_t  = __attribute__((ext_vector_type(8))) unsigned short;

__device__ __forceinline__ unsigned short f2b(float x) {
    union { float f; uint_t u; } c; c.f = x;
    uint_t r = c.u + 0x7fffu + ((c.u >> 16) & 1u);   // RNE
    return (unsigned short)(r >> 16);
}
__device__ __forceinline__ float gelu_exact(float v) {
    return 0.5f * v * (1.0f + erff(v * 0.70710678118654752f));
}

#define GCAST(p) ((const __attribute__((address_space(1))) void*)(p))
#define LCAST(p) ((__attribute__((address_space(3))) void*)(p))

// ------------------------- bf16 MFMA GEMM ---------------------------------
// C[m,n] = sum_k A[m,k]*B[n,k]  (A: [M,K] bf16 row-major, B: [N,K] bf16 row-major)
// 128x128 tile, BK=32, 8 waves of 32x64, double-buffered LDS, 1 barrier/K-step.
enum { ME_F32 = 0, ME_BF16, ME_BIASROW_BF16, ME_BIASCOL_DUAL,
       ME_BIASCOL_ACC_F32, ME_GELU_BF16, ME_RES_F32, ME_TREND };

template<int EPI>
__global__ __launch_bounds__(512)
void mgemm_k(const ushort_t* __restrict__ A, const ushort_t* __restrict__ B,
             const float* __restrict__ bias, const float* __restrict__ Res,
             void* __restrict__ Cv, ushort_t* __restrict__ C2,
             int M, int N, int K, int ldc, int ldres,
             long sA, long sB, long sC, long sRes)
{
    // XCD-aware bijective swizzle (all grids have nwg % 8 == 0)
    const int gx = gridDim.x, gy = gridDim.y;
    const int nwg = gx * gy * gridDim.z;
    const int lin = (blockIdx.z * gy + blockIdx.y) * gx + blockIdx.x;
    const int cpx = nwg >> 3;
    const int swz = (lin & 7) * cpx + (lin >> 3);
    const int bx = swz % gx;
    const int t2 = swz / gx;
    const int by = t2 % gy;
    const int bz = t2 / gy;

    A += bz * sA;
    B += bz * sB;
    const int m0 = by * 128, n0 = bx * 128;

    __shared__ __align__(16) ushort_t As[2][128 * 32];
    __shared__ __align__(16) ushort_t Bs[2][128 * 32];

    const int tid = threadIdx.x;
    const int wave = tid >> 6, lane = tid & 63;
    const int wr = wave >> 1, wc = wave & 1;   // wr 0..3 (rows), wc 0..1 (cols)

    f32x4_t acc[2][4] = {};

    const int srow = tid >> 2;           // 0..127 (tile row staged by this thread)
    const int skof = (tid & 3) * 8;      // k-offset in bf16 elems

    const ushort_t* ga = A + (long)(m0 + srow) * K + skof;
    const ushort_t* gb = B + (long)(n0 + srow) * K + skof;

    // prologue: stage K-step 0 into buffer 0
    __builtin_amdgcn_global_load_lds(GCAST(ga), LCAST(As[0] + wave * 512), 16, 0, 0);
    __builtin_amdgcn_global_load_lds(GCAST(gb), LCAST(Bs[0] + wave * 512), 16, 0, 0);
    __syncthreads();

    const int nt = K >> 5;
    int cur = 0;
    const int kg = (lane >> 4) * 8;

    for (int t = 0; t < nt; ++t) {
        if (t + 1 < nt) {
            const long ko = (long)(t + 1) << 5;
            __builtin_amdgcn_global_load_lds(GCAST(ga + ko), LCAST(As[cur ^ 1] + wave * 512), 16, 0, 0);
            __builtin_amdgcn_global_load_lds(GCAST(gb + ko), LCAST(Bs[cur ^ 1] + wave * 512), 16, 0, 0);
        }
        bf16x8_t a[2], b[4];
        #pragma unroll
        for (int i = 0; i < 2; ++i)
            a[i] = *(const bf16x8_t*)&As[cur][(wr * 32 + i * 16 + (lane & 15)) * 32 + kg];
        #pragma unroll
        for (int j = 0; j < 4; ++j)
            b[j] = *(const bf16x8_t*)&Bs[cur][(wc * 64 + j * 16 + (lane & 15)) * 32 + kg];
        #pragma unroll
        for (int i = 0; i < 2; ++i)
            #pragma unroll
            for (int j = 0; j < 4; ++j)
                acc[i][j] = __builtin_amdgcn_mfma_f32_16x16x32_bf16(a[i], b[j], acc[i][j], 0, 0, 0);
        __syncthreads();   // drains vmcnt(0): next buffer ready for all waves
        cur ^= 1;
    }

    float*    Cf  = (float*)Cv + bz * sC;
    ushort_t* Cb  = (ushort_t*)Cv + bz * sC;
    ushort_t* Cb2 = C2 ? C2 + bz * sC : nullptr;
    const float* R = Res ? Res + bz * sRes : nullptr;

    #pragma unroll
    for (int i = 0; i < 2; ++i) {
        #pragma unroll
        for (int j = 0; j < 4; ++j) {
            #pragma unroll
            for (int r = 0; r < 4; ++r) {
                int gm = m0 + wr * 32 + i * 16 + (lane >> 4) * 4 + r;
                int gn = n0 + wc * 64 + j * 16 + (lane & 15);
                float v = acc[i][j][r];
                long idx = (long)gm * ldc + gn;
                if (EPI == ME_F32)               Cf[idx] = v;
                else if (EPI == ME_BF16)         Cb[idx] = f2b(v);
                else if (EPI == ME_BIASROW_BF16) Cb[idx] = f2b(v + bias[gm]);
                else if (EPI == ME_BIASCOL_DUAL) {
                    float vv = v + bias[gn];
                    Cf[idx] = vv; Cb2[idx] = f2b(vv);
                }
                else if (EPI == ME_BIASCOL_ACC_F32) Cf[idx] += v + bias[gn];
                else if (EPI == ME_GELU_BF16)    Cb[idx] = f2b(gelu_exact(v));
                else if (EPI == ME_RES_F32)      Cf[idx] = v + R[(long)gm * ldres + gn];
                else if (EPI == ME_TREND) { if (gm < 96) Cf[idx] = v + bias[gm]; }
            }
        }
    }
}

// ---------------- batched complex mode-mix MFMA (per h,m) ------------------
__global__ __launch_bounds__(256)
void fmix_k(const ushort_t* __restrict__ A2, const ushort_t* __restrict__ B2,
            ushort_t* __restrict__ OS)
{
    const int hm = blockIdx.x;
    const int h = hm >> 6, m = hm & 63;
    __shared__ __align__(16) ushort_t As[32 * 128];
    __shared__ __align__(16) ushort_t Bs[128 * 128];

    const int tid = threadIdx.x;
    const int w = tid >> 6, lane = tid & 63;

    const ushort_t* Ag = A2 + (long)hm * 4096;
    const ushort_t* Bg = B2 + (long)hm * 16384;
    #pragma unroll
    for (int r = 0; r < 2; ++r)
        __builtin_amdgcn_global_load_lds(GCAST(Ag + w * 1024 + r * 512 + lane * 8),
                                         LCAST(As + w * 1024 + r * 512), 16, 0, 0);
    #pragma unroll
    for (int r = 0; r < 8; ++r)
        __builtin_amdgcn_global_load_lds(GCAST(Bg + w * 4096 + r * 512 + lane * 8),
                                         LCAST(Bs + w * 4096 + r * 512), 16, 0, 0);
    __syncthreads();

    f32x4_t acc[2][2] = {};
    const int kg = (lane >> 4) * 8;
    #pragma unroll
    for (int kk = 0; kk < 4; ++kk) {
        bf16x8_t a[2], b[2];
        #pragma unroll
        for (int i = 0; i < 2; ++i)
            a[i] = *(const bf16x8_t*)&As[(i * 16 + (lane & 15)) * 128 + kk * 32 + kg];
        #pragma unroll
        for (int j = 0; j < 2; ++j)
            b[j] = *(const bf16x8_t*)&Bs[(w * 32 + j * 16 + (lane & 15)) * 128 + kk * 32 + kg];
        #pragma unroll
        for (int i = 0; i < 2; ++i)
            #pragma unroll
            for (int j = 0; j < 2; ++j)
                acc[i][j] = __builtin_amdgcn_mfma_f32_16x16x32_bf16(a[i], b[j], acc[i][j], 0, 0, 0);
    }

    #pragma unroll
    for (int i = 0; i < 2; ++i) {
        #pragma unroll
        for (int j = 0; j < 2; ++j) {
            #pragma unroll
            for (int r = 0; r < 4; ++r) {
                int b = i * 16 + (lane >> 4) * 4 + r;
                int n2 = w * 32 + j * 16 + (lane & 15);
                int o = n2 & 63, ri = n2 >> 6;
                OS[((long)b * 512 + h * 64 + o) * 128 + ri * 64 + m] = f2b(acc[i][j][r]);
            }
        }
    }
}

// B2 prep: block per (h,o). Fr/Fi [h][i][o][m] f32 -> B2[h][m][n2][k2] bf16
__global__ __launch_bounds__(256)
void bprep_k(const float* __restrict__ FR, const float* __restrict__ FI,
             ushort_t* __restrict__ B2)
{
    const int bx = blockIdx.x;
    const int h = bx >> 6, o = bx & 63;
    __shared__ float fr_s[64][65];
    __shared__ float fi_s[64][65];
    for (int e = threadIdx.x; e < 4096; e += 256) {
        int i = e >> 6, m = e & 63;
        long src = ((long)(h * 64 + i) * 64 + o) * 64 + m;
        fr_s[i][m] = FR[src];
        fi_s[i][m] = FI[src];
    }
    __syncthreads();
    const int m = threadIdx.x & 63;
    const int kq = threadIdx.x >> 6;
    ushort_t* b0 = B2 + ((long)(h * 64 + m) * 128 + o) * 128;
    ushort_t* b1 = B2 + ((long)(h * 64 + m) * 128 + o + 64) * 128;
    for (int kk = 0; kk < 32; ++kk) {
        int k2 = kq * 32 + kk;
        int ik = k2 & 63, hi = k2 >> 6;
        float fr = fr_s[ik][m], fi = fi_s[ik][m];
        b0[k2] = f2b(hi ? -fi : fr);
        b1[k2] = f2b(hi ?  fr : fi);
    }
}

// A2 prep: block per (b,h). XFT [b][c=h*64+i][mp] f32 -> A2[h][m][b][k2] bf16
__global__ __launch_bounds__(256)
void aprep_k(const float* __restrict__ XFT, ushort_t* __restrict__ A2)
{
    const int bx = blockIdx.x;
    const int b = bx >> 3, h = bx & 7;
    __shared__ float xs[64][129];
    for (int e = threadIdx.x; e < 8192; e += 256) {
        int i = e >> 7, mp = e & 127;
        xs[i][mp] = XFT[((long)b * 512 + h * 64 + i) * 128 + mp];
    }
    __syncthreads();
    const int m = threadIdx.x & 63;
    const int kq = threadIdx.x >> 6;
    ushort_t* dst = A2 + ((long)(h * 64 + m) * 32 + b) * 128;
    for (int kk = 0; kk < 32; ++kk) {
        int k2 = kq * 32 + kk;
        int i = k2 & 63, ri = k2 >> 6;
        dst[k2] = f2b(xs[i][ri * 64 + m]);
    }
}

// ------------- sliding-window series_decomp (k=25), dual output ------------
__global__ __launch_bounds__(256)
void decomp2_k(const float* __restrict__ X, float* __restrict__ S,
               ushort_t* __restrict__ Sb, float* __restrict__ Tr)
{
    const int id = blockIdx.x;
    const int ch = id & 1, rc = (id >> 1) & 31, b = id >> 6;
    const int c = ch * 256 + threadIdx.x;
    const int r0 = rc * 16;
    const long base = ((long)b << 18) + c;
    float s = 0.f;
    #pragma unroll
    for (int j = -12; j <= 12; ++j) {
        int rr = r0 + j; rr = rr < 0 ? 0 : (rr > 511 ? 511 : rr);
        s += X[base + ((long)rr << 9)];
    }
    for (int rr = 0; rr < 16; ++rr) {
        int r = r0 + rr;
        float mean = s * (1.f / 25.f);
        long idx = base + ((long)r << 9);
        float x = X[idx];
        if (S)  S[idx] = x - mean;
        if (Sb) Sb[idx] = f2b(x - mean);
        if (Tr) Tr[idx] = mean;
        int rp = r + 13; rp = rp > 511 ? 511 : rp;
        int rm = r - 12; rm = rm < 0 ? 0 : rm;
        s += X[base + ((long)rp << 9)] - X[base + ((long)rm << 9)];
    }
}

// ----------------------- bf16 DFT tables ([N,K] layouts) -------------------
__global__ __launch_bounds__(256)
void init_tables_k(ushort_t* __restrict__ TFb, ushort_t* __restrict__ TIb)
{
    int t = blockIdx.x * 256 + threadIdx.x;   // 0..131071
    const float w = 6.283185307179586f / 512.f;
    if (t < 65536) {
        int mp = t >> 9, n = t & 511;
        int m = mp & 63;
        float ang = ((m * n) & 511) * w;
        TFb[t] = f2b((mp < 64) ? cosf(ang) : -sinf(ang));
    } else {
        int u = t - 65536;
        int n = u >> 7, mp = u & 127;
        int m = mp & 63;
        float ang = ((m * n) & 511) * w;
        float v;
        if (mp < 64) v = (m == 0) ? (1.f / 512.f) : (2.f / 512.f) * cosf(ang);
        else         v = (m == 0) ? 0.f : -(2.f / 512.f) * sinf(ang);
        TIb[u] = f2b(v);
    }
}

// ----------------------- fp32 -> bf16 convert (weights) --------------------
__global__ __launch_bounds__(256)
void f2b_k(const float* __restrict__ X, ushort_t* __restrict__ Y, long n)
{
    long i = ((long)blockIdx.x * 256 + threadIdx.x) * 8;
    if (i >= n) return;
    const float4* xp = (const float4*)(X + i);
    float4 v0 = xp[0], v1 = xp[1];
    u16x8_t o;
    o[0] = f2b(v0.x); o[1] = f2b(v0.y); o[2] = f2b(v0.z); o[3] = f2b(v0.w);
    o[4] = f2b(v1.x); o[5] = f2b(v1.y); o[6] = f2b(v1.z); o[7] = f2b(v1.w);
    *(u16x8_t*)(Y + i) = o;
}

// ----------------- fp32 [R,C] -> bf16 transposed [C,R] ---------------------
__global__ __launch_bounds__(256)
void trans_b_k(const float* __restrict__ X, ushort_t* __restrict__ Y,
               int R, int C, long sX, long sY)
{
    __shared__ float t[32][33];
    X += (long)blockIdx.z * sX;
    Y += (long)blockIdx.z * sY;
    int r0 = blockIdx.y * 32, c0 = blockIdx.x * 32;
    int tx = threadIdx.x & 31, ty = threadIdx.x >> 5;
    #pragma unroll
    for (int i = ty; i < 32; i += 8)
        t[i][tx] = X[(long)(r0 + i) * C + c0 + tx];
    __syncthreads();
    #pragma unroll
    for (int i = ty; i < 32; i += 8)
        Y[(long)(c0 + i) * R + r0 + tx] = f2b(t[tx][i]);
}

// ------------------------------ layernorm ----------------------------------
__global__ __launch_bounds__(256)
void ln_rows_k(const float* __restrict__ X, const float* __restrict__ g,
               const float* __restrict__ bta, float* __restrict__ Y)
{
    int wave = threadIdx.x >> 6, lane = threadIdx.x & 63;
    long row = (long)blockIdx.x * 4 + wave;
    const float* x = X + row * 512;
    float s = 0.f, ss = 0.f;
    for (int d = lane; d < 512; d += 64) { float v = x[d]; s += v; ss += v * v; }
    #pragma unroll
    for (int o = 32; o; o >>= 1) { s += __shfl_xor(s, o); ss += __shfl_xor(ss, o); }
    float mu = s * (1.f / 512.f);
    float var = ss * (1.f / 512.f) - mu * mu;
    float inv = rsqrtf(var + 1e-5f);
    float* y = Y + row * 512;
    for (int d = lane; d < 512; d += 64)
        y[d] = (x[d] - mu) * inv * g[d] + bta[d];
}

// subtract per-(b,d) seq-mean, emit bf16
__global__ __launch_bounds__(64)
void colmean_b16_k(const float* __restrict__ Y, ushort_t* __restrict__ O)
{
    int b = blockIdx.x, dg = blockIdx.y;
    int d = dg * 64 + threadIdx.x;
    long base = (long)b * 262144 + d;
    float s = 0.f;
    for (int t = 0; t < 512; ++t) s += Y[base + ((long)t << 9)];
    float mean = s * (1.f / 512.f);
    for (int t = 0; t < 512; ++t)
        O[base + ((long)t << 9)] = f2b(Y[base + ((long)t << 9)] - mean);
}

// head transpose-add: out[b,p,t] += Thead[(b*512+t)*128+p] + b_head[p]
__global__ __launch_bounds__(256)
void headadd_k(const float* __restrict__ Th, const float* __restrict__ bh,
               float* __restrict__ out)
{
    const int id = blockIdx.x;          // b*16 + tc
    const int b = id >> 4, t0 = (id & 15) * 32;
    __shared__ float tile[32][100];
    for (int e = threadIdx.x; e < 32 * 96; e += 256) {
        int tl = e / 96, p = e - tl * 96;
        tile[tl][p] = Th[((long)(b * 512 + t0 + tl)) * 128 + p];
    }
    __syncthreads();
    for (int e = threadIdx.x; e < 96 * 32; e += 256) {
        int p = e >> 5, tl = e & 31;
        out[(long)b * 49152 + p * 512 + t0 + tl] += tile[tl][p] + bh[p];
    }
}

// ===========================================================================
extern "C" void kernel_launch(void* const* d_in, const int* in_sizes, int n_in,
                              void* d_out, int out_size, void* d_ws, size_t ws_size,
                              hipStream_t stream)
{
    const float* x_enc   = (const float*)d_in[0];
    const float* W_trend = (const float*)d_in[4];
    const float* b_trend = (const float*)d_in[5];
    const float* W_emb   = (const float*)d_in[6];
    const float* b_emb   = (const float*)d_in[7];
    const float* Wq      = (const float*)d_in[8];
    const float* bq      = (const float*)d_in[9];
    const float* fw_r    = (const float*)d_in[14];
    const float* fw_i    = (const float*)d_in[15];
    const float* Wo      = (const float*)d_in[16];
    const float* bo      = (const float*)d_in[17];
    const float* W1      = (const float*)d_in[18];
    const float* W2      = (const float*)d_in[19];
    const float* ln_g    = (const float*)d_in[20];
    const float* ln_b    = (const float*)d_in[21];
    const float* W_head  = (const float*)d_in[22];
    const float* b_head  = (const float*)d_in[23];
    float* out = (float*)d_out;
    float* ws  = (float*)d_ws;

    const long F = 8388608;
    float* G    = ws;
    float* bufB = ws + 2 * F;
    float* X    = ws + 3 * F;
    float* T1   = ws + 4 * F;
    ushort_t* qT = (ushort_t*)(ws + 5 * F);
    ushort_t* xb = qT + 8388608;

    float*    XFT   = G;
    ushort_t* A2    = (ushort_t*)(G + 2097152);
    ushort_t* OSELb = (ushort_t*)(G + 3145728);
    ushort_t* xtb   = (ushort_t*)(G + 4194304);
    ushort_t* B2    = (ushort_t*)(G + 8388608);
    float*    trend = G;
    float*    Thead = G;
    ushort_t* gb    = (ushort_t*)G;

    ushort_t* WembT  = (ushort_t*)(ws + 6 * F);
    ushort_t* WTq    = WembT + 262144;
    ushort_t* WTo    = WTq + 262144;
    ushort_t* W1b    = WTo + 262144;
    ushort_t* W2b    = W1b + 1048576;
    ushort_t* TFb    = W2b + 1048576;
    ushort_t* TIb    = TFb + 65536;
    ushort_t* WtT    = TIb + 65536;
    ushort_t* WheadT = WtT + 65536;

    dim3 blk(256), blk5(512);

    init_tables_k<<<dim3(512), blk, 0, stream>>>(TFb, TIb);

    decomp2_k<<<dim3(2048), blk, 0, stream>>>(x_enc, bufB, nullptr, trend);

    trans_b_k<<<dim3(3, 16, 1), blk, 0, stream>>>(W_trend, WtT, 512, 96, 0L, 0L);
    trans_b_k<<<dim3(3, 16, 1), blk, 0, stream>>>(W_head, WheadT, 512, 96, 0L, 0L);
    trans_b_k<<<dim3(16, 16, 1), blk, 0, stream>>>(W_emb, WembT, 512, 512, 0L, 0L);

    trans_b_k<<<dim3(16, 16, 32), blk, 0, stream>>>(trend, qT, 512, 512, 262144L, 262144L);
    mgemm_k<ME_TREND><<<dim3(4, 1, 32), blk5, 0, stream>>>(
        WtT, qT, b_trend, nullptr, out, nullptr,
        128, 512, 512, 512, 0, 0L, 262144L, 49152L, 0L);

    trans_b_k<<<dim3(16, 16, 32), blk, 0, stream>>>(bufB, qT, 512, 512, 262144L, 262144L);
    mgemm_k<ME_BIASCOL_DUAL><<<dim3(4, 4, 32), blk5, 0, stream>>>(
        qT, WembT, b_emb, nullptr, X, xb,
        512, 512, 512, 512, 0, 262144L, 0L, 262144L, 0L);

    for (int l = 0; l < 2; ++l) {
        const float* Wq_l = Wq + (long)l * 262144;
        const float* bq_l = bq + (long)l * 512;
        const float* Wo_l = Wo + (long)l * 262144;
        const float* bo_l = bo + (long)l * 512;
        const float* W1_l = W1 + (long)l * 1048576;
        const float* W2_l = W2 + (long)l * 1048576;
        const float* fr_l = fw_r + (long)l * 2097152;
        const float* fi_l = fw_i + (long)l * 2097152;

        trans_b_k<<<dim3(16, 16, 1), blk, 0, stream>>>(Wq_l, WTq, 512, 512, 0L, 0L);
        trans_b_k<<<dim3(16, 16, 1), blk, 0, stream>>>(Wo_l, WTo, 512, 512, 0L, 0L);
        f2b_k<<<dim3(512), blk, 0, stream>>>(W1_l, W1b, 1048576L);
        f2b_k<<<dim3(512), blk, 0, stream>>>(W2_l, W2b, 1048576L);
        bprep_k<<<dim3(512), blk, 0, stream>>>(fr_l, fi_l, B2);

        // qT[b,c,n] = WTq[c,:] . X[b,n,:] + bq[c]
        mgemm_k<ME_BIASROW_BF16><<<dim3(4, 4, 32), blk5, 0, stream>>>(
            WTq, xb, bq_l, nullptr, qT, nullptr,
            512, 512, 512, 512, 0, 0L, 262144L, 262144L, 0L);

        // XFT[b,c,mp] = qT[b,c,:] . TFb[mp,:]
        mgemm_k<ME_F32><<<dim3(1, 4, 32), blk5, 0, stream>>>(
            qT, TFb, nullptr, nullptr, XFT, nullptr,
            512, 128, 512, 128, 0, 262144L, 0L, 65536L, 0L);

        aprep_k<<<dim3(256), blk, 0, stream>>>(XFT, A2);
        fmix_k<<<dim3(512), blk, 0, stream>>>(A2, B2, OSELb);

        // xtb[(b,c),n] = OSELb[(b,c),:] . TIb[n,:]
        mgemm_k<ME_BF16><<<dim3(4, 128, 1), blk5, 0, stream>>>(
            OSELb, TIb, nullptr, nullptr, xtb, nullptr,
            16384, 512, 128, 512, 0, 0L, 0L, 0L, 0L);

        // X += xtb . WTo^T + bo
        mgemm_k<ME_BIASCOL_ACC_F32><<<dim3(4, 128, 1), blk5, 0, stream>>>(
            xtb, WTo, bo_l, nullptr, X, nullptr,
            16384, 512, 512, 512, 0, 0L, 0L, 0L, 0L);

        decomp2_k<<<dim3(2048), blk, 0, stream>>>(X, bufB, xb, nullptr);

        // FFN, full M=16384
        mgemm_k<ME_GELU_BF16><<<dim3(16, 128, 1), blk5, 0, stream>>>(
            xb, W1b, nullptr, nullptr, gb, nullptr,
            16384, 2048, 512, 2048, 0, 0L, 0L, 0L, 0L);
        mgemm_k<ME_RES_F32><<<dim3(4, 128, 1), blk5, 0, stream>>>(
            gb, W2b, nullptr, bufB, T1, nullptr,
            16384, 512, 2048, 512, 512, 0L, 0L, 0L, 0L);

        decomp2_k<<<dim3(2048), blk, 0, stream>>>(T1, X, xb, nullptr);
    }

    ln_rows_k<<<dim3(4096), blk, 0, stream>>>(X, ln_g, ln_b, T1);
    colmean_b16_k<<<dim3(32, 8), dim3(64), 0, stream>>>(T1, xb);

    mgemm_k<ME_F32><<<dim3(1, 128, 1), blk5, 0, stream>>>(
        xb, WheadT, nullptr, nullptr, Thead, nullptr,
        16384, 128, 512, 128, 0, 0L, 0L, 0L, 0L);

    headadd_k<<<dim3(512), blk, 0, stream>>>(Thead, b_head, out);
}

// Round 6
// 738.911 us; speedup vs baseline: 6.4999x; 1.0171x over previous
//
#include <hip/hip_runtime.h>
#include <math.h>

// ---------------------------------------------------------------------------
// Model_24180665876772  Round 6: algebraic folding of the Fourier branch.
//   XFT = Wq^T (X^T TF)  (two 4.3GF GEMMs replace 21.5GF; bq -> DC column)
//   X  += OSEL (TI Wo) + bo  (one K=128 GEMM replaces irfft GEMM + Wo GEMM)
// ---------------------------------------------------------------------------

typedef unsigned short ushort_t;
typedef unsigned int uint_t;
using bf16x8_t = __attribute__((ext_vector_type(8))) short;
using f32x4_t  = __attribute__((ext_vector_type(4))) float;
using u16x8_t  = __attribute__((ext_vector_type(8))) unsigned short;

__device__ __forceinline__ unsigned short f2b(float x) {
    union { float f; uint_t u; } c; c.f = x;
    uint_t r = c.u + 0x7fffu + ((c.u >> 16) & 1u);   // RNE
    return (unsigned short)(r >> 16);
}
__device__ __forceinline__ float b2f(unsigned short h) {
    union { uint_t u; float f; } c; c.u = ((uint_t)h) << 16; return c.f;
}
__device__ __forceinline__ float gelu_exact(float v) {
    return 0.5f * v * (1.0f + erff(v * 0.70710678118654752f));
}

#define GCAST(p) ((const __attribute__((address_space(1))) void*)(p))
#define LCAST(p) ((__attribute__((address_space(3))) void*)(p))

// ------------------------- bf16 MFMA GEMM ---------------------------------
// C[m,n] = sum_k A[m,k]*B[n,k]  (A: [M,K] bf16 row-major, B: [N,K] bf16 row-major)
// 128x128 tile, BK=32, 8 waves of 32x64, double-buffered LDS, 1 barrier/K-step.
enum { ME_F32 = 0, ME_BF16, ME_DCBIAS_BF16, ME_BIASCOL_DUAL,
       ME_BIASCOL_ACC_F32, ME_GELU_BF16, ME_RESB_F32, ME_TREND };

template<int EPI>
__global__ __launch_bounds__(512)
void mgemm_k(const ushort_t* __restrict__ A, const ushort_t* __restrict__ B,
             const float* __restrict__ bias, const ushort_t* __restrict__ Resb,
             void* __restrict__ Cv, ushort_t* __restrict__ C2,
             int M, int N, int K, int ldc, int ldres,
             long sA, long sB, long sC, long sRes)
{
    // XCD-aware bijective swizzle (identity when nwg % 8 != 0)
    const int gx = gridDim.x, gy = gridDim.y;
    const int nwg = gx * gy * gridDim.z;
    const int lin = (blockIdx.z * gy + blockIdx.y) * gx + blockIdx.x;
    const int cpx = nwg >> 3;
    const int swz = (nwg & 7) ? lin : ((lin & 7) * cpx + (lin >> 3));
    const int bx = swz % gx;
    const int t2 = swz / gx;
    const int by = t2 % gy;
    const int bz = t2 / gy;

    A += bz * sA;
    B += bz * sB;
    const int m0 = by * 128, n0 = bx * 128;

    __shared__ __align__(16) ushort_t As[2][128 * 32];
    __shared__ __align__(16) ushort_t Bs[2][128 * 32];

    const int tid = threadIdx.x;
    const int wave = tid >> 6, lane = tid & 63;
    const int wr = wave >> 1, wc = wave & 1;   // wr 0..3 (rows), wc 0..1 (cols)

    f32x4_t acc[2][4] = {};

    const int srow = tid >> 2;           // 0..127 (tile row staged by this thread)
    const int skof = (tid & 3) * 8;      // k-offset in bf16 elems

    const ushort_t* ga = A + (long)(m0 + srow) * K + skof;
    const ushort_t* gb = B + (long)(n0 + srow) * K + skof;

    __builtin_amdgcn_global_load_lds(GCAST(ga), LCAST(As[0] + wave * 512), 16, 0, 0);
    __builtin_amdgcn_global_load_lds(GCAST(gb), LCAST(Bs[0] + wave * 512), 16, 0, 0);
    __syncthreads();

    const int nt = K >> 5;
    int cur = 0;
    const int kg = (lane >> 4) * 8;

    for (int t = 0; t < nt; ++t) {
        if (t + 1 < nt) {
            const long ko = (long)(t + 1) << 5;
            __builtin_amdgcn_global_load_lds(GCAST(ga + ko), LCAST(As[cur ^ 1] + wave * 512), 16, 0, 0);
            __builtin_amdgcn_global_load_lds(GCAST(gb + ko), LCAST(Bs[cur ^ 1] + wave * 512), 16, 0, 0);
        }
        bf16x8_t a[2], b[4];
        #pragma unroll
        for (int i = 0; i < 2; ++i)
            a[i] = *(const bf16x8_t*)&As[cur][(wr * 32 + i * 16 + (lane & 15)) * 32 + kg];
        #pragma unroll
        for (int j = 0; j < 4; ++j)
            b[j] = *(const bf16x8_t*)&Bs[cur][(wc * 64 + j * 16 + (lane & 15)) * 32 + kg];
        #pragma unroll
        for (int i = 0; i < 2; ++i)
            #pragma unroll
            for (int j = 0; j < 4; ++j)
                acc[i][j] = __builtin_amdgcn_mfma_f32_16x16x32_bf16(a[i], b[j], acc[i][j], 0, 0, 0);
        __syncthreads();
        cur ^= 1;
    }

    float*    Cf  = (float*)Cv + bz * sC;
    ushort_t* Cb  = (ushort_t*)Cv + bz * sC;
    ushort_t* Cb2 = C2 ? C2 + bz * sC : nullptr;
    const ushort_t* R = Resb ? Resb + bz * sRes : nullptr;

    #pragma unroll
    for (int i = 0; i < 2; ++i) {
        #pragma unroll
        for (int j = 0; j < 4; ++j) {
            #pragma unroll
            for (int r = 0; r < 4; ++r) {
                int gm = m0 + wr * 32 + i * 16 + (lane >> 4) * 4 + r;
                int gn = n0 + wc * 64 + j * 16 + (lane & 15);
                float v = acc[i][j][r];
                long idx = (long)gm * ldc + gn;
                if (EPI == ME_F32)               Cf[idx] = v;
                else if (EPI == ME_BF16)         Cb[idx] = f2b(v);
                else if (EPI == ME_DCBIAS_BF16)  Cb[idx] = f2b(v + (gn == 0 ? 512.f * bias[gm] : 0.f));
                else if (EPI == ME_BIASCOL_DUAL) {
                    float vv = v + bias[gn];
                    Cf[idx] = vv; Cb2[idx] = f2b(vv);
                }
                else if (EPI == ME_BIASCOL_ACC_F32) Cf[idx] += v + bias[gn];
                else if (EPI == ME_GELU_BF16)    Cb[idx] = f2b(gelu_exact(v));
                else if (EPI == ME_RESB_F32)     Cf[idx] = v + b2f(R[(long)gm * ldres + gn]);
                else if (EPI == ME_TREND) { if (gm < 96) Cf[idx] = v + bias[gm]; }
            }
        }
    }
}

// ---------------- batched complex mode-mix MFMA (per h,m) ------------------
__global__ __launch_bounds__(256)
void fmix_k(const ushort_t* __restrict__ A2, const ushort_t* __restrict__ B2,
            ushort_t* __restrict__ OS)
{
    const int hm = blockIdx.x;
    const int h = hm >> 6, m = hm & 63;
    __shared__ __align__(16) ushort_t As[32 * 128];
    __shared__ __align__(16) ushort_t Bs[128 * 128];

    const int tid = threadIdx.x;
    const int w = tid >> 6, lane = tid & 63;

    const ushort_t* Ag = A2 + (long)hm * 4096;
    const ushort_t* Bg = B2 + (long)hm * 16384;
    #pragma unroll
    for (int r = 0; r < 2; ++r)
        __builtin_amdgcn_global_load_lds(GCAST(Ag + w * 1024 + r * 512 + lane * 8),
                                         LCAST(As + w * 1024 + r * 512), 16, 0, 0);
    #pragma unroll
    for (int r = 0; r < 8; ++r)
        __builtin_amdgcn_global_load_lds(GCAST(Bg + w * 4096 + r * 512 + lane * 8),
                                         LCAST(Bs + w * 4096 + r * 512), 16, 0, 0);
    __syncthreads();

    f32x4_t acc[2][2] = {};
    const int kg = (lane >> 4) * 8;
    #pragma unroll
    for (int kk = 0; kk < 4; ++kk) {
        bf16x8_t a[2], b[2];
        #pragma unroll
        for (int i = 0; i < 2; ++i)
            a[i] = *(const bf16x8_t*)&As[(i * 16 + (lane & 15)) * 128 + kk * 32 + kg];
        #pragma unroll
        for (int j = 0; j < 2; ++j)
            b[j] = *(const bf16x8_t*)&Bs[(w * 32 + j * 16 + (lane & 15)) * 128 + kk * 32 + kg];
        #pragma unroll
        for (int i = 0; i < 2; ++i)
            #pragma unroll
            for (int j = 0; j < 2; ++j)
                acc[i][j] = __builtin_amdgcn_mfma_f32_16x16x32_bf16(a[i], b[j], acc[i][j], 0, 0, 0);
    }

    #pragma unroll
    for (int i = 0; i < 2; ++i) {
        #pragma unroll
        for (int j = 0; j < 2; ++j) {
            #pragma unroll
            for (int r = 0; r < 4; ++r) {
                int b = i * 16 + (lane >> 4) * 4 + r;
                int n2 = w * 32 + j * 16 + (lane & 15);
                int o = n2 & 63, ri = n2 >> 6;
                OS[((long)b * 512 + h * 64 + o) * 128 + ri * 64 + m] = f2b(acc[i][j][r]);
            }
        }
    }
}

// B2 prep: block per (h,o). Fr/Fi [h][i][o][m] f32 -> B2[h][m][n2][k2] bf16
__global__ __launch_bounds__(256)
void bprep_k(const float* __restrict__ FR, const float* __restrict__ FI,
             ushort_t* __restrict__ B2)
{
    const int bx = blockIdx.x;
    const int h = bx >> 6, o = bx & 63;
    __shared__ float fr_s[64][65];
    __shared__ float fi_s[64][65];
    for (int e = threadIdx.x; e < 4096; e += 256) {
        int i = e >> 6, m = e & 63;
        long src = ((long)(h * 64 + i) * 64 + o) * 64 + m;
        fr_s[i][m] = FR[src];
        fi_s[i][m] = FI[src];
    }
    __syncthreads();
    const int m = threadIdx.x & 63;
    const int kq = threadIdx.x >> 6;
    ushort_t* b0 = B2 + ((long)(h * 64 + m) * 128 + o) * 128;
    ushort_t* b1 = B2 + ((long)(h * 64 + m) * 128 + o + 64) * 128;
    for (int kk = 0; kk < 32; ++kk) {
        int k2 = kq * 32 + kk;
        int ik = k2 & 63, hi = k2 >> 6;
        float fr = fr_s[ik][m], fi = fi_s[ik][m];
        b0[k2] = f2b(hi ? -fi : fr);
        b1[k2] = f2b(hi ?  fr : fi);
    }
}

// A2 prep: block per (b,h). XFTb [b][c=h*64+i][mp] bf16 -> A2[h][m][b][k2] bf16
__global__ __launch_bounds__(256)
void aprep_k(const ushort_t* __restrict__ XFTb, ushort_t* __restrict__ A2)
{
    const int bx = blockIdx.x;
    const int b = bx >> 3, h = bx & 7;
    __shared__ ushort_t xs[64][130];
    for (int e = threadIdx.x; e < 8192; e += 256) {
        int i = e >> 7, mp = e & 127;
        xs[i][mp] = XFTb[((long)b * 512 + h * 64 + i) * 128 + mp];
    }
    __syncthreads();
    const int m = threadIdx.x & 63;
    const int kq = threadIdx.x >> 6;
    ushort_t* dst = A2 + ((long)(h * 64 + m) * 32 + b) * 128;
    for (int kk = 0; kk < 32; ++kk) {
        int k2 = kq * 32 + kk;
        int i = k2 & 63, ri = k2 >> 6;
        dst[k2] = xs[i][ri * 64 + m];
    }
}

// ------------- sliding-window series_decomp (k=25), dual output ------------
__global__ __launch_bounds__(256)
void decomp2_k(const float* __restrict__ X, float* __restrict__ S,
               ushort_t* __restrict__ Sb, float* __restrict__ Tr)
{
    const int id = blockIdx.x;
    const int ch = id & 1, rc = (id >> 1) & 31, b = id >> 6;
    const int c = ch * 256 + threadIdx.x;
    const int r0 = rc * 16;
    const long base = ((long)b << 18) + c;
    float s = 0.f;
    #pragma unroll
    for (int j = -12; j <= 12; ++j) {
        int rr = r0 + j; rr = rr < 0 ? 0 : (rr > 511 ? 511 : rr);
        s += X[base + ((long)rr << 9)];
    }
    for (int rr = 0; rr < 16; ++rr) {
        int r = r0 + rr;
        float mean = s * (1.f / 25.f);
        long idx = base + ((long)r << 9);
        float x = X[idx];
        if (S)  S[idx] = x - mean;
        if (Sb) Sb[idx] = f2b(x - mean);
        if (Tr) Tr[idx] = mean;
        int rp = r + 13; rp = rp > 511 ? 511 : rp;
        int rm = r - 12; rm = rm < 0 ? 0 : rm;
        s += X[base + ((long)rp << 9)] - X[base + ((long)rm << 9)];
    }
}

// ----------------------- bf16 DFT tables -----------------------------------
// TFb  [128 mp][512 n]:  mp<64: cos(2pi m n/512); mp>=64: -sin
// TI2b [128 mp][512 n]:  irfft coefs: mp<64: m==0?1/512:(2/512)cos;
//                                     mp>=64: m==0?0:-(2/512)sin
__global__ __launch_bounds__(256)
void init_tables_k(ushort_t* __restrict__ TFb, ushort_t* __restrict__ TI2b)
{
    int t = blockIdx.x * 256 + threadIdx.x;   // 0..131071
    const float w = 6.283185307179586f / 512.f;
    if (t < 65536) {
        int mp = t >> 9, n = t & 511;
        int m = mp & 63;
        float ang = ((m * n) & 511) * w;
        TFb[t] = f2b((mp < 64) ? cosf(ang) : -sinf(ang));
    } else {
        int u = t - 65536;
        int mp = u >> 9, n = u & 511;
        int m = mp & 63;
        float ang = ((m * n) & 511) * w;
        float v;
        if (mp < 64) v = (m == 0) ? (1.f / 512.f) : (2.f / 512.f) * cosf(ang);
        else         v = (m == 0) ? 0.f : -(2.f / 512.f) * sinf(ang);
        TI2b[u] = f2b(v);
    }
}

// ----------------------- fp32 -> bf16 convert (weights) --------------------
__global__ __launch_bounds__(256)
void f2b_k(const float* __restrict__ X, ushort_t* __restrict__ Y, long n)
{
    long i = ((long)blockIdx.x * 256 + threadIdx.x) * 8;
    if (i >= n) return;
    const float4* xp = (const float4*)(X + i);
    float4 v0 = xp[0], v1 = xp[1];
    u16x8_t o;
    o[0] = f2b(v0.x); o[1] = f2b(v0.y); o[2] = f2b(v0.z); o[3] = f2b(v0.w);
    o[4] = f2b(v1.x); o[5] = f2b(v1.y); o[6] = f2b(v1.z); o[7] = f2b(v1.w);
    *(u16x8_t*)(Y + i) = o;
}

// ----------------- fp32 [R,C] -> bf16 transposed [C,R] ---------------------
__global__ __launch_bounds__(256)
void trans_b_k(const float* __restrict__ X, ushort_t* __restrict__ Y,
               int R, int C, long sX, long sY)
{
    __shared__ float t[32][33];
    X += (long)blockIdx.z * sX;
    Y += (long)blockIdx.z * sY;
    int r0 = blockIdx.y * 32, c0 = blockIdx.x * 32;
    int tx = threadIdx.x & 31, ty = threadIdx.x >> 5;
    #pragma unroll
    for (int i = ty; i < 32; i += 8)
        t[i][tx] = X[(long)(r0 + i) * C + c0 + tx];
    __syncthreads();
    #pragma unroll
    for (int i = ty; i < 32; i += 8)
        Y[(long)(c0 + i) * R + r0 + tx] = f2b(t[tx][i]);
}

// ------------------------------ layernorm ----------------------------------
__global__ __launch_bounds__(256)
void ln_rows_k(const float* __restrict__ X, const float* __restrict__ g,
               const float* __restrict__ bta, float* __restrict__ Y)
{
    int wave = threadIdx.x >> 6, lane = threadIdx.x & 63;
    long row = (long)blockIdx.x * 4 + wave;
    const float* x = X + row * 512;
    float s = 0.f, ss = 0.f;
    for (int d = lane; d < 512; d += 64) { float v = x[d]; s += v; ss += v * v; }
    #pragma unroll
    for (int o = 32; o; o >>= 1) { s += __shfl_xor(s, o); ss += __shfl_xor(ss, o); }
    float mu = s * (1.f / 512.f);
    float var = ss * (1.f / 512.f) - mu * mu;
    float inv = rsqrtf(var + 1e-5f);
    float* y = Y + row * 512;
    for (int d = lane; d < 512; d += 64)
        y[d] = (x[d] - mu) * inv * g[d] + bta[d];
}

// subtract per-(b,d) seq-mean, emit bf16
__global__ __launch_bounds__(64)
void colmean_b16_k(const float* __restrict__ Y, ushort_t* __restrict__ O)
{
    int b = blockIdx.x, dg = blockIdx.y;
    int d = dg * 64 + threadIdx.x;
    long base = (long)b * 262144 + d;
    float s = 0.f;
    for (int t = 0; t < 512; ++t) s += Y[base + ((long)t << 9)];
    float mean = s * (1.f / 512.f);
    for (int t = 0; t < 512; ++t)
        O[base + ((long)t << 9)] = f2b(Y[base + ((long)t << 9)] - mean);
}

// head transpose-add: out[b,p,t] += Thead[(b*512+t)*128+p] + b_head[p]
__global__ __launch_bounds__(256)
void headadd_k(const float* __restrict__ Th, const float* __restrict__ bh,
               float* __restrict__ out)
{
    const int id = blockIdx.x;          // b*16 + tc
    const int b = id >> 4, t0 = (id & 15) * 32;
    __shared__ float tile[32][100];
    for (int e = threadIdx.x; e < 32 * 96; e += 256) {
        int tl = e / 96, p = e - tl * 96;
        tile[tl][p] = Th[((long)(b * 512 + t0 + tl)) * 128 + p];
    }
    __syncthreads();
    for (int e = threadIdx.x; e < 96 * 32; e += 256) {
        int p = e >> 5, tl = e & 31;
        out[(long)b * 49152 + p * 512 + t0 + tl] += tile[tl][p] + bh[p];
    }
}

// ===========================================================================
extern "C" void kernel_launch(void* const* d_in, const int* in_sizes, int n_in,
                              void* d_out, int out_size, void* d_ws, size_t ws_size,
                              hipStream_t stream)
{
    const float* x_enc   = (const float*)d_in[0];
    const float* W_trend = (const float*)d_in[4];
    const float* b_trend = (const float*)d_in[5];
    const float* W_emb   = (const float*)d_in[6];
    const float* b_emb   = (const float*)d_in[7];
    const float* Wq      = (const float*)d_in[8];
    const float* bq      = (const float*)d_in[9];
    const float* fw_r    = (const float*)d_in[14];
    const float* fw_i    = (const float*)d_in[15];
    const float* Wo      = (const float*)d_in[16];
    const float* bo      = (const float*)d_in[17];
    const float* W1      = (const float*)d_in[18];
    const float* W2      = (const float*)d_in[19];
    const float* ln_g    = (const float*)d_in[20];
    const float* ln_b    = (const float*)d_in[21];
    const float* W_head  = (const float*)d_in[22];
    const float* b_head  = (const float*)d_in[23];
    float* out = (float*)d_out;
    float* ws  = (float*)d_ws;

    const long F = 8388608;
    // [0..2F)   G: phase-overlaid scratch
    // [2F..3F)  bufB f32 (decomp seasonal)
    // [3F..4F)  X f32 (encoder state)
    // [4F..5F)  T1 f32 (FFN out / LN out)
    // [5F..6F)  qT bf16 (trendT/seasonalT) + xb bf16
    // [6F..)    weights bf16
    float* G    = ws;
    float* bufB = ws + 2 * F;
    float* X    = ws + 3 * F;
    float* T1   = ws + 4 * F;
    ushort_t* qT = (ushort_t*)(ws + 5 * F);
    ushort_t* xb = qT + 8388608;

    // attn-phase overlays in G
    ushort_t* XFTb  = (ushort_t*)G;                    // [B,512,128] bf16 (then Yb after)
    ushort_t* Yb    = (ushort_t*)(G + 1048576);        // [B,128,512] bf16
    ushort_t* A2    = (ushort_t*)(G + 2097152);        // [8][64][32][128] bf16
    ushort_t* OSELb = (ushort_t*)(G + 3145728);        // [B,512,128] bf16
    ushort_t* xbT   = (ushort_t*)(G + 4194304);        // [B,512d,512n] bf16
    ushort_t* B2    = (ushort_t*)(G + 8388608);        // [8][64][128][128] bf16
    float*    trend = G;                               // start-phase
    float*    Thead = G;                               // end-phase
    ushort_t* gb    = (ushort_t*)G;                    // FFN-phase [16384,2048]

    ushort_t* WembT  = (ushort_t*)(ws + 6 * F);        // [512,512]
    ushort_t* WTq    = WembT + 262144;
    ushort_t* WTo    = WTq + 262144;
    ushort_t* W1b    = WTo + 262144;                   // [2048,512]
    ushort_t* W2b    = W1b + 1048576;                  // [512,2048]
    ushort_t* TFb    = W2b + 1048576;                  // [128,512]
    ushort_t* TI2b   = TFb + 65536;                    // [128,512]
    ushort_t* WtT    = TI2b + 65536;                   // [128,512] rows<96 valid
    ushort_t* WheadT = WtT + 65536;                    // [128,512] rows<96 valid
    ushort_t* TIWob  = WheadT + 65536;                 // [512,128]

    dim3 blk(256), blk5(512);

    init_tables_k<<<dim3(512), blk, 0, stream>>>(TFb, TI2b);

    // decomp(x_enc): bufB = seasonal f32, G = trend f32
    decomp2_k<<<dim3(2048), blk, 0, stream>>>(x_enc, bufB, nullptr, trend);

    trans_b_k<<<dim3(3, 16, 1), blk, 0, stream>>>(W_trend, WtT, 512, 96, 0L, 0L);
    trans_b_k<<<dim3(3, 16, 1), blk, 0, stream>>>(W_head, WheadT, 512, 96, 0L, 0L);
    trans_b_k<<<dim3(16, 16, 1), blk, 0, stream>>>(W_emb, WembT, 512, 512, 0L, 0L);

    // trendT bf16 into qT slot, trend head GEMM -> out
    trans_b_k<<<dim3(16, 16, 32), blk, 0, stream>>>(trend, qT, 512, 512, 262144L, 262144L);
    mgemm_k<ME_TREND><<<dim3(4, 1, 32), blk5, 0, stream>>>(
        WtT, qT, b_trend, nullptr, out, nullptr,
        128, 512, 512, 512, 0, 0L, 262144L, 49152L, 0L);

    // seasonalT bf16 into qT slot; embedding -> X f32 + xb bf16
    trans_b_k<<<dim3(16, 16, 32), blk, 0, stream>>>(bufB, qT, 512, 512, 262144L, 262144L);
    mgemm_k<ME_BIASCOL_DUAL><<<dim3(4, 4, 32), blk5, 0, stream>>>(
        qT, WembT, b_emb, nullptr, X, xb,
        512, 512, 512, 512, 0, 262144L, 0L, 262144L, 0L);

    for (int l = 0; l < 2; ++l) {
        const float* Wq_l = Wq + (long)l * 262144;
        const float* bq_l = bq + (long)l * 512;
        const float* Wo_l = Wo + (long)l * 262144;
        const float* bo_l = bo + (long)l * 512;
        const float* W1_l = W1 + (long)l * 1048576;
        const float* W2_l = W2 + (long)l * 1048576;
        const float* fr_l = fw_r + (long)l * 2097152;
        const float* fi_l = fw_i + (long)l * 2097152;

        // weight prep
        trans_b_k<<<dim3(16, 16, 1), blk, 0, stream>>>(Wq_l, WTq, 512, 512, 0L, 0L);
        trans_b_k<<<dim3(16, 16, 1), blk, 0, stream>>>(Wo_l, WTo, 512, 512, 0L, 0L);
        f2b_k<<<dim3(512), blk, 0, stream>>>(W1_l, W1b, 1048576L);
        f2b_k<<<dim3(512), blk, 0, stream>>>(W2_l, W2b, 1048576L);
        bprep_k<<<dim3(512), blk, 0, stream>>>(fr_l, fi_l, B2);

        // TIWob[d,mp] = sum_n WTo[d,n] * TI2b[mp,n]   (fold irfft into Wo)
        mgemm_k<ME_BF16><<<dim3(1, 4, 1), blk5, 0, stream>>>(
            WTo, TI2b, nullptr, nullptr, TIWob, nullptr,
            512, 128, 512, 128, 0, 0L, 0L, 0L, 0L);

        // xbT[b,d,n] = X[b,n,d]^T (bf16)
        trans_b_k<<<dim3(16, 16, 32), blk, 0, stream>>>(X, xbT, 512, 512, 262144L, 262144L);

        // G1: Yb[b,mp,d] = sum_n TFb[mp,n] * xbT[b,d,n]
        mgemm_k<ME_BF16><<<dim3(4, 1, 32), blk5, 0, stream>>>(
            TFb, xbT, nullptr, nullptr, Yb, nullptr,
            128, 512, 512, 512, 0, 0L, 262144L, 65536L, 0L);

        // G2: XFTb[b,c,mp] = sum_d WTq[c,d] * Yb[b,mp,d]  (+512*bq[c] at mp=0)
        mgemm_k<ME_DCBIAS_BF16><<<dim3(1, 4, 32), blk5, 0, stream>>>(
            WTq, Yb, bq_l, nullptr, XFTb, nullptr,
            512, 128, 512, 128, 0, 0L, 65536L, 65536L, 0L);

        // complex mode mixing
        aprep_k<<<dim3(256), blk, 0, stream>>>(XFTb, A2);
        fmix_k<<<dim3(512), blk, 0, stream>>>(A2, B2, OSELb);

        // X += OSEL . TIWo^T + bo   (irfft+Wo folded, K=128)
        mgemm_k<ME_BIASCOL_ACC_F32><<<dim3(4, 128, 1), blk5, 0, stream>>>(
            OSELb, TIWob, bo_l, nullptr, X, nullptr,
            16384, 512, 128, 512, 0, 0L, 0L, 0L, 0L);

        // decomp -> bufB f32 + xb bf16
        decomp2_k<<<dim3(2048), blk, 0, stream>>>(X, bufB, xb, nullptr);

        // FFN, full M=16384 (gb overlays attn scratch in G)
        mgemm_k<ME_GELU_BF16><<<dim3(16, 128, 1), blk5, 0, stream>>>(
            xb, W1b, nullptr, nullptr, gb, nullptr,
            16384, 2048, 512, 2048, 0, 0L, 0L, 0L, 0L);
        mgemm_k<ME_RESB_F32><<<dim3(4, 128, 1), blk5, 0, stream>>>(
            gb, W2b, nullptr, xb, T1, nullptr,
            16384, 512, 2048, 512, 512, 0L, 0L, 0L, 0L);

        // decomp -> X f32 + xb bf16 (next layer / LN input)
        decomp2_k<<<dim3(2048), blk, 0, stream>>>(T1, X, xb, nullptr);
    }

    // my_layernorm
    ln_rows_k<<<dim3(4096), blk, 0, stream>>>(X, ln_g, ln_b, T1);
    colmean_b16_k<<<dim3(32, 8), dim3(64), 0, stream>>>(T1, xb);

    // head
    mgemm_k<ME_F32><<<dim3(1, 128, 1), blk5, 0, stream>>>(
        xb, WheadT, nullptr, nullptr, Thead, nullptr,
        16384, 128, 512, 128, 0, 0L, 0L, 0L, 0L);

    headadd_k<<<dim3(512), blk, 0, stream>>>(Thead, b_head, out);
}

// Round 8
// 711.392 us; speedup vs baseline: 6.7514x; 1.0387x over previous
//
#include <hip/hip_runtime.h>
#include <math.h>

// ---------------------------------------------------------------------------
// Model_24180665876772  Round 8: fix workspace overlay bug from R7 (trendb/
// seasb aliased over [8MB,16MB) of G). Pipeline + memory diet retained.
// ---------------------------------------------------------------------------

typedef unsigned short ushort_t;
typedef unsigned int uint_t;
using bf16x8_t = __attribute__((ext_vector_type(8))) short;
using f32x4_t  = __attribute__((ext_vector_type(4))) float;
using u16x8_t  = __attribute__((ext_vector_type(8))) unsigned short;

__device__ __forceinline__ unsigned short f2b(float x) {
    union { float f; uint_t u; } c; c.f = x;
    uint_t r = c.u + 0x7fffu + ((c.u >> 16) & 1u);   // RNE
    return (unsigned short)(r >> 16);
}
__device__ __forceinline__ float b2f(unsigned short h) {
    union { uint_t u; float f; } c; c.u = ((uint_t)h) << 16; return c.f;
}
__device__ __forceinline__ float gelu_exact(float v) {
    return 0.5f * v * (1.0f + erff(v * 0.70710678118654752f));
}

#define GCAST(p) ((const __attribute__((address_space(1))) void*)(p))
#define LCAST(p) ((__attribute__((address_space(3))) void*)(p))

// ------------------------- bf16 MFMA GEMM ---------------------------------
// C[m,n] = sum_k A[m,k]*B[n,k]  (A: [M,K] bf16 row-major, B: [N,K] bf16 row-major)
// 128x128 tile, BK=32, 8 waves of 32x64. 3-buffer LDS pipeline with counted
// vmcnt: STAGE(t+2) issued right after barrier t; vmcnt(2) per iter (0 at tail).
enum { ME_F32 = 0, ME_BF16, ME_DCBIAS_BF16, ME_BIASCOL_DUAL,
       ME_BIASCOL_ACC_F32, ME_GELU_BF16, ME_RESB_F32, ME_TREND };

template<int EPI>
__global__ __launch_bounds__(512)
void mgemm_k(const ushort_t* __restrict__ A, const ushort_t* __restrict__ B,
             const float* __restrict__ bias, const ushort_t* __restrict__ Resb,
             void* __restrict__ Cv, ushort_t* __restrict__ C2,
             int M, int N, int K, int ldc, int ldres,
             long sA, long sB, long sC, long sRes)
{
    // XCD-aware bijective swizzle (identity when nwg % 8 != 0)
    const int gx = gridDim.x, gy = gridDim.y;
    const int nwg = gx * gy * gridDim.z;
    const int lin = (blockIdx.z * gy + blockIdx.y) * gx + blockIdx.x;
    const int cpx = nwg >> 3;
    const int swz = (nwg & 7) ? lin : ((lin & 7) * cpx + (lin >> 3));
    const int bx = swz % gx;
    const int t2 = swz / gx;
    const int by = t2 % gy;
    const int bz = t2 / gy;

    A += bz * sA;
    B += bz * sB;
    const int m0 = by * 128, n0 = bx * 128;

    __shared__ __align__(16) ushort_t As[3][4096];
    __shared__ __align__(16) ushort_t Bs[3][4096];

    const int tid = threadIdx.x;
    const int wave = tid >> 6, lane = tid & 63;
    const int wr = wave >> 1, wc = wave & 1;   // wr 0..3 (rows), wc 0..1 (cols)

    f32x4_t acc[2][4] = {};

    const int srow = tid >> 2;           // 0..127 (tile row staged by this thread)
    const int skof = (tid & 3) * 8;      // k-offset in bf16 elems

    const ushort_t* ga = A + (long)(m0 + srow) * K + skof;
    const ushort_t* gb = B + (long)(n0 + srow) * K + skof;
    const int nt = K >> 5;

#define STG(s, bidx) { const long ko = (long)(s) << 5; \
    __builtin_amdgcn_global_load_lds(GCAST(ga + ko), LCAST(As[bidx] + wave * 512), 16, 0, 0); \
    __builtin_amdgcn_global_load_lds(GCAST(gb + ko), LCAST(Bs[bidx] + wave * 512), 16, 0, 0); }

    // prologue: 2 tiles in flight
    STG(0, 0)
    STG(1, 1)

    const int kg = (lane >> 4) * 8;
    int cb = 0;

    for (int t = 0; t < nt; ++t) {
        // wait for tile t's loads only (2 newer stay in flight), then sync
        if (t + 1 < nt) { asm volatile("s_waitcnt vmcnt(2)" ::: "memory"); }
        else            { asm volatile("s_waitcnt vmcnt(0)" ::: "memory"); }
        __builtin_amdgcn_s_barrier();
        asm volatile("" ::: "memory");
        __builtin_amdgcn_sched_barrier(0);
        // buf[(t+2)%3] == buf[(t-1)%3]: freed because all waves passed barrier t
        if (t + 2 < nt) { int nb = cb + 2; if (nb >= 3) nb -= 3; STG(t + 2, nb) }

        bf16x8_t a[2], b[4];
        #pragma unroll
        for (int i = 0; i < 2; ++i)
            a[i] = *(const bf16x8_t*)&As[cb][(wr * 32 + i * 16 + (lane & 15)) * 32 + kg];
        #pragma unroll
        for (int j = 0; j < 4; ++j)
            b[j] = *(const bf16x8_t*)&Bs[cb][(wc * 64 + j * 16 + (lane & 15)) * 32 + kg];
        #pragma unroll
        for (int i = 0; i < 2; ++i)
            #pragma unroll
            for (int j = 0; j < 4; ++j)
                acc[i][j] = __builtin_amdgcn_mfma_f32_16x16x32_bf16(a[i], b[j], acc[i][j], 0, 0, 0);
        ++cb; if (cb >= 3) cb = 0;
    }
#undef STG

    float*    Cf  = (float*)Cv + bz * sC;
    ushort_t* Cb  = (ushort_t*)Cv + bz * sC;
    ushort_t* Cb2 = C2 ? C2 + bz * sC : nullptr;
    const ushort_t* R = Resb ? Resb + bz * sRes : nullptr;

    #pragma unroll
    for (int i = 0; i < 2; ++i) {
        #pragma unroll
        for (int j = 0; j < 4; ++j) {
            #pragma unroll
            for (int r = 0; r < 4; ++r) {
                int gm = m0 + wr * 32 + i * 16 + (lane >> 4) * 4 + r;
                int gn = n0 + wc * 64 + j * 16 + (lane & 15);
                float v = acc[i][j][r];
                long idx = (long)gm * ldc + gn;
                if (EPI == ME_F32)               Cf[idx] = v;
                else if (EPI == ME_BF16)         Cb[idx] = f2b(v);
                else if (EPI == ME_DCBIAS_BF16)  Cb[idx] = f2b(v + (gn == 0 ? 512.f * bias[gm] : 0.f));
                else if (EPI == ME_BIASCOL_DUAL) {
                    float vv = v + bias[gn];
                    Cf[idx] = vv; Cb2[idx] = f2b(vv);
                }
                else if (EPI == ME_BIASCOL_ACC_F32) Cf[idx] += v + bias[gn];
                else if (EPI == ME_GELU_BF16)    Cb[idx] = f2b(gelu_exact(v));
                else if (EPI == ME_RESB_F32)     Cf[idx] = v + b2f(R[(long)gm * ldres + gn]);
                else if (EPI == ME_TREND) { if (gm < 96) Cf[idx] = v + bias[gm]; }
            }
        }
    }
}

// ---------------- batched complex mode-mix MFMA (per h,m) ------------------
__global__ __launch_bounds__(256)
void fmix_k(const ushort_t* __restrict__ A2, const ushort_t* __restrict__ B2,
            ushort_t* __restrict__ OS)
{
    const int hm = blockIdx.x;
    const int h = hm >> 6, m = hm & 63;
    __shared__ __align__(16) ushort_t As[32 * 128];
    __shared__ __align__(16) ushort_t Bs[128 * 128];

    const int tid = threadIdx.x;
    const int w = tid >> 6, lane = tid & 63;

    const ushort_t* Ag = A2 + (long)hm * 4096;
    const ushort_t* Bg = B2 + (long)hm * 16384;
    #pragma unroll
    for (int r = 0; r < 2; ++r)
        __builtin_amdgcn_global_load_lds(GCAST(Ag + w * 1024 + r * 512 + lane * 8),
                                         LCAST(As + w * 1024 + r * 512), 16, 0, 0);
    #pragma unroll
    for (int r = 0; r < 8; ++r)
        __builtin_amdgcn_global_load_lds(GCAST(Bg + w * 4096 + r * 512 + lane * 8),
                                         LCAST(Bs + w * 4096 + r * 512), 16, 0, 0);
    __syncthreads();

    f32x4_t acc[2][2] = {};
    const int kg = (lane >> 4) * 8;
    #pragma unroll
    for (int kk = 0; kk < 4; ++kk) {
        bf16x8_t a[2], b[2];
        #pragma unroll
        for (int i = 0; i < 2; ++i)
            a[i] = *(const bf16x8_t*)&As[(i * 16 + (lane & 15)) * 128 + kk * 32 + kg];
        #pragma unroll
        for (int j = 0; j < 2; ++j)
            b[j] = *(const bf16x8_t*)&Bs[(w * 32 + j * 16 + (lane & 15)) * 128 + kk * 32 + kg];
        #pragma unroll
        for (int i = 0; i < 2; ++i)
            #pragma unroll
            for (int j = 0; j < 2; ++j)
                acc[i][j] = __builtin_amdgcn_mfma_f32_16x16x32_bf16(a[i], b[j], acc[i][j], 0, 0, 0);
    }

    #pragma unroll
    for (int i = 0; i < 2; ++i) {
        #pragma unroll
        for (int j = 0; j < 2; ++j) {
            #pragma unroll
            for (int r = 0; r < 4; ++r) {
                int b = i * 16 + (lane >> 4) * 4 + r;
                int n2 = w * 32 + j * 16 + (lane & 15);
                int o = n2 & 63, ri = n2 >> 6;
                OS[((long)b * 512 + h * 64 + o) * 128 + ri * 64 + m] = f2b(acc[i][j][r]);
            }
        }
    }
}

// B2 prep: block per (h,o). Fr/Fi [h][i][o][m] f32 -> B2[h][m][n2][k2] bf16
__global__ __launch_bounds__(256)
void bprep_k(const float* __restrict__ FR, const float* __restrict__ FI,
             ushort_t* __restrict__ B2)
{
    const int bx = blockIdx.x;
    const int h = bx >> 6, o = bx & 63;
    __shared__ float fr_s[64][65];
    __shared__ float fi_s[64][65];
    for (int e = threadIdx.x; e < 4096; e += 256) {
        int i = e >> 6, m = e & 63;
        long src = ((long)(h * 64 + i) * 64 + o) * 64 + m;
        fr_s[i][m] = FR[src];
        fi_s[i][m] = FI[src];
    }
    __syncthreads();
    const int m = threadIdx.x & 63;
    const int kq = threadIdx.x >> 6;
    ushort_t* b0 = B2 + ((long)(h * 64 + m) * 128 + o) * 128;
    ushort_t* b1 = B2 + ((long)(h * 64 + m) * 128 + o + 64) * 128;
    for (int kk = 0; kk < 32; ++kk) {
        int k2 = kq * 32 + kk;
        int ik = k2 & 63, hi = k2 >> 6;
        float fr = fr_s[ik][m], fi = fi_s[ik][m];
        b0[k2] = f2b(hi ? -fi : fr);
        b1[k2] = f2b(hi ?  fr : fi);
    }
}

// A2 prep: block per (b,h). XFTb [b][c=h*64+i][mp] bf16 -> A2[h][m][b][k2] bf16
__global__ __launch_bounds__(256)
void aprep_k(const ushort_t* __restrict__ XFTb, ushort_t* __restrict__ A2)
{
    const int bx = blockIdx.x;
    const int b = bx >> 3, h = bx & 7;
    __shared__ ushort_t xs[64][130];
    for (int e = threadIdx.x; e < 8192; e += 256) {
        int i = e >> 7, mp = e & 127;
        xs[i][mp] = XFTb[((long)b * 512 + h * 64 + i) * 128 + mp];
    }
    __syncthreads();
    const int m = threadIdx.x & 63;
    const int kq = threadIdx.x >> 6;
    ushort_t* dst = A2 + ((long)(h * 64 + m) * 32 + b) * 128;
    for (int kk = 0; kk < 32; ++kk) {
        int k2 = kq * 32 + kk;
        int i = k2 & 63, ri = k2 >> 6;
        dst[k2] = xs[i][ri * 64 + m];
    }
}

// ------------- sliding-window series_decomp (k=25), multi output -----------
__global__ __launch_bounds__(256)
void decomp2_k(const float* __restrict__ X, float* __restrict__ S,
               ushort_t* __restrict__ Sb, ushort_t* __restrict__ Trb)
{
    const int id = blockIdx.x;
    const int ch = id & 1, rc = (id >> 1) & 31, b = id >> 6;
    const int c = ch * 256 + threadIdx.x;
    const int r0 = rc * 16;
    const long base = ((long)b << 18) + c;
    float s = 0.f;
    #pragma unroll
    for (int j = -12; j <= 12; ++j) {
        int rr = r0 + j; rr = rr < 0 ? 0 : (rr > 511 ? 511 : rr);
        s += X[base + ((long)rr << 9)];
    }
    for (int rr = 0; rr < 16; ++rr) {
        int r = r0 + rr;
        float mean = s * (1.f / 25.f);
        long idx = base + ((long)r << 9);
        float x = X[idx];
        if (S)   S[idx] = x - mean;
        if (Sb)  Sb[idx] = f2b(x - mean);
        if (Trb) Trb[idx] = f2b(mean);
        int rp = r + 13; rp = rp > 511 ? 511 : rp;
        int rm = r - 12; rm = rm < 0 ? 0 : rm;
        s += X[base + ((long)rp << 9)] - X[base + ((long)rm << 9)];
    }
}

// ----------------------- bf16 DFT tables -----------------------------------
__global__ __launch_bounds__(256)
void init_tables_k(ushort_t* __restrict__ TFb, ushort_t* __restrict__ TI2b)
{
    int t = blockIdx.x * 256 + threadIdx.x;   // 0..131071
    const float w = 6.283185307179586f / 512.f;
    if (t < 65536) {
        int mp = t >> 9, n = t & 511;
        int m = mp & 63;
        float ang = ((m * n) & 511) * w;
        TFb[t] = f2b((mp < 64) ? cosf(ang) : -sinf(ang));
    } else {
        int u = t - 65536;
        int mp = u >> 9, n = u & 511;
        int m = mp & 63;
        float ang = ((m * n) & 511) * w;
        float v;
        if (mp < 64) v = (m == 0) ? (1.f / 512.f) : (2.f / 512.f) * cosf(ang);
        else         v = (m == 0) ? 0.f : -(2.f / 512.f) * sinf(ang);
        TI2b[u] = f2b(v);
    }
}

// ----------------------- fp32 -> bf16 convert (weights) --------------------
__global__ __launch_bounds__(256)
void f2b_k(const float* __restrict__ X, ushort_t* __restrict__ Y, long n)
{
    long i = ((long)blockIdx.x * 256 + threadIdx.x) * 8;
    if (i >= n) return;
    const float4* xp = (const float4*)(X + i);
    float4 v0 = xp[0], v1 = xp[1];
    u16x8_t o;
    o[0] = f2b(v0.x); o[1] = f2b(v0.y); o[2] = f2b(v0.z); o[3] = f2b(v0.w);
    o[4] = f2b(v1.x); o[5] = f2b(v1.y); o[6] = f2b(v1.z); o[7] = f2b(v1.w);
    *(u16x8_t*)(Y + i) = o;
}

// ----------------- fp32 [R,C] -> bf16 transposed [C,R] ---------------------
__global__ __launch_bounds__(256)
void trans_b_k(const float* __restrict__ X, ushort_t* __restrict__ Y,
               int R, int C, long sX, long sY)
{
    __shared__ float t[32][33];
    X += (long)blockIdx.z * sX;
    Y += (long)blockIdx.z * sY;
    int r0 = blockIdx.y * 32, c0 = blockIdx.x * 32;
    int tx = threadIdx.x & 31, ty = threadIdx.x >> 5;
    #pragma unroll
    for (int i = ty; i < 32; i += 8)
        t[i][tx] = X[(long)(r0 + i) * C + c0 + tx];
    __syncthreads();
    #pragma unroll
    for (int i = ty; i < 32; i += 8)
        Y[(long)(c0 + i) * R + r0 + tx] = f2b(t[tx][i]);
}

// ----------------- bf16 [R,C] -> bf16 transposed [C,R] ---------------------
__global__ __launch_bounds__(256)
void trans_bb_k(const ushort_t* __restrict__ X, ushort_t* __restrict__ Y,
                int R, int C, long sX, long sY)
{
    __shared__ ushort_t t[32][34];
    X += (long)blockIdx.z * sX;
    Y += (long)blockIdx.z * sY;
    int r0 = blockIdx.y * 32, c0 = blockIdx.x * 32;
    int tx = threadIdx.x & 31, ty = threadIdx.x >> 5;
    #pragma unroll
    for (int i = ty; i < 32; i += 8)
        t[i][tx] = X[(long)(r0 + i) * C + c0 + tx];
    __syncthreads();
    #pragma unroll
    for (int i = ty; i < 32; i += 8)
        Y[(long)(c0 + i) * R + r0 + tx] = t[tx][i];
}

// ------------------------------ layernorm ----------------------------------
__global__ __launch_bounds__(256)
void ln_rows_k(const float* __restrict__ X, const float* __restrict__ g,
               const float* __restrict__ bta, float* __restrict__ Y)
{
    int wave = threadIdx.x >> 6, lane = threadIdx.x & 63;
    long row = (long)blockIdx.x * 4 + wave;
    const float* x = X + row * 512;
    float s = 0.f, ss = 0.f;
    for (int d = lane; d < 512; d += 64) { float v = x[d]; s += v; ss += v * v; }
    #pragma unroll
    for (int o = 32; o; o >>= 1) { s += __shfl_xor(s, o); ss += __shfl_xor(ss, o); }
    float mu = s * (1.f / 512.f);
    float var = ss * (1.f / 512.f) - mu * mu;
    float inv = rsqrtf(var + 1e-5f);
    float* y = Y + row * 512;
    for (int d = lane; d < 512; d += 64)
        y[d] = (x[d] - mu) * inv * g[d] + bta[d];
}

// subtract per-(b,d) seq-mean, emit bf16
__global__ __launch_bounds__(64)
void colmean_b16_k(const float* __restrict__ Y, ushort_t* __restrict__ O)
{
    int b = blockIdx.x, dg = blockIdx.y;
    int d = dg * 64 + threadIdx.x;
    long base = (long)b * 262144 + d;
    float s = 0.f;
    for (int t = 0; t < 512; ++t) s += Y[base + ((long)t << 9)];
    float mean = s * (1.f / 512.f);
    for (int t = 0; t < 512; ++t)
        O[base + ((long)t << 9)] = f2b(Y[base + ((long)t << 9)] - mean);
}

// head transpose-add: out[b,p,t] += Thead[(b*512+t)*128+p] + b_head[p]
__global__ __launch_bounds__(256)
void headadd_k(const float* __restrict__ Th, const float* __restrict__ bh,
               float* __restrict__ out)
{
    const int id = blockIdx.x;          // b*16 + tc
    const int b = id >> 4, t0 = (id & 15) * 32;
    __shared__ float tile[32][100];
    for (int e = threadIdx.x; e < 32 * 96; e += 256) {
        int tl = e / 96, p = e - tl * 96;
        tile[tl][p] = Th[((long)(b * 512 + t0 + tl)) * 128 + p];
    }
    __syncthreads();
    for (int e = threadIdx.x; e < 96 * 32; e += 256) {
        int p = e >> 5, tl = e & 31;
        out[(long)b * 49152 + p * 512 + t0 + tl] += tile[tl][p] + bh[p];
    }
}

// ===========================================================================
extern "C" void kernel_launch(void* const* d_in, const int* in_sizes, int n_in,
                              void* d_out, int out_size, void* d_ws, size_t ws_size,
                              hipStream_t stream)
{
    const float* x_enc   = (const float*)d_in[0];
    const float* W_trend = (const float*)d_in[4];
    const float* b_trend = (const float*)d_in[5];
    const float* W_emb   = (const float*)d_in[6];
    const float* b_emb   = (const float*)d_in[7];
    const float* Wq      = (const float*)d_in[8];
    const float* bq      = (const float*)d_in[9];
    const float* fw_r    = (const float*)d_in[14];
    const float* fw_i    = (const float*)d_in[15];
    const float* Wo      = (const float*)d_in[16];
    const float* bo      = (const float*)d_in[17];
    const float* W1      = (const float*)d_in[18];
    const float* W2      = (const float*)d_in[19];
    const float* ln_g    = (const float*)d_in[20];
    const float* ln_b    = (const float*)d_in[21];
    const float* W_head  = (const float*)d_in[22];
    const float* b_head  = (const float*)d_in[23];
    float* out = (float*)d_out;
    float* ws  = (float*)d_ws;

    const long F = 8388608;
    // [0..2F)   G: phase-overlaid scratch (64 MB)
    // [3F..4F)  X f32 (encoder state)
    // [4F..5F)  T1 f32 (FFN out / LN out)
    // [5F..6F)  qT bf16 + xb bf16
    // [6F..)    weights bf16
    float* G    = ws;
    float* X    = ws + 3 * F;
    float* T1   = ws + 4 * F;
    ushort_t* qT = (ushort_t*)(ws + 5 * F);
    ushort_t* xb = qT + 8388608;

    // start-phase overlays in G (trendb: bytes [0,16MB), seasb: [16MB,32MB))
    ushort_t* trendb = (ushort_t*)G;                   // [B,512,512] bf16
    ushort_t* seasb  = (ushort_t*)(G + 4194304);       // [B,512,512] bf16
    // attn-phase overlays in G
    ushort_t* XFTb  = (ushort_t*)G;                    // [B,512,128] bf16 [0,4MB)
    ushort_t* Yb    = (ushort_t*)(G + 1048576);        // [B,128,512] bf16 [4,8MB)
    ushort_t* A2    = (ushort_t*)(G + 2097152);        // [8,64,32,128] bf16 [8,12MB)
    ushort_t* OSELb = (ushort_t*)(G + 3145728);        // [B,512,128] bf16 [12,16MB)
    ushort_t* xbT   = (ushort_t*)(G + 4194304);        // [B,512,512] bf16 [16,32MB)
    ushort_t* B2    = (ushort_t*)(G + 8388608);        // [8,64,128,128] bf16 [32,48MB)
    float*    Thead = G;                               // end-phase
    ushort_t* gb    = (ushort_t*)G;                    // FFN-phase [16384,2048] 64MB

    ushort_t* WembT  = (ushort_t*)(ws + 6 * F);        // [512,512]
    ushort_t* WTq    = WembT + 262144;
    ushort_t* WTo    = WTq + 262144;
    ushort_t* W1b    = WTo + 262144;                   // [2048,512]
    ushort_t* W2b    = W1b + 1048576;                  // [512,2048]
    ushort_t* TFb    = W2b + 1048576;                  // [128,512]
    ushort_t* TI2b   = TFb + 65536;                    // [128,512]
    ushort_t* WtT    = TI2b + 65536;                   // [128,512] rows<96 valid
    ushort_t* WheadT = WtT + 65536;                    // [128,512] rows<96 valid
    ushort_t* TIWob  = WheadT + 65536;                 // [512,128]

    dim3 blk(256), blk5(512);

    init_tables_k<<<dim3(512), blk, 0, stream>>>(TFb, TI2b);

    // decomp(x_enc) -> bf16 seasonal + bf16 trend
    decomp2_k<<<dim3(2048), blk, 0, stream>>>(x_enc, nullptr, seasb, trendb);

    trans_b_k<<<dim3(3, 16, 1), blk, 0, stream>>>(W_trend, WtT, 512, 96, 0L, 0L);
    trans_b_k<<<dim3(3, 16, 1), blk, 0, stream>>>(W_head, WheadT, 512, 96, 0L, 0L);
    trans_b_k<<<dim3(16, 16, 1), blk, 0, stream>>>(W_emb, WembT, 512, 512, 0L, 0L);

    // trendT bf16 into qT slot, trend head GEMM -> out
    trans_bb_k<<<dim3(16, 16, 32), blk, 0, stream>>>(trendb, qT, 512, 512, 262144L, 262144L);
    mgemm_k<ME_TREND><<<dim3(4, 1, 32), blk5, 0, stream>>>(
        WtT, qT, b_trend, nullptr, out, nullptr,
        128, 512, 512, 512, 0, 0L, 262144L, 49152L, 0L);

    // seasonalT bf16 into qT slot; embedding -> X f32 + xb bf16
    trans_bb_k<<<dim3(16, 16, 32), blk, 0, stream>>>(seasb, qT, 512, 512, 262144L, 262144L);
    mgemm_k<ME_BIASCOL_DUAL><<<dim3(4, 4, 32), blk5, 0, stream>>>(
        qT, WembT, b_emb, nullptr, X, xb,
        512, 512, 512, 512, 0, 262144L, 0L, 262144L, 0L);

    for (int l = 0; l < 2; ++l) {
        const float* Wq_l = Wq + (long)l * 262144;
        const float* bq_l = bq + (long)l * 512;
        const float* Wo_l = Wo + (long)l * 262144;
        const float* bo_l = bo + (long)l * 512;
        const float* W1_l = W1 + (long)l * 1048576;
        const float* W2_l = W2 + (long)l * 1048576;
        const float* fr_l = fw_r + (long)l * 2097152;
        const float* fi_l = fw_i + (long)l * 2097152;

        // weight prep
        trans_b_k<<<dim3(16, 16, 1), blk, 0, stream>>>(Wq_l, WTq, 512, 512, 0L, 0L);
        trans_b_k<<<dim3(16, 16, 1), blk, 0, stream>>>(Wo_l, WTo, 512, 512, 0L, 0L);
        f2b_k<<<dim3(512), blk, 0, stream>>>(W1_l, W1b, 1048576L);
        f2b_k<<<dim3(512), blk, 0, stream>>>(W2_l, W2b, 1048576L);
        bprep_k<<<dim3(512), blk, 0, stream>>>(fr_l, fi_l, B2);

        // TIWob[d,mp] = sum_n WTo[d,n] * TI2b[mp,n]   (fold irfft into Wo)
        mgemm_k<ME_BF16><<<dim3(1, 4, 1), blk5, 0, stream>>>(
            WTo, TI2b, nullptr, nullptr, TIWob, nullptr,
            512, 128, 512, 128, 0, 0L, 0L, 0L, 0L);

        // xbT[b,d,n] = xb[b,n,d]^T (bf16 in/out)
        trans_bb_k<<<dim3(16, 16, 32), blk, 0, stream>>>(xb, xbT, 512, 512, 262144L, 262144L);

        // G1: Yb[b,mp,d] = sum_n TFb[mp,n] * xbT[b,d,n]
        mgemm_k<ME_BF16><<<dim3(4, 1, 32), blk5, 0, stream>>>(
            TFb, xbT, nullptr, nullptr, Yb, nullptr,
            128, 512, 512, 512, 0, 0L, 262144L, 65536L, 0L);

        // G2: XFTb[b,c,mp] = sum_d WTq[c,d] * Yb[b,mp,d]  (+512*bq[c] at mp=0)
        mgemm_k<ME_DCBIAS_BF16><<<dim3(1, 4, 32), blk5, 0, stream>>>(
            WTq, Yb, bq_l, nullptr, XFTb, nullptr,
            512, 128, 512, 128, 0, 0L, 65536L, 65536L, 0L);

        // complex mode mixing
        aprep_k<<<dim3(256), blk, 0, stream>>>(XFTb, A2);
        fmix_k<<<dim3(512), blk, 0, stream>>>(A2, B2, OSELb);

        // X += OSEL . TIWo^T + bo   (irfft+Wo folded, K=128)
        mgemm_k<ME_BIASCOL_ACC_F32><<<dim3(4, 128, 1), blk5, 0, stream>>>(
            OSELb, TIWob, bo_l, nullptr, X, nullptr,
            16384, 512, 128, 512, 0, 0L, 0L, 0L, 0L);

        // decomp -> xb bf16 only (FFN input + FFN2 residual)
        decomp2_k<<<dim3(2048), blk, 0, stream>>>(X, nullptr, xb, nullptr);

        // FFN, full M=16384 (gb overlays attn scratch in G)
        mgemm_k<ME_GELU_BF16><<<dim3(16, 128, 1), blk5, 0, stream>>>(
            xb, W1b, nullptr, nullptr, gb, nullptr,
            16384, 2048, 512, 2048, 0, 0L, 0L, 0L, 0L);
        mgemm_k<ME_RESB_F32><<<dim3(4, 128, 1), blk5, 0, stream>>>(
            gb, W2b, nullptr, xb, T1, nullptr,
            16384, 512, 2048, 512, 512, 0L, 0L, 0L, 0L);

        // decomp -> X f32 (residual/LN) + xb bf16 (next layer's transpose src)
        decomp2_k<<<dim3(2048), blk, 0, stream>>>(T1, X, xb, nullptr);
    }

    // my_layernorm
    ln_rows_k<<<dim3(4096), blk, 0, stream>>>(X, ln_g, ln_b, T1);
    colmean_b16_k<<<dim3(32, 8), dim3(64), 0, stream>>>(T1, xb);

    // head
    mgemm_k<ME_F32><<<dim3(1, 128, 1), blk5, 0, stream>>>(
        xb, WheadT, nullptr, nullptr, Thead, nullptr,
        16384, 128, 512, 128, 0, 0L, 0L, 0L, 0L);

    headadd_k<<<dim3(512), blk, 0, stream>>>(Thead, b_head, out);
}

// Round 9
// 688.114 us; speedup vs baseline: 6.9798x; 1.0338x over previous
//
#include <hip/hip_runtime.h>
#include <math.h>

// ---------------------------------------------------------------------------
// Model_24180665876772  Round 9: fat-accumulator GEMM (256x128 tile, acc[4][4],
// MFMA/ds_read ratio 2.0 vs 1.33) for the big GEMMs; FFN path bf16; parallel
// colmean.
// ---------------------------------------------------------------------------

typedef unsigned short ushort_t;
typedef unsigned int uint_t;
using bf16x8_t = __attribute__((ext_vector_type(8))) short;
using f32x4_t  = __attribute__((ext_vector_type(4))) float;
using u16x8_t  = __attribute__((ext_vector_type(8))) unsigned short;

__device__ __forceinline__ unsigned short f2b(float x) {
    union { float f; uint_t u; } c; c.f = x;
    uint_t r = c.u + 0x7fffu + ((c.u >> 16) & 1u);   // RNE
    return (unsigned short)(r >> 16);
}
__device__ __forceinline__ float b2f(unsigned short h) {
    union { uint_t u; float f; } c; c.u = ((uint_t)h) << 16; return c.f;
}
__device__ __forceinline__ float gelu_exact(float v) {
    return 0.5f * v * (1.0f + erff(v * 0.70710678118654752f));
}

#define GCAST(p) ((const __attribute__((address_space(1))) void*)(p))
#define LCAST(p) ((__attribute__((address_space(3))) void*)(p))

enum { ME_F32 = 0, ME_BF16, ME_DCBIAS_BF16, ME_BIASCOL_DUAL,
       ME_BIASCOL_ACC_F32, ME_GELU_BF16, ME_RESB_BF16, ME_TREND };

// ---------------- 128x128 GEMM (small/odd shapes), 8 waves, 3-buf ----------
template<int EPI>
__global__ __launch_bounds__(512)
void mgemm_k(const ushort_t* __restrict__ A, const ushort_t* __restrict__ B,
             const float* __restrict__ bias, const ushort_t* __restrict__ Resb,
             void* __restrict__ Cv, ushort_t* __restrict__ C2,
             int M, int N, int K, int ldc, int ldres,
             long sA, long sB, long sC, long sRes)
{
    const int gx = gridDim.x, gy = gridDim.y;
    const int nwg = gx * gy * gridDim.z;
    const int lin = (blockIdx.z * gy + blockIdx.y) * gx + blockIdx.x;
    const int cpx = nwg >> 3;
    const int swz = (nwg & 7) ? lin : ((lin & 7) * cpx + (lin >> 3));
    const int bx = swz % gx;
    const int t2 = swz / gx;
    const int by = t2 % gy;
    const int bz = t2 / gy;

    A += bz * sA;
    B += bz * sB;
    const int m0 = by * 128, n0 = bx * 128;

    __shared__ __align__(16) ushort_t As[3][4096];
    __shared__ __align__(16) ushort_t Bs[3][4096];

    const int tid = threadIdx.x;
    const int wave = tid >> 6, lane = tid & 63;
    const int wr = wave >> 1, wc = wave & 1;

    f32x4_t acc[2][4] = {};

    const int srow = tid >> 2;
    const int skof = (tid & 3) * 8;

    const ushort_t* ga = A + (long)(m0 + srow) * K + skof;
    const ushort_t* gb = B + (long)(n0 + srow) * K + skof;
    const int nt = K >> 5;

#define STG(s, bidx) { const long ko = (long)(s) << 5; \
    __builtin_amdgcn_global_load_lds(GCAST(ga + ko), LCAST(As[bidx] + wave * 512), 16, 0, 0); \
    __builtin_amdgcn_global_load_lds(GCAST(gb + ko), LCAST(Bs[bidx] + wave * 512), 16, 0, 0); }

    STG(0, 0)
    STG(1, 1)

    const int kg = (lane >> 4) * 8;
    int cb = 0;

    for (int t = 0; t < nt; ++t) {
        if (t + 1 < nt) { asm volatile("s_waitcnt vmcnt(2)" ::: "memory"); }
        else            { asm volatile("s_waitcnt vmcnt(0)" ::: "memory"); }
        __builtin_amdgcn_s_barrier();
        asm volatile("" ::: "memory");
        __builtin_amdgcn_sched_barrier(0);
        if (t + 2 < nt) { int nb = cb + 2; if (nb >= 3) nb -= 3; STG(t + 2, nb) }

        bf16x8_t a[2], b[4];
        #pragma unroll
        for (int i = 0; i < 2; ++i)
            a[i] = *(const bf16x8_t*)&As[cb][(wr * 32 + i * 16 + (lane & 15)) * 32 + kg];
        #pragma unroll
        for (int j = 0; j < 4; ++j)
            b[j] = *(const bf16x8_t*)&Bs[cb][(wc * 64 + j * 16 + (lane & 15)) * 32 + kg];
        #pragma unroll
        for (int i = 0; i < 2; ++i)
            #pragma unroll
            for (int j = 0; j < 4; ++j)
                acc[i][j] = __builtin_amdgcn_mfma_f32_16x16x32_bf16(a[i], b[j], acc[i][j], 0, 0, 0);
        ++cb; if (cb >= 3) cb = 0;
    }
#undef STG

    float*    Cf  = (float*)Cv + bz * sC;
    ushort_t* Cb  = (ushort_t*)Cv + bz * sC;
    ushort_t* Cb2 = C2 ? C2 + bz * sC : nullptr;
    const ushort_t* R = Resb ? Resb + bz * sRes : nullptr;

    #pragma unroll
    for (int i = 0; i < 2; ++i) {
        #pragma unroll
        for (int j = 0; j < 4; ++j) {
            #pragma unroll
            for (int r = 0; r < 4; ++r) {
                int gm = m0 + wr * 32 + i * 16 + (lane >> 4) * 4 + r;
                int gn = n0 + wc * 64 + j * 16 + (lane & 15);
                float v = acc[i][j][r];
                long idx = (long)gm * ldc + gn;
                if (EPI == ME_F32)               Cf[idx] = v;
                else if (EPI == ME_BF16)         Cb[idx] = f2b(v);
                else if (EPI == ME_DCBIAS_BF16)  Cb[idx] = f2b(v + (gn == 0 ? 512.f * bias[gm] : 0.f));
                else if (EPI == ME_TREND) { if (gm < 96) Cf[idx] = v + bias[gm]; }
            }
        }
    }
}

// ------------- 256x128 GEMM (big GEMMs), acc[4][4], 3-buf, vmcnt(3) --------
template<int EPI>
__global__ __launch_bounds__(512)
void mgemm2_k(const ushort_t* __restrict__ A, const ushort_t* __restrict__ B,
              const float* __restrict__ bias, const ushort_t* __restrict__ Resb,
              void* __restrict__ Cv, ushort_t* __restrict__ C2,
              int M, int N, int K, int ldc, int ldres,
              long sA, long sB, long sC, long sRes)
{
    const int gx = gridDim.x, gy = gridDim.y;
    const int nwg = gx * gy * gridDim.z;
    const int lin = (blockIdx.z * gy + blockIdx.y) * gx + blockIdx.x;
    const int cpx = nwg >> 3;
    const int swz = (nwg & 7) ? lin : ((lin & 7) * cpx + (lin >> 3));
    const int bx = swz % gx;
    const int t2 = swz / gx;
    const int by = t2 % gy;
    const int bz = t2 / gy;

    A += bz * sA;
    B += bz * sB;
    const int m0 = by * 256, n0 = bx * 128;

    __shared__ __align__(16) ushort_t As[3][8192];   // 256 x 32
    __shared__ __align__(16) ushort_t Bs[3][4096];   // 128 x 32

    const int tid = threadIdx.x;
    const int wave = tid >> 6, lane = tid & 63;
    const int wr = wave >> 1, wc = wave & 1;   // wr 0..3 (64-row strips), wc 0..1

    f32x4_t acc[4][4] = {};

    const int srow = tid >> 2;           // 0..127
    const int skof = (tid & 3) * 8;

    const ushort_t* gaA  = A + (long)(m0 + srow) * K + skof;         // rows 0..127
    const ushort_t* gaA2 = gaA + (long)128 * K;                      // rows 128..255
    const ushort_t* gbB  = B + (long)(n0 + srow) * K + skof;
    const int nt = K >> 5;

#define STG2(s, bidx) { const long ko = (long)(s) << 5; \
    __builtin_amdgcn_global_load_lds(GCAST(gaA  + ko), LCAST(As[bidx] + wave * 512),        16, 0, 0); \
    __builtin_amdgcn_global_load_lds(GCAST(gaA2 + ko), LCAST(As[bidx] + 4096 + wave * 512), 16, 0, 0); \
    __builtin_amdgcn_global_load_lds(GCAST(gbB  + ko), LCAST(Bs[bidx] + wave * 512),        16, 0, 0); }

    STG2(0, 0)
    STG2(1, 1)

    const int kg = (lane >> 4) * 8;
    int cb = 0;

    for (int t = 0; t < nt; ++t) {
        if (t + 1 < nt) { asm volatile("s_waitcnt vmcnt(3)" ::: "memory"); }
        else            { asm volatile("s_waitcnt vmcnt(0)" ::: "memory"); }
        __builtin_amdgcn_s_barrier();
        asm volatile("" ::: "memory");
        __builtin_amdgcn_sched_barrier(0);
        if (t + 2 < nt) { int nb = cb + 2; if (nb >= 3) nb -= 3; STG2(t + 2, nb) }

        bf16x8_t a[4], b[4];
        #pragma unroll
        for (int i = 0; i < 4; ++i)
            a[i] = *(const bf16x8_t*)&As[cb][(wr * 64 + i * 16 + (lane & 15)) * 32 + kg];
        #pragma unroll
        for (int j = 0; j < 4; ++j)
            b[j] = *(const bf16x8_t*)&Bs[cb][(wc * 64 + j * 16 + (lane & 15)) * 32 + kg];
        #pragma unroll
        for (int i = 0; i < 4; ++i)
            #pragma unroll
            for (int j = 0; j < 4; ++j)
                acc[i][j] = __builtin_amdgcn_mfma_f32_16x16x32_bf16(a[i], b[j], acc[i][j], 0, 0, 0);
        ++cb; if (cb >= 3) cb = 0;
    }
#undef STG2

    float*    Cf  = (float*)Cv + bz * sC;
    ushort_t* Cb  = (ushort_t*)Cv + bz * sC;
    ushort_t* Cb2 = C2 ? C2 + bz * sC : nullptr;
    const ushort_t* R = Resb ? Resb + bz * sRes : nullptr;

    #pragma unroll
    for (int i = 0; i < 4; ++i) {
        #pragma unroll
        for (int j = 0; j < 4; ++j) {
            #pragma unroll
            for (int r = 0; r < 4; ++r) {
                int gm = m0 + wr * 64 + i * 16 + (lane >> 4) * 4 + r;
                int gn = n0 + wc * 64 + j * 16 + (lane & 15);
                float v = acc[i][j][r];
                long idx = (long)gm * ldc + gn;
                if (EPI == ME_BIASCOL_DUAL) {
                    float vv = v + bias[gn];
                    Cf[idx] = vv; Cb2[idx] = f2b(vv);
                }
                else if (EPI == ME_BIASCOL_ACC_F32) Cf[idx] += v + bias[gn];
                else if (EPI == ME_GELU_BF16)    Cb[idx] = f2b(gelu_exact(v));
                else if (EPI == ME_RESB_BF16)    Cb[idx] = f2b(v + b2f(R[(long)gm * ldres + gn]));
            }
        }
    }
}

// ---------------- batched complex mode-mix MFMA (per h,m) ------------------
__global__ __launch_bounds__(256)
void fmix_k(const ushort_t* __restrict__ A2, const ushort_t* __restrict__ B2,
            ushort_t* __restrict__ OS)
{
    const int hm = blockIdx.x;
    const int h = hm >> 6, m = hm & 63;
    __shared__ __align__(16) ushort_t As[32 * 128];
    __shared__ __align__(16) ushort_t Bs[128 * 128];

    const int tid = threadIdx.x;
    const int w = tid >> 6, lane = tid & 63;

    const ushort_t* Ag = A2 + (long)hm * 4096;
    const ushort_t* Bg = B2 + (long)hm * 16384;
    #pragma unroll
    for (int r = 0; r < 2; ++r)
        __builtin_amdgcn_global_load_lds(GCAST(Ag + w * 1024 + r * 512 + lane * 8),
                                         LCAST(As + w * 1024 + r * 512), 16, 0, 0);
    #pragma unroll
    for (int r = 0; r < 8; ++r)
        __builtin_amdgcn_global_load_lds(GCAST(Bg + w * 4096 + r * 512 + lane * 8),
                                         LCAST(Bs + w * 4096 + r * 512), 16, 0, 0);
    __syncthreads();

    f32x4_t acc[2][2] = {};
    const int kg = (lane >> 4) * 8;
    #pragma unroll
    for (int kk = 0; kk < 4; ++kk) {
        bf16x8_t a[2], b[2];
        #pragma unroll
        for (int i = 0; i < 2; ++i)
            a[i] = *(const bf16x8_t*)&As[(i * 16 + (lane & 15)) * 128 + kk * 32 + kg];
        #pragma unroll
        for (int j = 0; j < 2; ++j)
            b[j] = *(const bf16x8_t*)&Bs[(w * 32 + j * 16 + (lane & 15)) * 128 + kk * 32 + kg];
        #pragma unroll
        for (int i = 0; i < 2; ++i)
            #pragma unroll
            for (int j = 0; j < 2; ++j)
                acc[i][j] = __builtin_amdgcn_mfma_f32_16x16x32_bf16(a[i], b[j], acc[i][j], 0, 0, 0);
    }

    #pragma unroll
    for (int i = 0; i < 2; ++i) {
        #pragma unroll
        for (int j = 0; j < 2; ++j) {
            #pragma unroll
            for (int r = 0; r < 4; ++r) {
                int b = i * 16 + (lane >> 4) * 4 + r;
                int n2 = w * 32 + j * 16 + (lane & 15);
                int o = n2 & 63, ri = n2 >> 6;
                OS[((long)b * 512 + h * 64 + o) * 128 + ri * 64 + m] = f2b(acc[i][j][r]);
            }
        }
    }
}

// B2 prep: block per (h,o). Fr/Fi [h][i][o][m] f32 -> B2[h][m][n2][k2] bf16
__global__ __launch_bounds__(256)
void bprep_k(const float* __restrict__ FR, const float* __restrict__ FI,
             ushort_t* __restrict__ B2)
{
    const int bx = blockIdx.x;
    const int h = bx >> 6, o = bx & 63;
    __shared__ float fr_s[64][65];
    __shared__ float fi_s[64][65];
    for (int e = threadIdx.x; e < 4096; e += 256) {
        int i = e >> 6, m = e & 63;
        long src = ((long)(h * 64 + i) * 64 + o) * 64 + m;
        fr_s[i][m] = FR[src];
        fi_s[i][m] = FI[src];
    }
    __syncthreads();
    const int m = threadIdx.x & 63;
    const int kq = threadIdx.x >> 6;
    ushort_t* b0 = B2 + ((long)(h * 64 + m) * 128 + o) * 128;
    ushort_t* b1 = B2 + ((long)(h * 64 + m) * 128 + o + 64) * 128;
    for (int kk = 0; kk < 32; ++kk) {
        int k2 = kq * 32 + kk;
        int ik = k2 & 63, hi = k2 >> 6;
        float fr = fr_s[ik][m], fi = fi_s[ik][m];
        b0[k2] = f2b(hi ? -fi : fr);
        b1[k2] = f2b(hi ?  fr : fi);
    }
}

// A2 prep: block per (b,h). XFTb [b][c=h*64+i][mp] bf16 -> A2[h][m][b][k2] bf16
__global__ __launch_bounds__(256)
void aprep_k(const ushort_t* __restrict__ XFTb, ushort_t* __restrict__ A2)
{
    const int bx = blockIdx.x;
    const int b = bx >> 3, h = bx & 7;
    __shared__ ushort_t xs[64][130];
    for (int e = threadIdx.x; e < 8192; e += 256) {
        int i = e >> 7, mp = e & 127;
        xs[i][mp] = XFTb[((long)b * 512 + h * 64 + i) * 128 + mp];
    }
    __syncthreads();
    const int m = threadIdx.x & 63;
    const int kq = threadIdx.x >> 6;
    ushort_t* dst = A2 + ((long)(h * 64 + m) * 32 + b) * 128;
    for (int kk = 0; kk < 32; ++kk) {
        int k2 = kq * 32 + kk;
        int i = k2 & 63, ri = k2 >> 6;
        dst[k2] = xs[i][ri * 64 + m];
    }
}

// ------------- sliding-window series_decomp (k=25), f32 input --------------
__global__ __launch_bounds__(256)
void decomp2_k(const float* __restrict__ X, float* __restrict__ S,
               ushort_t* __restrict__ Sb, ushort_t* __restrict__ Trb)
{
    const int id = blockIdx.x;
    const int ch = id & 1, rc = (id >> 1) & 31, b = id >> 6;
    const int c = ch * 256 + threadIdx.x;
    const int r0 = rc * 16;
    const long base = ((long)b << 18) + c;
    float s = 0.f;
    #pragma unroll
    for (int j = -12; j <= 12; ++j) {
        int rr = r0 + j; rr = rr < 0 ? 0 : (rr > 511 ? 511 : rr);
        s += X[base + ((long)rr << 9)];
    }
    for (int rr = 0; rr < 16; ++rr) {
        int r = r0 + rr;
        float mean = s * (1.f / 25.f);
        long idx = base + ((long)r << 9);
        float x = X[idx];
        if (S)   S[idx] = x - mean;
        if (Sb)  Sb[idx] = f2b(x - mean);
        if (Trb) Trb[idx] = f2b(mean);
        int rp = r + 13; rp = rp > 511 ? 511 : rp;
        int rm = r - 12; rm = rm < 0 ? 0 : rm;
        s += X[base + ((long)rp << 9)] - X[base + ((long)rm << 9)];
    }
}

// ------------- sliding-window series_decomp (k=25), bf16 input -------------
__global__ __launch_bounds__(256)
void decomp2h_k(const ushort_t* __restrict__ Xb, float* __restrict__ S,
                ushort_t* __restrict__ Sb)
{
    const int id = blockIdx.x;
    const int ch = id & 1, rc = (id >> 1) & 31, b = id >> 6;
    const int c = ch * 256 + threadIdx.x;
    const int r0 = rc * 16;
    const long base = ((long)b << 18) + c;
    float s = 0.f;
    #pragma unroll
    for (int j = -12; j <= 12; ++j) {
        int rr = r0 + j; rr = rr < 0 ? 0 : (rr > 511 ? 511 : rr);
        s += b2f(Xb[base + ((long)rr << 9)]);
    }
    for (int rr = 0; rr < 16; ++rr) {
        int r = r0 + rr;
        float mean = s * (1.f / 25.f);
        long idx = base + ((long)r << 9);
        float x = b2f(Xb[idx]);
        if (S)   S[idx] = x - mean;
        if (Sb)  Sb[idx] = f2b(x - mean);
        int rp = r + 13; rp = rp > 511 ? 511 : rp;
        int rm = r - 12; rm = rm < 0 ? 0 : rm;
        s += b2f(Xb[base + ((long)rp << 9)]) - b2f(Xb[base + ((long)rm << 9)]);
    }
}

// ----------------------- bf16 DFT tables -----------------------------------
__global__ __launch_bounds__(256)
void init_tables_k(ushort_t* __restrict__ TFb, ushort_t* __restrict__ TI2b)
{
    int t = blockIdx.x * 256 + threadIdx.x;   // 0..131071
    const float w = 6.283185307179586f / 512.f;
    if (t < 65536) {
        int mp = t >> 9, n = t & 511;
        int m = mp & 63;
        float ang = ((m * n) & 511) * w;
        TFb[t] = f2b((mp < 64) ? cosf(ang) : -sinf(ang));
    } else {
        int u = t - 65536;
        int mp = u >> 9, n = u & 511;
        int m = mp & 63;
        float ang = ((m * n) & 511) * w;
        float v;
        if (mp < 64) v = (m == 0) ? (1.f / 512.f) : (2.f / 512.f) * cosf(ang);
        else         v = (m == 0) ? 0.f : -(2.f / 512.f) * sinf(ang);
        TI2b[u] = f2b(v);
    }
}

// ----------------------- fp32 -> bf16 convert (weights) --------------------
__global__ __launch_bounds__(256)
void f2b_k(const float* __restrict__ X, ushort_t* __restrict__ Y, long n)
{
    long i = ((long)blockIdx.x * 256 + threadIdx.x) * 8;
    if (i >= n) return;
    const float4* xp = (const float4*)(X + i);
    float4 v0 = xp[0], v1 = xp[1];
    u16x8_t o;
    o[0] = f2b(v0.x); o[1] = f2b(v0.y); o[2] = f2b(v0.z); o[3] = f2b(v0.w);
    o[4] = f2b(v1.x); o[5] = f2b(v1.y); o[6] = f2b(v1.z); o[7] = f2b(v1.w);
    *(u16x8_t*)(Y + i) = o;
}

// ----------------- fp32 [R,C] -> bf16 transposed [C,R] ---------------------
__global__ __launch_bounds__(256)
void trans_b_k(const float* __restrict__ X, ushort_t* __restrict__ Y,
               int R, int C, long sX, long sY)
{
    __shared__ float t[32][33];
    X += (long)blockIdx.z * sX;
    Y += (long)blockIdx.z * sY;
    int r0 = blockIdx.y * 32, c0 = blockIdx.x * 32;
    int tx = threadIdx.x & 31, ty = threadIdx.x >> 5;
    #pragma unroll
    for (int i = ty; i < 32; i += 8)
        t[i][tx] = X[(long)(r0 + i) * C + c0 + tx];
    __syncthreads();
    #pragma unroll
    for (int i = ty; i < 32; i += 8)
        Y[(long)(c0 + i) * R + r0 + tx] = f2b(t[tx][i]);
}

// ----------------- bf16 [R,C] -> bf16 transposed [C,R] ---------------------
__global__ __launch_bounds__(256)
void trans_bb_k(const ushort_t* __restrict__ X, ushort_t* __restrict__ Y,
                int R, int C, long sX, long sY)
{
    __shared__ ushort_t t[32][34];
    X += (long)blockIdx.z * sX;
    Y += (long)blockIdx.z * sY;
    int r0 = blockIdx.y * 32, c0 = blockIdx.x * 32;
    int tx = threadIdx.x & 31, ty = threadIdx.x >> 5;
    #pragma unroll
    for (int i = ty; i < 32; i += 8)
        t[i][tx] = X[(long)(r0 + i) * C + c0 + tx];
    __syncthreads();
    #pragma unroll
    for (int i = ty; i < 32; i += 8)
        Y[(long)(c0 + i) * R + r0 + tx] = t[tx][i];
}

// ------------------------------ layernorm ----------------------------------
__global__ __launch_bounds__(256)
void ln_rows_k(const float* __restrict__ X, const float* __restrict__ g,
               const float* __restrict__ bta, float* __restrict__ Y)
{
    int wave = threadIdx.x >> 6, lane = threadIdx.x & 63;
    long row = (long)blockIdx.x * 4 + wave;
    const float* x = X + row * 512;
    float s = 0.f, ss = 0.f;
    for (int d = lane; d < 512; d += 64) { float v = x[d]; s += v; ss += v * v; }
    #pragma unroll
    for (int o = 32; o; o >>= 1) { s += __shfl_xor(s, o); ss += __shfl_xor(ss, o); }
    float mu = s * (1.f / 512.f);
    float var = ss * (1.f / 512.f) - mu * mu;
    float inv = rsqrtf(var + 1e-5f);
    float* y = Y + row * 512;
    for (int d = lane; d < 512; d += 64)
        y[d] = (x[d] - mu) * inv * g[d] + bta[d];
}

// subtract per-(b,d) seq-mean, emit bf16 (4 waves split the t-loop)
__global__ __launch_bounds__(256)
void colmean_b16_k(const float* __restrict__ Y, ushort_t* __restrict__ O)
{
    __shared__ float ps[4][64];
    int b = blockIdx.x, dg = blockIdx.y;
    int wave = threadIdx.x >> 6, lane = threadIdx.x & 63;
    int d = dg * 64 + lane;
    long base = (long)b * 262144 + d;
    float s = 0.f;
    for (int t = wave * 128; t < wave * 128 + 128; ++t)
        s += Y[base + ((long)t << 9)];
    ps[wave][lane] = s;
    __syncthreads();
    float mean = (ps[0][lane] + ps[1][lane] + ps[2][lane] + ps[3][lane]) * (1.f / 512.f);
    for (int t = wave * 128; t < wave * 128 + 128; ++t)
        O[base + ((long)t << 9)] = f2b(Y[base + ((long)t << 9)] - mean);
}

// head transpose-add: out[b,p,t] += Thead[(b*512+t)*128+p] + b_head[p]
__global__ __launch_bounds__(256)
void headadd_k(const float* __restrict__ Th, const float* __restrict__ bh,
               float* __restrict__ out)
{
    const int id = blockIdx.x;          // b*16 + tc
    const int b = id >> 4, t0 = (id & 15) * 32;
    __shared__ float tile[32][100];
    for (int e = threadIdx.x; e < 32 * 96; e += 256) {
        int tl = e / 96, p = e - tl * 96;
        tile[tl][p] = Th[((long)(b * 512 + t0 + tl)) * 128 + p];
    }
    __syncthreads();
    for (int e = threadIdx.x; e < 96 * 32; e += 256) {
        int p = e >> 5, tl = e & 31;
        out[(long)b * 49152 + p * 512 + t0 + tl] += tile[tl][p] + bh[p];
    }
}

// ===========================================================================
extern "C" void kernel_launch(void* const* d_in, const int* in_sizes, int n_in,
                              void* d_out, int out_size, void* d_ws, size_t ws_size,
                              hipStream_t stream)
{
    const float* x_enc   = (const float*)d_in[0];
    const float* W_trend = (const float*)d_in[4];
    const float* b_trend = (const float*)d_in[5];
    const float* W_emb   = (const float*)d_in[6];
    const float* b_emb   = (const float*)d_in[7];
    const float* Wq      = (const float*)d_in[8];
    const float* bq      = (const float*)d_in[9];
    const float* fw_r    = (const float*)d_in[14];
    const float* fw_i    = (const float*)d_in[15];
    const float* Wo      = (const float*)d_in[16];
    const float* bo      = (const float*)d_in[17];
    const float* W1      = (const float*)d_in[18];
    const float* W2      = (const float*)d_in[19];
    const float* ln_g    = (const float*)d_in[20];
    const float* ln_b    = (const float*)d_in[21];
    const float* W_head  = (const float*)d_in[22];
    const float* b_head  = (const float*)d_in[23];
    float* out = (float*)d_out;
    float* ws  = (float*)d_ws;

    const long F = 8388608;
    float* G    = ws;
    float* X    = ws + 3 * F;
    float* T1   = ws + 4 * F;
    ushort_t* T1b = (ushort_t*)T1;                     // FFN output, bf16
    ushort_t* qT = (ushort_t*)(ws + 5 * F);
    ushort_t* xb = qT + 8388608;

    // start-phase overlays in G (trendb: [0,16MB), seasb: [16MB,32MB))
    ushort_t* trendb = (ushort_t*)G;
    ushort_t* seasb  = (ushort_t*)(G + 4194304);
    // attn-phase overlays in G
    ushort_t* XFTb  = (ushort_t*)G;                    // [0,4MB)
    ushort_t* Yb    = (ushort_t*)(G + 1048576);        // [4,8MB)
    ushort_t* A2    = (ushort_t*)(G + 2097152);        // [8,12MB)
    ushort_t* OSELb = (ushort_t*)(G + 3145728);        // [12,16MB)
    ushort_t* xbT   = (ushort_t*)(G + 4194304);        // [16,32MB)
    ushort_t* B2    = (ushort_t*)(G + 8388608);        // [32,48MB)
    float*    Thead = G;
    ushort_t* gb    = (ushort_t*)G;                    // FFN-phase 64MB

    ushort_t* WembT  = (ushort_t*)(ws + 6 * F);
    ushort_t* WTq    = WembT + 262144;
    ushort_t* WTo    = WTq + 262144;
    ushort_t* W1b    = WTo + 262144;
    ushort_t* W2b    = W1b + 1048576;
    ushort_t* TFb    = W2b + 1048576;
    ushort_t* TI2b   = TFb + 65536;
    ushort_t* WtT    = TI2b + 65536;
    ushort_t* WheadT = WtT + 65536;
    ushort_t* TIWob  = WheadT + 65536;

    dim3 blk(256), blk5(512);

    init_tables_k<<<dim3(512), blk, 0, stream>>>(TFb, TI2b);

    decomp2_k<<<dim3(2048), blk, 0, stream>>>(x_enc, nullptr, seasb, trendb);

    trans_b_k<<<dim3(3, 16, 1), blk, 0, stream>>>(W_trend, WtT, 512, 96, 0L, 0L);
    trans_b_k<<<dim3(3, 16, 1), blk, 0, stream>>>(W_head, WheadT, 512, 96, 0L, 0L);
    trans_b_k<<<dim3(16, 16, 1), blk, 0, stream>>>(W_emb, WembT, 512, 512, 0L, 0L);

    trans_bb_k<<<dim3(16, 16, 32), blk, 0, stream>>>(trendb, qT, 512, 512, 262144L, 262144L);
    mgemm_k<ME_TREND><<<dim3(4, 1, 32), blk5, 0, stream>>>(
        WtT, qT, b_trend, nullptr, out, nullptr,
        128, 512, 512, 512, 0, 0L, 262144L, 49152L, 0L);

    trans_bb_k<<<dim3(16, 16, 32), blk, 0, stream>>>(seasb, qT, 512, 512, 262144L, 262144L);
    mgemm2_k<ME_BIASCOL_DUAL><<<dim3(4, 2, 32), blk5, 0, stream>>>(
        qT, WembT, b_emb, nullptr, X, xb,
        512, 512, 512, 512, 0, 262144L, 0L, 262144L, 0L);

    for (int l = 0; l < 2; ++l) {
        const float* Wq_l = Wq + (long)l * 262144;
        const float* bq_l = bq + (long)l * 512;
        const float* Wo_l = Wo + (long)l * 262144;
        const float* bo_l = bo + (long)l * 512;
        const float* W1_l = W1 + (long)l * 1048576;
        const float* W2_l = W2 + (long)l * 1048576;
        const float* fr_l = fw_r + (long)l * 2097152;
        const float* fi_l = fw_i + (long)l * 2097152;

        trans_b_k<<<dim3(16, 16, 1), blk, 0, stream>>>(Wq_l, WTq, 512, 512, 0L, 0L);
        trans_b_k<<<dim3(16, 16, 1), blk, 0, stream>>>(Wo_l, WTo, 512, 512, 0L, 0L);
        f2b_k<<<dim3(512), blk, 0, stream>>>(W1_l, W1b, 1048576L);
        f2b_k<<<dim3(512), blk, 0, stream>>>(W2_l, W2b, 1048576L);
        bprep_k<<<dim3(512), blk, 0, stream>>>(fr_l, fi_l, B2);

        // TIWob[d,mp] = sum_n WTo[d,n] * TI2b[mp,n]
        mgemm_k<ME_BF16><<<dim3(1, 4, 1), blk5, 0, stream>>>(
            WTo, TI2b, nullptr, nullptr, TIWob, nullptr,
            512, 128, 512, 128, 0, 0L, 0L, 0L, 0L);

        // xbT[b,d,n] = xb[b,n,d]^T
        trans_bb_k<<<dim3(16, 16, 32), blk, 0, stream>>>(xb, xbT, 512, 512, 262144L, 262144L);

        // G1: Yb[b,mp,d] = sum_n TFb[mp,n] * xbT[b,d,n]
        mgemm_k<ME_BF16><<<dim3(4, 1, 32), blk5, 0, stream>>>(
            TFb, xbT, nullptr, nullptr, Yb, nullptr,
            128, 512, 512, 512, 0, 0L, 262144L, 65536L, 0L);

        // G2: XFTb[b,c,mp] = sum_d WTq[c,d] * Yb[b,mp,d]  (+512*bq[c] at mp=0)
        mgemm_k<ME_DCBIAS_BF16><<<dim3(1, 4, 32), blk5, 0, stream>>>(
            WTq, Yb, bq_l, nullptr, XFTb, nullptr,
            512, 128, 512, 128, 0, 0L, 65536L, 65536L, 0L);

        aprep_k<<<dim3(256), blk, 0, stream>>>(XFTb, A2);
        fmix_k<<<dim3(512), blk, 0, stream>>>(A2, B2, OSELb);

        // X += OSEL . TIWo^T + bo
        mgemm2_k<ME_BIASCOL_ACC_F32><<<dim3(4, 64, 1), blk5, 0, stream>>>(
            OSELb, TIWob, bo_l, nullptr, X, nullptr,
            16384, 512, 128, 512, 0, 0L, 0L, 0L, 0L);

        // decomp -> xb bf16 (FFN input + FFN2 residual)
        decomp2_k<<<dim3(2048), blk, 0, stream>>>(X, nullptr, xb, nullptr);

        // FFN, full M=16384
        mgemm2_k<ME_GELU_BF16><<<dim3(16, 64, 1), blk5, 0, stream>>>(
            xb, W1b, nullptr, nullptr, gb, nullptr,
            16384, 2048, 512, 2048, 0, 0L, 0L, 0L, 0L);
        mgemm2_k<ME_RESB_BF16><<<dim3(4, 64, 1), blk5, 0, stream>>>(
            gb, W2b, nullptr, xb, T1b, nullptr,
            16384, 512, 2048, 512, 512, 0L, 0L, 0L, 0L);

        // decomp (bf16 in) -> X f32 (residual/LN) + xb bf16 (next transpose src)
        decomp2h_k<<<dim3(2048), blk, 0, stream>>>(T1b, X, xb);
    }

    // my_layernorm
    ln_rows_k<<<dim3(4096), blk, 0, stream>>>(X, ln_g, ln_b, T1);
    colmean_b16_k<<<dim3(32, 8), blk, 0, stream>>>(T1, xb);

    // head
    mgemm_k<ME_F32><<<dim3(1, 128, 1), blk5, 0, stream>>>(
        xb, WheadT, nullptr, nullptr, Thead, nullptr,
        16384, 128, 512, 128, 0, 0L, 0L, 0L, 0L);

    headadd_k<<<dim3(512), blk, 0, stream>>>(Thead, b_head, out);
}

// Round 10
// 603.109 us; speedup vs baseline: 7.9635x; 1.1409x over previous
//
#include <hip/hip_runtime.h>
#include <math.h>

// ---------------------------------------------------------------------------
// Model_24180665876772  Round 10: revert fat-tile (TLP loss: 72KB LDS -> 2
// blocks/CU vs 48KB -> 3). All big GEMMs on the proven 128^2 3-buf kernel.
// Encoder state fully bf16 (embed/Wo-acc/decomp/LN) -> ~135MB less traffic.
// ---------------------------------------------------------------------------

typedef unsigned short ushort_t;
typedef unsigned int uint_t;
using bf16x8_t = __attribute__((ext_vector_type(8))) short;
using f32x4_t  = __attribute__((ext_vector_type(4))) float;
using u16x8_t  = __attribute__((ext_vector_type(8))) unsigned short;

__device__ __forceinline__ unsigned short f2b(float x) {
    union { float f; uint_t u; } c; c.f = x;
    uint_t r = c.u + 0x7fffu + ((c.u >> 16) & 1u);   // RNE
    return (unsigned short)(r >> 16);
}
__device__ __forceinline__ float b2f(unsigned short h) {
    union { uint_t u; float f; } c; c.u = ((uint_t)h) << 16; return c.f;
}
__device__ __forceinline__ float gelu_exact(float v) {
    return 0.5f * v * (1.0f + erff(v * 0.70710678118654752f));
}

#define GCAST(p) ((const __attribute__((address_space(1))) void*)(p))
#define LCAST(p) ((__attribute__((address_space(3))) void*)(p))

enum { ME_F32 = 0, ME_BF16, ME_DCBIAS_BF16, ME_BIASCOL_BF16,
       ME_BIASCOL_ACCB16, ME_GELU_BF16, ME_RESB_BF16, ME_TREND };

// ---------------- 128x128 GEMM, 8 waves, 3-buf, counted vmcnt --------------
// C[m,n] = sum_k A[m,k]*B[n,k]  (A,B row-major bf16 [*,K])
template<int EPI>
__global__ __launch_bounds__(512)
void mgemm_k(const ushort_t* __restrict__ A, const ushort_t* __restrict__ B,
             const float* __restrict__ bias, const ushort_t* __restrict__ Resb,
             void* __restrict__ Cv,
             int M, int N, int K, int ldc, int ldres,
             long sA, long sB, long sC, long sRes)
{
    const int gx = gridDim.x, gy = gridDim.y;
    const int nwg = gx * gy * gridDim.z;
    const int lin = (blockIdx.z * gy + blockIdx.y) * gx + blockIdx.x;
    const int cpx = nwg >> 3;
    const int swz = (nwg & 7) ? lin : ((lin & 7) * cpx + (lin >> 3));
    const int bx = swz % gx;
    const int t2 = swz / gx;
    const int by = t2 % gy;
    const int bz = t2 / gy;

    A += bz * sA;
    B += bz * sB;
    const int m0 = by * 128, n0 = bx * 128;

    __shared__ __align__(16) ushort_t As[3][4096];
    __shared__ __align__(16) ushort_t Bs[3][4096];

    const int tid = threadIdx.x;
    const int wave = tid >> 6, lane = tid & 63;
    const int wr = wave >> 1, wc = wave & 1;

    f32x4_t acc[2][4] = {};

    const int srow = tid >> 2;
    const int skof = (tid & 3) * 8;

    const ushort_t* ga = A + (long)(m0 + srow) * K + skof;
    const ushort_t* gb = B + (long)(n0 + srow) * K + skof;
    const int nt = K >> 5;

#define STG(s, bidx) { const long ko = (long)(s) << 5; \
    __builtin_amdgcn_global_load_lds(GCAST(ga + ko), LCAST(As[bidx] + wave * 512), 16, 0, 0); \
    __builtin_amdgcn_global_load_lds(GCAST(gb + ko), LCAST(Bs[bidx] + wave * 512), 16, 0, 0); }

    STG(0, 0)
    STG(1, 1)

    const int kg = (lane >> 4) * 8;
    int cb = 0;

    for (int t = 0; t < nt; ++t) {
        if (t + 1 < nt) { asm volatile("s_waitcnt vmcnt(2)" ::: "memory"); }
        else            { asm volatile("s_waitcnt vmcnt(0)" ::: "memory"); }
        __builtin_amdgcn_s_barrier();
        asm volatile("" ::: "memory");
        __builtin_amdgcn_sched_barrier(0);
        if (t + 2 < nt) { int nb = cb + 2; if (nb >= 3) nb -= 3; STG(t + 2, nb) }

        bf16x8_t a[2], b[4];
        #pragma unroll
        for (int i = 0; i < 2; ++i)
            a[i] = *(const bf16x8_t*)&As[cb][(wr * 32 + i * 16 + (lane & 15)) * 32 + kg];
        #pragma unroll
        for (int j = 0; j < 4; ++j)
            b[j] = *(const bf16x8_t*)&Bs[cb][(wc * 64 + j * 16 + (lane & 15)) * 32 + kg];
        #pragma unroll
        for (int i = 0; i < 2; ++i)
            #pragma unroll
            for (int j = 0; j < 4; ++j)
                acc[i][j] = __builtin_amdgcn_mfma_f32_16x16x32_bf16(a[i], b[j], acc[i][j], 0, 0, 0);
        ++cb; if (cb >= 3) cb = 0;
    }
#undef STG

    float*    Cf  = (float*)Cv + bz * sC;
    ushort_t* Cb  = (ushort_t*)Cv + bz * sC;
    const ushort_t* R = Resb ? Resb + bz * sRes : nullptr;

    #pragma unroll
    for (int i = 0; i < 2; ++i) {
        #pragma unroll
        for (int j = 0; j < 4; ++j) {
            #pragma unroll
            for (int r = 0; r < 4; ++r) {
                int gm = m0 + wr * 32 + i * 16 + (lane >> 4) * 4 + r;
                int gn = n0 + wc * 64 + j * 16 + (lane & 15);
                float v = acc[i][j][r];
                long idx = (long)gm * ldc + gn;
                if (EPI == ME_F32)               Cf[idx] = v;
                else if (EPI == ME_BF16)         Cb[idx] = f2b(v);
                else if (EPI == ME_DCBIAS_BF16)  Cb[idx] = f2b(v + (gn == 0 ? 512.f * bias[gm] : 0.f));
                else if (EPI == ME_BIASCOL_BF16) Cb[idx] = f2b(v + bias[gn]);
                else if (EPI == ME_BIASCOL_ACCB16) Cb[idx] = f2b(b2f(Cb[idx]) + v + bias[gn]);
                else if (EPI == ME_GELU_BF16)    Cb[idx] = f2b(gelu_exact(v));
                else if (EPI == ME_RESB_BF16)    Cb[idx] = f2b(v + b2f(R[(long)gm * ldres + gn]));
                else if (EPI == ME_TREND) { if (gm < 96) Cf[idx] = v + bias[gm]; }
            }
        }
    }
}

// ---------------- batched complex mode-mix MFMA (per h,m) ------------------
__global__ __launch_bounds__(256)
void fmix_k(const ushort_t* __restrict__ A2, const ushort_t* __restrict__ B2,
            ushort_t* __restrict__ OS)
{
    const int hm = blockIdx.x;
    const int h = hm >> 6, m = hm & 63;
    __shared__ __align__(16) ushort_t As[32 * 128];
    __shared__ __align__(16) ushort_t Bs[128 * 128];

    const int tid = threadIdx.x;
    const int w = tid >> 6, lane = tid & 63;

    const ushort_t* Ag = A2 + (long)hm * 4096;
    const ushort_t* Bg = B2 + (long)hm * 16384;
    #pragma unroll
    for (int r = 0; r < 2; ++r)
        __builtin_amdgcn_global_load_lds(GCAST(Ag + w * 1024 + r * 512 + lane * 8),
                                         LCAST(As + w * 1024 + r * 512), 16, 0, 0);
    #pragma unroll
    for (int r = 0; r < 8; ++r)
        __builtin_amdgcn_global_load_lds(GCAST(Bg + w * 4096 + r * 512 + lane * 8),
                                         LCAST(Bs + w * 4096 + r * 512), 16, 0, 0);
    __syncthreads();

    f32x4_t acc[2][2] = {};
    const int kg = (lane >> 4) * 8;
    #pragma unroll
    for (int kk = 0; kk < 4; ++kk) {
        bf16x8_t a[2], b[2];
        #pragma unroll
        for (int i = 0; i < 2; ++i)
            a[i] = *(const bf16x8_t*)&As[(i * 16 + (lane & 15)) * 128 + kk * 32 + kg];
        #pragma unroll
        for (int j = 0; j < 2; ++j)
            b[j] = *(const bf16x8_t*)&Bs[(w * 32 + j * 16 + (lane & 15)) * 128 + kk * 32 + kg];
        #pragma unroll
        for (int i = 0; i < 2; ++i)
            #pragma unroll
            for (int j = 0; j < 2; ++j)
                acc[i][j] = __builtin_amdgcn_mfma_f32_16x16x32_bf16(a[i], b[j], acc[i][j], 0, 0, 0);
    }

    #pragma unroll
    for (int i = 0; i < 2; ++i) {
        #pragma unroll
        for (int j = 0; j < 2; ++j) {
            #pragma unroll
            for (int r = 0; r < 4; ++r) {
                int b = i * 16 + (lane >> 4) * 4 + r;
                int n2 = w * 32 + j * 16 + (lane & 15);
                int o = n2 & 63, ri = n2 >> 6;
                OS[((long)b * 512 + h * 64 + o) * 128 + ri * 64 + m] = f2b(acc[i][j][r]);
            }
        }
    }
}

// B2 prep: block per (h,o). Fr/Fi [h][i][o][m] f32 -> B2[h][m][n2][k2] bf16
__global__ __launch_bounds__(256)
void bprep_k(const float* __restrict__ FR, const float* __restrict__ FI,
             ushort_t* __restrict__ B2)
{
    const int bx = blockIdx.x;
    const int h = bx >> 6, o = bx & 63;
    __shared__ float fr_s[64][65];
    __shared__ float fi_s[64][65];
    for (int e = threadIdx.x; e < 4096; e += 256) {
        int i = e >> 6, m = e & 63;
        long src = ((long)(h * 64 + i) * 64 + o) * 64 + m;
        fr_s[i][m] = FR[src];
        fi_s[i][m] = FI[src];
    }
    __syncthreads();
    const int m = threadIdx.x & 63;
    const int kq = threadIdx.x >> 6;
    ushort_t* b0 = B2 + ((long)(h * 64 + m) * 128 + o) * 128;
    ushort_t* b1 = B2 + ((long)(h * 64 + m) * 128 + o + 64) * 128;
    for (int kk = 0; kk < 32; ++kk) {
        int k2 = kq * 32 + kk;
        int ik = k2 & 63, hi = k2 >> 6;
        float fr = fr_s[ik][m], fi = fi_s[ik][m];
        b0[k2] = f2b(hi ? -fi : fr);
        b1[k2] = f2b(hi ?  fr : fi);
    }
}

// A2 prep: block per (b,h). XFTb [b][c=h*64+i][mp] bf16 -> A2[h][m][b][k2] bf16
__global__ __launch_bounds__(256)
void aprep_k(const ushort_t* __restrict__ XFTb, ushort_t* __restrict__ A2)
{
    const int bx = blockIdx.x;
    const int b = bx >> 3, h = bx & 7;
    __shared__ ushort_t xs[64][130];
    for (int e = threadIdx.x; e < 8192; e += 256) {
        int i = e >> 7, mp = e & 127;
        xs[i][mp] = XFTb[((long)b * 512 + h * 64 + i) * 128 + mp];
    }
    __syncthreads();
    const int m = threadIdx.x & 63;
    const int kq = threadIdx.x >> 6;
    ushort_t* dst = A2 + ((long)(h * 64 + m) * 32 + b) * 128;
    for (int kk = 0; kk < 32; ++kk) {
        int k2 = kq * 32 + kk;
        int i = k2 & 63, ri = k2 >> 6;
        dst[k2] = xs[i][ri * 64 + m];
    }
}

// ------------- sliding-window series_decomp (k=25), f32 input --------------
__global__ __launch_bounds__(256)
void decomp2_k(const float* __restrict__ X, ushort_t* __restrict__ Sb,
               ushort_t* __restrict__ Trb)
{
    const int id = blockIdx.x;
    const int ch = id & 1, rc = (id >> 1) & 31, b = id >> 6;
    const int c = ch * 256 + threadIdx.x;
    const int r0 = rc * 16;
    const long base = ((long)b << 18) + c;
    float s = 0.f;
    #pragma unroll
    for (int j = -12; j <= 12; ++j) {
        int rr = r0 + j; rr = rr < 0 ? 0 : (rr > 511 ? 511 : rr);
        s += X[base + ((long)rr << 9)];
    }
    for (int rr = 0; rr < 16; ++rr) {
        int r = r0 + rr;
        float mean = s * (1.f / 25.f);
        long idx = base + ((long)r << 9);
        float x = X[idx];
        if (Sb)  Sb[idx] = f2b(x - mean);
        if (Trb) Trb[idx] = f2b(mean);
        int rp = r + 13; rp = rp > 511 ? 511 : rp;
        int rm = r - 12; rm = rm < 0 ? 0 : rm;
        s += X[base + ((long)rp << 9)] - X[base + ((long)rm << 9)];
    }
}

// ------------- sliding-window series_decomp (k=25), bf16 in/out ------------
__global__ __launch_bounds__(256)
void decomp2h_k(const ushort_t* __restrict__ Xb, ushort_t* __restrict__ Sb)
{
    const int id = blockIdx.x;
    const int ch = id & 1, rc = (id >> 1) & 31, b = id >> 6;
    const int c = ch * 256 + threadIdx.x;
    const int r0 = rc * 16;
    const long base = ((long)b << 18) + c;
    float s = 0.f;
    #pragma unroll
    for (int j = -12; j <= 12; ++j) {
        int rr = r0 + j; rr = rr < 0 ? 0 : (rr > 511 ? 511 : rr);
        s += b2f(Xb[base + ((long)rr << 9)]);
    }
    for (int rr = 0; rr < 16; ++rr) {
        int r = r0 + rr;
        float mean = s * (1.f / 25.f);
        long idx = base + ((long)r << 9);
        float x = b2f(Xb[idx]);
        Sb[idx] = f2b(x - mean);
        int rp = r + 13; rp = rp > 511 ? 511 : rp;
        int rm = r - 12; rm = rm < 0 ? 0 : rm;
        s += b2f(Xb[base + ((long)rp << 9)]) - b2f(Xb[base + ((long)rm << 9)]);
    }
}

// ----------------------- bf16 DFT tables -----------------------------------
__global__ __launch_bounds__(256)
void init_tables_k(ushort_t* __restrict__ TFb, ushort_t* __restrict__ TI2b)
{
    int t = blockIdx.x * 256 + threadIdx.x;   // 0..131071
    const float w = 6.283185307179586f / 512.f;
    if (t < 65536) {
        int mp = t >> 9, n = t & 511;
        int m = mp & 63;
        float ang = ((m * n) & 511) * w;
        TFb[t] = f2b((mp < 64) ? cosf(ang) : -sinf(ang));
    } else {
        int u = t - 65536;
        int mp = u >> 9, n = u & 511;
        int m = mp & 63;
        float ang = ((m * n) & 511) * w;
        float v;
        if (mp < 64) v = (m == 0) ? (1.f / 512.f) : (2.f / 512.f) * cosf(ang);
        else         v = (m == 0) ? 0.f : -(2.f / 512.f) * sinf(ang);
        TI2b[u] = f2b(v);
    }
}

// ----------------------- fp32 -> bf16 convert (weights) --------------------
__global__ __launch_bounds__(256)
void f2b_k(const float* __restrict__ X, ushort_t* __restrict__ Y, long n)
{
    long i = ((long)blockIdx.x * 256 + threadIdx.x) * 8;
    if (i >= n) return;
    const float4* xp = (const float4*)(X + i);
    float4 v0 = xp[0], v1 = xp[1];
    u16x8_t o;
    o[0] = f2b(v0.x); o[1] = f2b(v0.y); o[2] = f2b(v0.z); o[3] = f2b(v0.w);
    o[4] = f2b(v1.x); o[5] = f2b(v1.y); o[6] = f2b(v1.z); o[7] = f2b(v1.w);
    *(u16x8_t*)(Y + i) = o;
}

// ----------------- fp32 [R,C] -> bf16 transposed [C,R] ---------------------
__global__ __launch_bounds__(256)
void trans_b_k(const float* __restrict__ X, ushort_t* __restrict__ Y,
               int R, int C, long sX, long sY)
{
    __shared__ float t[32][33];
    X += (long)blockIdx.z * sX;
    Y += (long)blockIdx.z * sY;
    int r0 = blockIdx.y * 32, c0 = blockIdx.x * 32;
    int tx = threadIdx.x & 31, ty = threadIdx.x >> 5;
    #pragma unroll
    for (int i = ty; i < 32; i += 8)
        t[i][tx] = X[(long)(r0 + i) * C + c0 + tx];
    __syncthreads();
    #pragma unroll
    for (int i = ty; i < 32; i += 8)
        Y[(long)(c0 + i) * R + r0 + tx] = f2b(t[tx][i]);
}

// ----------------- bf16 [R,C] -> bf16 transposed [C,R] ---------------------
__global__ __launch_bounds__(256)
void trans_bb_k(const ushort_t* __restrict__ X, ushort_t* __restrict__ Y,
                int R, int C, long sX, long sY)
{
    __shared__ ushort_t t[32][34];
    X += (long)blockIdx.z * sX;
    Y += (long)blockIdx.z * sY;
    int r0 = blockIdx.y * 32, c0 = blockIdx.x * 32;
    int tx = threadIdx.x & 31, ty = threadIdx.x >> 5;
    #pragma unroll
    for (int i = ty; i < 32; i += 8)
        t[i][tx] = X[(long)(r0 + i) * C + c0 + tx];
    __syncthreads();
    #pragma unroll
    for (int i = ty; i < 32; i += 8)
        Y[(long)(c0 + i) * R + r0 + tx] = t[tx][i];
}

// --------------------- layernorm (bf16 in/out, f32 math) -------------------
__global__ __launch_bounds__(256)
void ln_rows_bb_k(const ushort_t* __restrict__ Xb, const float* __restrict__ g,
                  const float* __restrict__ bta, ushort_t* __restrict__ Yb)
{
    int wave = threadIdx.x >> 6, lane = threadIdx.x & 63;
    long row = (long)blockIdx.x * 4 + wave;
    const ushort_t* x = Xb + row * 512 + lane * 8;
    u16x8_t v = *(const u16x8_t*)x;
    float f[8];
    float s = 0.f, ss = 0.f;
    #pragma unroll
    for (int j = 0; j < 8; ++j) { f[j] = b2f(v[j]); s += f[j]; ss += f[j] * f[j]; }
    #pragma unroll
    for (int o = 32; o; o >>= 1) { s += __shfl_xor(s, o); ss += __shfl_xor(ss, o); }
    float mu = s * (1.f / 512.f);
    float var = ss * (1.f / 512.f) - mu * mu;
    float inv = rsqrtf(var + 1e-5f);
    u16x8_t ov;
    #pragma unroll
    for (int j = 0; j < 8; ++j)
        ov[j] = f2b((f[j] - mu) * inv * g[lane * 8 + j] + bta[lane * 8 + j]);
    *(u16x8_t*)(Yb + row * 512 + lane * 8) = ov;
}

// subtract per-(b,d) seq-mean, bf16 in/out (4 waves split the t-loop)
__global__ __launch_bounds__(256)
void colmean_bb_k(const ushort_t* __restrict__ Y, ushort_t* __restrict__ O)
{
    __shared__ float ps[4][64];
    int b = blockIdx.x, dg = blockIdx.y;
    int wave = threadIdx.x >> 6, lane = threadIdx.x & 63;
    int d = dg * 64 + lane;
    long base = (long)b * 262144 + d;
    float s = 0.f;
    for (int t = wave * 128; t < wave * 128 + 128; ++t)
        s += b2f(Y[base + ((long)t << 9)]);
    ps[wave][lane] = s;
    __syncthreads();
    float mean = (ps[0][lane] + ps[1][lane] + ps[2][lane] + ps[3][lane]) * (1.f / 512.f);
    for (int t = wave * 128; t < wave * 128 + 128; ++t)
        O[base + ((long)t << 9)] = f2b(b2f(Y[base + ((long)t << 9)]) - mean);
}

// head transpose-add: out[b,p,t] += Thead[(b*512+t)*128+p] + b_head[p]
__global__ __launch_bounds__(256)
void headadd_k(const float* __restrict__ Th, const float* __restrict__ bh,
               float* __restrict__ out)
{
    const int id = blockIdx.x;          // b*16 + tc
    const int b = id >> 4, t0 = (id & 15) * 32;
    __shared__ float tile[32][100];
    for (int e = threadIdx.x; e < 32 * 96; e += 256) {
        int tl = e / 96, p = e - tl * 96;
        tile[tl][p] = Th[((long)(b * 512 + t0 + tl)) * 128 + p];
    }
    __syncthreads();
    for (int e = threadIdx.x; e < 96 * 32; e += 256) {
        int p = e >> 5, tl = e & 31;
        out[(long)b * 49152 + p * 512 + t0 + tl] += tile[tl][p] + bh[p];
    }
}

// ===========================================================================
extern "C" void kernel_launch(void* const* d_in, const int* in_sizes, int n_in,
                              void* d_out, int out_size, void* d_ws, size_t ws_size,
                              hipStream_t stream)
{
    const float* x_enc   = (const float*)d_in[0];
    const float* W_trend = (const float*)d_in[4];
    const float* b_trend = (const float*)d_in[5];
    const float* W_emb   = (const float*)d_in[6];
    const float* b_emb   = (const float*)d_in[7];
    const float* Wq      = (const float*)d_in[8];
    const float* bq      = (const float*)d_in[9];
    const float* fw_r    = (const float*)d_in[14];
    const float* fw_i    = (const float*)d_in[15];
    const float* Wo      = (const float*)d_in[16];
    const float* bo      = (const float*)d_in[17];
    const float* W1      = (const float*)d_in[18];
    const float* W2      = (const float*)d_in[19];
    const float* ln_g    = (const float*)d_in[20];
    const float* ln_b    = (const float*)d_in[21];
    const float* W_head  = (const float*)d_in[22];
    const float* b_head  = (const float*)d_in[23];
    float* out = (float*)d_out;
    float* ws  = (float*)d_ws;

    const long F = 8388608;
    // [0..2F)   G: phase-overlaid scratch (64 MB)
    // [3F..4F)  xw bf16 state (16MB) | free
    // [4F..5F)  xs bf16 (16MB) + T1b bf16 (16MB)
    // [5F..6F)  qT bf16 (16MB)
    // [6F..)    weights bf16
    float* G    = ws;
    ushort_t* xw  = (ushort_t*)(ws + 3 * F);           // encoder state bf16
    ushort_t* xs  = (ushort_t*)(ws + 4 * F);           // seasonal / FFN residual
    ushort_t* T1b = xs + 8388608;                      // FFN out / LN out
    ushort_t* qT  = (ushort_t*)(ws + 5 * F);

    // start-phase overlays in G (trendb: [0,16MB), seasb: [16MB,32MB))
    ushort_t* trendb = (ushort_t*)G;
    ushort_t* seasb  = (ushort_t*)(G + 4194304);
    // attn-phase overlays in G
    ushort_t* XFTb  = (ushort_t*)G;                    // [0,4MB)
    ushort_t* Yb    = (ushort_t*)(G + 1048576);        // [4,8MB)
    ushort_t* A2    = (ushort_t*)(G + 2097152);        // [8,12MB)
    ushort_t* OSELb = (ushort_t*)(G + 3145728);        // [12,16MB)
    ushort_t* xbT   = (ushort_t*)(G + 4194304);        // [16,32MB)
    ushort_t* B2    = (ushort_t*)(G + 8388608);        // [32,48MB)
    float*    Thead = G;
    ushort_t* gb    = (ushort_t*)G;                    // FFN-phase 64MB

    ushort_t* WembT  = (ushort_t*)(ws + 6 * F);
    ushort_t* WTq    = WembT + 262144;
    ushort_t* WTo    = WTq + 262144;
    ushort_t* W1b    = WTo + 262144;
    ushort_t* W2b    = W1b + 1048576;
    ushort_t* TFb    = W2b + 1048576;
    ushort_t* TI2b   = TFb + 65536;
    ushort_t* WtT    = TI2b + 65536;
    ushort_t* WheadT = WtT + 65536;
    ushort_t* TIWob  = WheadT + 65536;

    dim3 blk(256), blk5(512);

    init_tables_k<<<dim3(512), blk, 0, stream>>>(TFb, TI2b);

    decomp2_k<<<dim3(2048), blk, 0, stream>>>(x_enc, seasb, trendb);

    trans_b_k<<<dim3(3, 16, 1), blk, 0, stream>>>(W_trend, WtT, 512, 96, 0L, 0L);
    trans_b_k<<<dim3(3, 16, 1), blk, 0, stream>>>(W_head, WheadT, 512, 96, 0L, 0L);
    trans_b_k<<<dim3(16, 16, 1), blk, 0, stream>>>(W_emb, WembT, 512, 512, 0L, 0L);

    // trendT bf16 into qT slot, trend head GEMM -> out
    trans_bb_k<<<dim3(16, 16, 32), blk, 0, stream>>>(trendb, qT, 512, 512, 262144L, 262144L);
    mgemm_k<ME_TREND><<<dim3(4, 1, 32), blk5, 0, stream>>>(
        WtT, qT, b_trend, nullptr, out,
        128, 512, 512, 512, 0, 0L, 262144L, 49152L, 0L);

    // seasonalT bf16 into qT slot; embedding -> xw bf16
    trans_bb_k<<<dim3(16, 16, 32), blk, 0, stream>>>(seasb, qT, 512, 512, 262144L, 262144L);
    mgemm_k<ME_BIASCOL_BF16><<<dim3(4, 4, 32), blk5, 0, stream>>>(
        qT, WembT, b_emb, nullptr, xw,
        512, 512, 512, 512, 0, 262144L, 0L, 262144L, 0L);

    for (int l = 0; l < 2; ++l) {
        const float* Wq_l = Wq + (long)l * 262144;
        const float* bq_l = bq + (long)l * 512;
        const float* Wo_l = Wo + (long)l * 262144;
        const float* bo_l = bo + (long)l * 512;
        const float* W1_l = W1 + (long)l * 1048576;
        const float* W2_l = W2 + (long)l * 1048576;
        const float* fr_l = fw_r + (long)l * 2097152;
        const float* fi_l = fw_i + (long)l * 2097152;

        trans_b_k<<<dim3(16, 16, 1), blk, 0, stream>>>(Wq_l, WTq, 512, 512, 0L, 0L);
        trans_b_k<<<dim3(16, 16, 1), blk, 0, stream>>>(Wo_l, WTo, 512, 512, 0L, 0L);
        f2b_k<<<dim3(512), blk, 0, stream>>>(W1_l, W1b, 1048576L);
        f2b_k<<<dim3(512), blk, 0, stream>>>(W2_l, W2b, 1048576L);
        bprep_k<<<dim3(512), blk, 0, stream>>>(fr_l, fi_l, B2);

        // TIWob[d,mp] = sum_n WTo[d,n] * TI2b[mp,n]
        mgemm_k<ME_BF16><<<dim3(1, 4, 1), blk5, 0, stream>>>(
            WTo, TI2b, nullptr, nullptr, TIWob,
            512, 128, 512, 128, 0, 0L, 0L, 0L, 0L);

        // xbT[b,d,n] = xw[b,n,d]^T
        trans_bb_k<<<dim3(16, 16, 32), blk, 0, stream>>>(xw, xbT, 512, 512, 262144L, 262144L);

        // G1: Yb[b,mp,d] = sum_n TFb[mp,n] * xbT[b,d,n]
        mgemm_k<ME_BF16><<<dim3(4, 1, 32), blk5, 0, stream>>>(
            TFb, xbT, nullptr, nullptr, Yb,
            128, 512, 512, 512, 0, 0L, 262144L, 65536L, 0L);

        // G2: XFTb[b,c,mp] = sum_d WTq[c,d] * Yb[b,mp,d]  (+512*bq[c] at mp=0)
        mgemm_k<ME_DCBIAS_BF16><<<dim3(1, 4, 32), blk5, 0, stream>>>(
            WTq, Yb, bq_l, nullptr, XFTb,
            512, 128, 512, 128, 0, 0L, 65536L, 65536L, 0L);

        aprep_k<<<dim3(256), blk, 0, stream>>>(XFTb, A2);
        fmix_k<<<dim3(512), blk, 0, stream>>>(A2, B2, OSELb);

        // xw += OSEL . TIWo^T + bo   (bf16 RMW)
        mgemm_k<ME_BIASCOL_ACCB16><<<dim3(4, 128, 1), blk5, 0, stream>>>(
            OSELb, TIWob, bo_l, nullptr, xw,
            16384, 512, 128, 512, 0, 0L, 0L, 0L, 0L);

        // decomp (bf16) -> xs (FFN input + FFN2 residual)
        decomp2h_k<<<dim3(2048), blk, 0, stream>>>(xw, xs);

        // FFN, full M=16384
        mgemm_k<ME_GELU_BF16><<<dim3(16, 128, 1), blk5, 0, stream>>>(
            xs, W1b, nullptr, nullptr, gb,
            16384, 2048, 512, 2048, 0, 0L, 0L, 0L, 0L);
        mgemm_k<ME_RESB_BF16><<<dim3(4, 128, 1), blk5, 0, stream>>>(
            gb, W2b, nullptr, xs, T1b,
            16384, 512, 2048, 512, 512, 0L, 0L, 0L, 0L);

        // decomp (bf16) -> xw (next layer state / LN input)
        decomp2h_k<<<dim3(2048), blk, 0, stream>>>(T1b, xw);
    }

    // my_layernorm (bf16): rows -> T1b, colmean-subtract -> xs
    ln_rows_bb_k<<<dim3(4096), blk, 0, stream>>>(xw, ln_g, ln_b, T1b);
    colmean_bb_k<<<dim3(32, 8), blk, 0, stream>>>(T1b, xs);

    // head
    mgemm_k<ME_F32><<<dim3(1, 128, 1), blk5, 0, stream>>>(
        xs, WheadT, nullptr, nullptr, Thead,
        16384, 128, 512, 128, 0, 0L, 0L, 0L, 0L);

    headadd_k<<<dim3(512), blk, 0, stream>>>(Thead, b_head, out);
}

// Round 11
// 564.936 us; speedup vs baseline: 8.5016x; 1.0676x over previous
//
#include <hip/hip_runtime.h>
#include <math.h>

// ---------------------------------------------------------------------------
// Model_24180665876772  Round 11: 64x64 small-GEMM variant (TLP for the
// latency-bound GEMMs), hoisted/batched weight prep, vectorized bf16 decomp,
// fast sigmoid-GELU (exact-erf replaced; |err| ~5e-4 << bf16 rounding).
// ---------------------------------------------------------------------------

typedef unsigned short ushort_t;
typedef unsigned int uint_t;
using bf16x8_t = __attribute__((ext_vector_type(8))) short;
using f32x4_t  = __attribute__((ext_vector_type(4))) float;
using u16x8_t  = __attribute__((ext_vector_type(8))) unsigned short;

__device__ __forceinline__ unsigned short f2b(float x) {
    union { float f; uint_t u; } c; c.f = x;
    uint_t r = c.u + 0x7fffu + ((c.u >> 16) & 1u);   // RNE
    return (unsigned short)(r >> 16);
}
__device__ __forceinline__ float b2f(unsigned short h) {
    union { uint_t u; float f; } c; c.u = ((uint_t)h) << 16; return c.f;
}
// tanh-form GELU via sigmoid: gelu(x) ~= x * sigmoid(1.59577x + 0.0713548x^3)
__device__ __forceinline__ float gelu_fast(float x) {
    float z = x * (1.5957691216f + 0.0713548163f * x * x);
    return x / (1.f + __expf(-z));
}

#define GCAST(p) ((const __attribute__((address_space(1))) void*)(p))
#define LCAST(p) ((__attribute__((address_space(3))) void*)(p))

enum { ME_F32 = 0, ME_BF16, ME_DCBIAS_BF16, ME_BIASCOL_BF16,
       ME_BIASCOL_ACCB16, ME_GELU_BF16, ME_RESB_BF16, ME_TREND };

// ---------------- 128x128 GEMM, 8 waves, 3-buf, counted vmcnt --------------
template<int EPI>
__global__ __launch_bounds__(512)
void mgemm_k(const ushort_t* __restrict__ A, const ushort_t* __restrict__ B,
             const float* __restrict__ bias, const ushort_t* __restrict__ Resb,
             void* __restrict__ Cv,
             int M, int N, int K, int ldc, int ldres,
             long sA, long sB, long sC, long sRes)
{
    const int gx = gridDim.x, gy = gridDim.y;
    const int nwg = gx * gy * gridDim.z;
    const int lin = (blockIdx.z * gy + blockIdx.y) * gx + blockIdx.x;
    const int cpx = nwg >> 3;
    const int swz = (nwg & 7) ? lin : ((lin & 7) * cpx + (lin >> 3));
    const int bx = swz % gx;
    const int t2 = swz / gx;
    const int by = t2 % gy;
    const int bz = t2 / gy;

    A += bz * sA;
    B += bz * sB;
    const int m0 = by * 128, n0 = bx * 128;

    __shared__ __align__(16) ushort_t As[3][4096];
    __shared__ __align__(16) ushort_t Bs[3][4096];

    const int tid = threadIdx.x;
    const int wave = tid >> 6, lane = tid & 63;
    const int wr = wave >> 1, wc = wave & 1;

    f32x4_t acc[2][4] = {};

    const int srow = tid >> 2;
    const int skof = (tid & 3) * 8;

    const ushort_t* ga = A + (long)(m0 + srow) * K + skof;
    const ushort_t* gb = B + (long)(n0 + srow) * K + skof;
    const int nt = K >> 5;

#define STG(s, bidx) { const long ko = (long)(s) << 5; \
    __builtin_amdgcn_global_load_lds(GCAST(ga + ko), LCAST(As[bidx] + wave * 512), 16, 0, 0); \
    __builtin_amdgcn_global_load_lds(GCAST(gb + ko), LCAST(Bs[bidx] + wave * 512), 16, 0, 0); }

    STG(0, 0)
    STG(1, 1)

    const int kg = (lane >> 4) * 8;
    int cb = 0;

    for (int t = 0; t < nt; ++t) {
        if (t + 1 < nt) { asm volatile("s_waitcnt vmcnt(2)" ::: "memory"); }
        else            { asm volatile("s_waitcnt vmcnt(0)" ::: "memory"); }
        __builtin_amdgcn_s_barrier();
        asm volatile("" ::: "memory");
        __builtin_amdgcn_sched_barrier(0);
        if (t + 2 < nt) { int nb = cb + 2; if (nb >= 3) nb -= 3; STG(t + 2, nb) }

        bf16x8_t a[2], b[4];
        #pragma unroll
        for (int i = 0; i < 2; ++i)
            a[i] = *(const bf16x8_t*)&As[cb][(wr * 32 + i * 16 + (lane & 15)) * 32 + kg];
        #pragma unroll
        for (int j = 0; j < 4; ++j)
            b[j] = *(const bf16x8_t*)&Bs[cb][(wc * 64 + j * 16 + (lane & 15)) * 32 + kg];
        #pragma unroll
        for (int i = 0; i < 2; ++i)
            #pragma unroll
            for (int j = 0; j < 4; ++j)
                acc[i][j] = __builtin_amdgcn_mfma_f32_16x16x32_bf16(a[i], b[j], acc[i][j], 0, 0, 0);
        ++cb; if (cb >= 3) cb = 0;
    }
#undef STG

    float*    Cf  = (float*)Cv + bz * sC;
    ushort_t* Cb  = (ushort_t*)Cv + bz * sC;
    const ushort_t* R = Resb ? Resb + bz * sRes : nullptr;

    #pragma unroll
    for (int i = 0; i < 2; ++i) {
        #pragma unroll
        for (int j = 0; j < 4; ++j) {
            #pragma unroll
            for (int r = 0; r < 4; ++r) {
                int gm = m0 + wr * 32 + i * 16 + (lane >> 4) * 4 + r;
                int gn = n0 + wc * 64 + j * 16 + (lane & 15);
                float v = acc[i][j][r];
                long idx = (long)gm * ldc + gn;
                if (EPI == ME_F32)               Cf[idx] = v;
                else if (EPI == ME_BF16)         Cb[idx] = f2b(v);
                else if (EPI == ME_BIASCOL_BF16) Cb[idx] = f2b(v + bias[gn]);
                else if (EPI == ME_BIASCOL_ACCB16) Cb[idx] = f2b(b2f(Cb[idx]) + v + bias[gn]);
                else if (EPI == ME_GELU_BF16)    Cb[idx] = f2b(gelu_fast(v));
                else if (EPI == ME_RESB_BF16)    Cb[idx] = f2b(v + b2f(R[(long)gm * ldres + gn]));
            }
        }
    }
}

// ---------------- 64x64 GEMM, 4 waves, 3-buf (latency-bound shapes) --------
template<int EPI>
__global__ __launch_bounds__(256)
void sgemm_k(const ushort_t* __restrict__ A, const ushort_t* __restrict__ B,
             const float* __restrict__ bias, void* __restrict__ Cv,
             int M, int N, int K, int ldc,
             long sA, long sB, long sC)
{
    const int gx = gridDim.x, gy = gridDim.y;
    const int nwg = gx * gy * gridDim.z;
    const int lin = (blockIdx.z * gy + blockIdx.y) * gx + blockIdx.x;
    const int cpx = nwg >> 3;
    const int swz = (nwg & 7) ? lin : ((lin & 7) * cpx + (lin >> 3));
    const int bx = swz % gx;
    const int t2 = swz / gx;
    const int by = t2 % gy;
    const int bz = t2 / gy;

    A += bz * sA;
    B += bz * sB;
    const int m0 = by * 64, n0 = bx * 64;

    __shared__ __align__(16) ushort_t As[3][2048];
    __shared__ __align__(16) ushort_t Bs[3][2048];

    const int tid = threadIdx.x;
    const int wave = tid >> 6, lane = tid & 63;
    const int wr = wave >> 1, wc = wave & 1;

    f32x4_t acc[2][2] = {};

    const int srow = tid >> 2;           // 0..63
    const int skof = (tid & 3) * 8;

    const ushort_t* ga = A + (long)(m0 + srow) * K + skof;
    const ushort_t* gb = B + (long)(n0 + srow) * K + skof;
    const int nt = K >> 5;

#define STG(s, bidx) { const long ko = (long)(s) << 5; \
    __builtin_amdgcn_global_load_lds(GCAST(ga + ko), LCAST(As[bidx] + wave * 512), 16, 0, 0); \
    __builtin_amdgcn_global_load_lds(GCAST(gb + ko), LCAST(Bs[bidx] + wave * 512), 16, 0, 0); }

    STG(0, 0)
    STG(1, 1)

    const int kg = (lane >> 4) * 8;
    int cb = 0;

    for (int t = 0; t < nt; ++t) {
        if (t + 1 < nt) { asm volatile("s_waitcnt vmcnt(2)" ::: "memory"); }
        else            { asm volatile("s_waitcnt vmcnt(0)" ::: "memory"); }
        __builtin_amdgcn_s_barrier();
        asm volatile("" ::: "memory");
        __builtin_amdgcn_sched_barrier(0);
        if (t + 2 < nt) { int nb = cb + 2; if (nb >= 3) nb -= 3; STG(t + 2, nb) }

        bf16x8_t a[2], b[2];
        #pragma unroll
        for (int i = 0; i < 2; ++i)
            a[i] = *(const bf16x8_t*)&As[cb][(wr * 32 + i * 16 + (lane & 15)) * 32 + kg];
        #pragma unroll
        for (int j = 0; j < 2; ++j)
            b[j] = *(const bf16x8_t*)&Bs[cb][(wc * 32 + j * 16 + (lane & 15)) * 32 + kg];
        #pragma unroll
        for (int i = 0; i < 2; ++i)
            #pragma unroll
            for (int j = 0; j < 2; ++j)
                acc[i][j] = __builtin_amdgcn_mfma_f32_16x16x32_bf16(a[i], b[j], acc[i][j], 0, 0, 0);
        ++cb; if (cb >= 3) cb = 0;
    }
#undef STG

    float*    Cf = (float*)Cv + bz * sC;
    ushort_t* Cb = (ushort_t*)Cv + bz * sC;

    #pragma unroll
    for (int i = 0; i < 2; ++i) {
        #pragma unroll
        for (int j = 0; j < 2; ++j) {
            #pragma unroll
            for (int r = 0; r < 4; ++r) {
                int gm = m0 + wr * 32 + i * 16 + (lane >> 4) * 4 + r;
                int gn = n0 + wc * 32 + j * 16 + (lane & 15);
                float v = acc[i][j][r];
                long idx = (long)gm * ldc + gn;
                if (EPI == ME_F32)               Cf[idx] = v;
                else if (EPI == ME_BF16)         Cb[idx] = f2b(v);
                else if (EPI == ME_DCBIAS_BF16)  Cb[idx] = f2b(v + (gn == 0 ? 512.f * bias[gm] : 0.f));
                else if (EPI == ME_TREND) { if (gm < 96) Cf[idx] = v + bias[gm]; }
            }
        }
    }
}

// ---------------- batched complex mode-mix MFMA (per h,m) ------------------
__global__ __launch_bounds__(256)
void fmix_k(const ushort_t* __restrict__ A2, const ushort_t* __restrict__ B2,
            ushort_t* __restrict__ OS)
{
    const int hm = blockIdx.x;
    const int h = hm >> 6, m = hm & 63;
    __shared__ __align__(16) ushort_t As[32 * 128];
    __shared__ __align__(16) ushort_t Bs[128 * 128];

    const int tid = threadIdx.x;
    const int w = tid >> 6, lane = tid & 63;

    const ushort_t* Ag = A2 + (long)hm * 4096;
    const ushort_t* Bg = B2 + (long)hm * 16384;
    #pragma unroll
    for (int r = 0; r < 2; ++r)
        __builtin_amdgcn_global_load_lds(GCAST(Ag + w * 1024 + r * 512 + lane * 8),
                                         LCAST(As + w * 1024 + r * 512), 16, 0, 0);
    #pragma unroll
    for (int r = 0; r < 8; ++r)
        __builtin_amdgcn_global_load_lds(GCAST(Bg + w * 4096 + r * 512 + lane * 8),
                                         LCAST(Bs + w * 4096 + r * 512), 16, 0, 0);
    __syncthreads();

    f32x4_t acc[2][2] = {};
    const int kg = (lane >> 4) * 8;
    #pragma unroll
    for (int kk = 0; kk < 4; ++kk) {
        bf16x8_t a[2], b[2];
        #pragma unroll
        for (int i = 0; i < 2; ++i)
            a[i] = *(const bf16x8_t*)&As[(i * 16 + (lane & 15)) * 128 + kk * 32 + kg];
        #pragma unroll
        for (int j = 0; j < 2; ++j)
            b[j] = *(const bf16x8_t*)&Bs[(w * 32 + j * 16 + (lane & 15)) * 128 + kk * 32 + kg];
        #pragma unroll
        for (int i = 0; i < 2; ++i)
            #pragma unroll
            for (int j = 0; j < 2; ++j)
                acc[i][j] = __builtin_amdgcn_mfma_f32_16x16x32_bf16(a[i], b[j], acc[i][j], 0, 0, 0);
    }

    #pragma unroll
    for (int i = 0; i < 2; ++i) {
        #pragma unroll
        for (int j = 0; j < 2; ++j) {
            #pragma unroll
            for (int r = 0; r < 4; ++r) {
                int b = i * 16 + (lane >> 4) * 4 + r;
                int n2 = w * 32 + j * 16 + (lane & 15);
                int o = n2 & 63, ri = n2 >> 6;
                OS[((long)b * 512 + h * 64 + o) * 128 + ri * 64 + m] = f2b(acc[i][j][r]);
            }
        }
    }
}

// B2 prep: block per (h,o). Fr/Fi [h][i][o][m] f32 -> B2[h][m][n2][k2] bf16
__global__ __launch_bounds__(256)
void bprep_k(const float* __restrict__ FR, const float* __restrict__ FI,
             ushort_t* __restrict__ B2)
{
    const int bx = blockIdx.x;
    const int h = bx >> 6, o = bx & 63;
    __shared__ float fr_s[64][65];
    __shared__ float fi_s[64][65];
    for (int e = threadIdx.x; e < 4096; e += 256) {
        int i = e >> 6, m = e & 63;
        long src = ((long)(h * 64 + i) * 64 + o) * 64 + m;
        fr_s[i][m] = FR[src];
        fi_s[i][m] = FI[src];
    }
    __syncthreads();
    const int m = threadIdx.x & 63;
    const int kq = threadIdx.x >> 6;
    ushort_t* b0 = B2 + ((long)(h * 64 + m) * 128 + o) * 128;
    ushort_t* b1 = B2 + ((long)(h * 64 + m) * 128 + o + 64) * 128;
    for (int kk = 0; kk < 32; ++kk) {
        int k2 = kq * 32 + kk;
        int ik = k2 & 63, hi = k2 >> 6;
        float fr = fr_s[ik][m], fi = fi_s[ik][m];
        b0[k2] = f2b(hi ? -fi : fr);
        b1[k2] = f2b(hi ?  fr : fi);
    }
}

// A2 prep: block per (b,h). XFTb [b][c=h*64+i][mp] bf16 -> A2[h][m][b][k2] bf16
__global__ __launch_bounds__(256)
void aprep_k(const ushort_t* __restrict__ XFTb, ushort_t* __restrict__ A2)
{
    const int bx = blockIdx.x;
    const int b = bx >> 3, h = bx & 7;
    __shared__ ushort_t xs[64][130];
    for (int e = threadIdx.x; e < 8192; e += 256) {
        int i = e >> 7, mp = e & 127;
        xs[i][mp] = XFTb[((long)b * 512 + h * 64 + i) * 128 + mp];
    }
    __syncthreads();
    const int m = threadIdx.x & 63;
    const int kq = threadIdx.x >> 6;
    ushort_t* dst = A2 + ((long)(h * 64 + m) * 32 + b) * 128;
    for (int kk = 0; kk < 32; ++kk) {
        int k2 = kq * 32 + kk;
        int i = k2 & 63, ri = k2 >> 6;
        dst[k2] = xs[i][ri * 64 + m];
    }
}

// ------------- sliding-window series_decomp (k=25), f32 input --------------
__global__ __launch_bounds__(256)
void decomp2_k(const float* __restrict__ X, ushort_t* __restrict__ Sb,
               ushort_t* __restrict__ Trb)
{
    const int id = blockIdx.x;
    const int ch = id & 1, rc = (id >> 1) & 31, b = id >> 6;
    const int c = ch * 256 + threadIdx.x;
    const int r0 = rc * 16;
    const long base = ((long)b << 18) + c;
    float s = 0.f;
    #pragma unroll
    for (int j = -12; j <= 12; ++j) {
        int rr = r0 + j; rr = rr < 0 ? 0 : (rr > 511 ? 511 : rr);
        s += X[base + ((long)rr << 9)];
    }
    for (int rr = 0; rr < 16; ++rr) {
        int r = r0 + rr;
        float mean = s * (1.f / 25.f);
        long idx = base + ((long)r << 9);
        float x = X[idx];
        if (Sb)  Sb[idx] = f2b(x - mean);
        if (Trb) Trb[idx] = f2b(mean);
        int rp = r + 13; rp = rp > 511 ? 511 : rp;
        int rm = r - 12; rm = rm < 0 ? 0 : rm;
        s += X[base + ((long)rp << 9)] - X[base + ((long)rm << 9)];
    }
}

// ------- sliding-window series_decomp (k=25), bf16 in/out, vectorized ------
// grid 512: b(32) x rc(16); thread: 8 cols (u16x8) x 8 rows
__global__ __launch_bounds__(256)
void decomp2v_k(const ushort_t* __restrict__ Xb, ushort_t* __restrict__ Sb)
{
    const int id = blockIdx.x;
    const int b = id >> 4, rc = id & 15;
    const int c0 = (threadIdx.x & 63) * 8;
    const int rsub = threadIdx.x >> 6;
    const int r0 = rc * 32 + rsub * 8;
    const ushort_t* base = Xb + ((long)b << 18) + c0;
    ushort_t* obase = Sb + ((long)b << 18) + c0;

    float s[8] = {};
    #pragma unroll
    for (int j = -12; j <= 12; ++j) {
        int rr = r0 + j; rr = rr < 0 ? 0 : (rr > 511 ? 511 : rr);
        u16x8_t v = *(const u16x8_t*)(base + ((long)rr << 9));
        #pragma unroll
        for (int k = 0; k < 8; ++k) s[k] += b2f(v[k]);
    }
    for (int rr = 0; rr < 8; ++rr) {
        int r = r0 + rr;
        u16x8_t xv = *(const u16x8_t*)(base + ((long)r << 9));
        u16x8_t ov;
        #pragma unroll
        for (int k = 0; k < 8; ++k) ov[k] = f2b(b2f(xv[k]) - s[k] * (1.f / 25.f));
        *(u16x8_t*)(obase + ((long)r << 9)) = ov;
        int rp = r + 13; rp = rp > 511 ? 511 : rp;
        int rm = r - 12; rm = rm < 0 ? 0 : rm;
        u16x8_t vp = *(const u16x8_t*)(base + ((long)rp << 9));
        u16x8_t vm = *(const u16x8_t*)(base + ((long)rm << 9));
        #pragma unroll
        for (int k = 0; k < 8; ++k) s[k] += b2f(vp[k]) - b2f(vm[k]);
    }
}

// ----------------------- bf16 DFT tables -----------------------------------
__global__ __launch_bounds__(256)
void init_tables_k(ushort_t* __restrict__ TFb, ushort_t* __restrict__ TI2b)
{
    int t = blockIdx.x * 256 + threadIdx.x;   // 0..131071
    const float w = 6.283185307179586f / 512.f;
    if (t < 65536) {
        int mp = t >> 9, n = t & 511;
        int m = mp & 63;
        float ang = ((m * n) & 511) * w;
        TFb[t] = f2b((mp < 64) ? cosf(ang) : -sinf(ang));
    } else {
        int u = t - 65536;
        int mp = u >> 9, n = u & 511;
        int m = mp & 63;
        float ang = ((m * n) & 511) * w;
        float v;
        if (mp < 64) v = (m == 0) ? (1.f / 512.f) : (2.f / 512.f) * cosf(ang);
        else         v = (m == 0) ? 0.f : -(2.f / 512.f) * sinf(ang);
        TI2b[u] = f2b(v);
    }
}

// ----------------------- fp32 -> bf16 convert (weights) --------------------
__global__ __launch_bounds__(256)
void f2b_k(const float* __restrict__ X, ushort_t* __restrict__ Y, long n)
{
    long i = ((long)blockIdx.x * 256 + threadIdx.x) * 8;
    if (i >= n) return;
    const float4* xp = (const float4*)(X + i);
    float4 v0 = xp[0], v1 = xp[1];
    u16x8_t o;
    o[0] = f2b(v0.x); o[1] = f2b(v0.y); o[2] = f2b(v0.z); o[3] = f2b(v0.w);
    o[4] = f2b(v1.x); o[5] = f2b(v1.y); o[6] = f2b(v1.z); o[7] = f2b(v1.w);
    *(u16x8_t*)(Y + i) = o;
}

// ----------------- fp32 [R,C] -> bf16 transposed [C,R] ---------------------
__global__ __launch_bounds__(256)
void trans_b_k(const float* __restrict__ X, ushort_t* __restrict__ Y,
               int R, int C, long sX, long sY)
{
    __shared__ float t[32][33];
    X += (long)blockIdx.z * sX;
    Y += (long)blockIdx.z * sY;
    int r0 = blockIdx.y * 32, c0 = blockIdx.x * 32;
    int tx = threadIdx.x & 31, ty = threadIdx.x >> 5;
    #pragma unroll
    for (int i = ty; i < 32; i += 8)
        t[i][tx] = X[(long)(r0 + i) * C + c0 + tx];
    __syncthreads();
    #pragma unroll
    for (int i = ty; i < 32; i += 8)
        Y[(long)(c0 + i) * R + r0 + tx] = f2b(t[tx][i]);
}

// ----------------- bf16 [R,C] -> bf16 transposed [C,R] ---------------------
__global__ __launch_bounds__(256)
void trans_bb_k(const ushort_t* __restrict__ X, ushort_t* __restrict__ Y,
                int R, int C, long sX, long sY)
{
    __shared__ ushort_t t[32][34];
    X += (long)blockIdx.z * sX;
    Y += (long)blockIdx.z * sY;
    int r0 = blockIdx.y * 32, c0 = blockIdx.x * 32;
    int tx = threadIdx.x & 31, ty = threadIdx.x >> 5;
    #pragma unroll
    for (int i = ty; i < 32; i += 8)
        t[i][tx] = X[(long)(r0 + i) * C + c0 + tx];
    __syncthreads();
    #pragma unroll
    for (int i = ty; i < 32; i += 8)
        Y[(long)(c0 + i) * R + r0 + tx] = t[tx][i];
}

// --------------------- layernorm (bf16 in/out, f32 math) -------------------
__global__ __launch_bounds__(256)
void ln_rows_bb_k(const ushort_t* __restrict__ Xb, const float* __restrict__ g,
                  const float* __restrict__ bta, ushort_t* __restrict__ Yb)
{
    int wave = threadIdx.x >> 6, lane = threadIdx.x & 63;
    long row = (long)blockIdx.x * 4 + wave;
    const ushort_t* x = Xb + row * 512 + lane * 8;
    u16x8_t v = *(const u16x8_t*)x;
    float f[8];
    float s = 0.f, ss = 0.f;
    #pragma unroll
    for (int j = 0; j < 8; ++j) { f[j] = b2f(v[j]); s += f[j]; ss += f[j] * f[j]; }
    #pragma unroll
    for (int o = 32; o; o >>= 1) { s += __shfl_xor(s, o); ss += __shfl_xor(ss, o); }
    float mu = s * (1.f / 512.f);
    float var = ss * (1.f / 512.f) - mu * mu;
    float inv = rsqrtf(var + 1e-5f);
    u16x8_t ov;
    #pragma unroll
    for (int j = 0; j < 8; ++j)
        ov[j] = f2b((f[j] - mu) * inv * g[lane * 8 + j] + bta[lane * 8 + j]);
    *(u16x8_t*)(Yb + row * 512 + lane * 8) = ov;
}

// subtract per-(b,d) seq-mean, bf16 in/out (4 waves split the t-loop)
__global__ __launch_bounds__(256)
void colmean_bb_k(const ushort_t* __restrict__ Y, ushort_t* __restrict__ O)
{
    __shared__ float ps[4][64];
    int b = blockIdx.x, dg = blockIdx.y;
    int wave = threadIdx.x >> 6, lane = threadIdx.x & 63;
    int d = dg * 64 + lane;
    long base = (long)b * 262144 + d;
    float s = 0.f;
    for (int t = wave * 128; t < wave * 128 + 128; ++t)
        s += b2f(Y[base + ((long)t << 9)]);
    ps[wave][lane] = s;
    __syncthreads();
    float mean = (ps[0][lane] + ps[1][lane] + ps[2][lane] + ps[3][lane]) * (1.f / 512.f);
    for (int t = wave * 128; t < wave * 128 + 128; ++t)
        O[base + ((long)t << 9)] = f2b(b2f(Y[base + ((long)t << 9)]) - mean);
}

// head transpose-add: out[b,p,t] += Thead[(b*512+t)*128+p] + b_head[p]
__global__ __launch_bounds__(256)
void headadd_k(const float* __restrict__ Th, const float* __restrict__ bh,
               float* __restrict__ out)
{
    const int id = blockIdx.x;          // b*16 + tc
    const int b = id >> 4, t0 = (id & 15) * 32;
    __shared__ float tile[32][100];
    for (int e = threadIdx.x; e < 32 * 96; e += 256) {
        int tl = e / 96, p = e - tl * 96;
        tile[tl][p] = Th[((long)(b * 512 + t0 + tl)) * 128 + p];
    }
    __syncthreads();
    for (int e = threadIdx.x; e < 96 * 32; e += 256) {
        int p = e >> 5, tl = e & 31;
        out[(long)b * 49152 + p * 512 + t0 + tl] += tile[tl][p] + bh[p];
    }
}

// ===========================================================================
extern "C" void kernel_launch(void* const* d_in, const int* in_sizes, int n_in,
                              void* d_out, int out_size, void* d_ws, size_t ws_size,
                              hipStream_t stream)
{
    const float* x_enc   = (const float*)d_in[0];
    const float* W_trend = (const float*)d_in[4];
    const float* b_trend = (const float*)d_in[5];
    const float* W_emb   = (const float*)d_in[6];
    const float* b_emb   = (const float*)d_in[7];
    const float* Wq      = (const float*)d_in[8];
    const float* bq      = (const float*)d_in[9];
    const float* fw_r    = (const float*)d_in[14];
    const float* fw_i    = (const float*)d_in[15];
    const float* Wo      = (const float*)d_in[16];
    const float* bo      = (const float*)d_in[17];
    const float* W1      = (const float*)d_in[18];
    const float* W2      = (const float*)d_in[19];
    const float* ln_g    = (const float*)d_in[20];
    const float* ln_b    = (const float*)d_in[21];
    const float* W_head  = (const float*)d_in[22];
    const float* b_head  = (const float*)d_in[23];
    float* out = (float*)d_out;
    float* ws  = (float*)d_ws;

    const long F = 8388608;
    float* G    = ws;
    ushort_t* xw  = (ushort_t*)(ws + 3 * F);           // encoder state bf16
    ushort_t* xs  = (ushort_t*)(ws + 4 * F);           // seasonal / FFN residual
    ushort_t* T1b = xs + 8388608;                      // FFN out / LN out
    ushort_t* qT  = (ushort_t*)(ws + 5 * F);

    ushort_t* trendb = (ushort_t*)G;
    ushort_t* seasb  = (ushort_t*)(G + 4194304);
    ushort_t* XFTb  = (ushort_t*)G;                    // [0,4MB)
    ushort_t* Yb    = (ushort_t*)(G + 1048576);        // [4,8MB)
    ushort_t* A2    = (ushort_t*)(G + 2097152);        // [8,12MB)
    ushort_t* OSELb = (ushort_t*)(G + 3145728);        // [12,16MB)
    ushort_t* xbT   = (ushort_t*)(G + 4194304);        // [16,32MB)
    ushort_t* B2    = (ushort_t*)(G + 8388608);        // [32,48MB)
    float*    Thead = G;
    ushort_t* gb    = (ushort_t*)G;                    // FFN-phase 64MB

    ushort_t* WembT  = (ushort_t*)(ws + 6 * F);        // 262144
    ushort_t* WTq2   = WembT + 262144;                 // 2 x 262144
    ushort_t* WTo2   = WTq2 + 524288;                  // 2 x 262144
    ushort_t* W1b2   = WTo2 + 524288;                  // 2 x 1048576
    ushort_t* W2b2   = W1b2 + 2097152;                 // 2 x 1048576
    ushort_t* TFb    = W2b2 + 2097152;                 // 65536
    ushort_t* TI2b   = TFb + 65536;                    // 65536
    ushort_t* WtT    = TI2b + 65536;                   // [128,512] rows<96 valid
    ushort_t* WheadT = WtT + 65536;                    // [128,512] rows<96 valid
    ushort_t* TIWob2 = WheadT + 65536;                 // 2 x 65536

    dim3 blk(256), blk5(512);

    init_tables_k<<<dim3(512), blk, 0, stream>>>(TFb, TI2b);

    decomp2_k<<<dim3(2048), blk, 0, stream>>>(x_enc, seasb, trendb);

    // hoisted weight prep (both layers batched)
    trans_b_k<<<dim3(3, 16, 1), blk, 0, stream>>>(W_trend, WtT, 512, 96, 0L, 0L);
    trans_b_k<<<dim3(3, 16, 1), blk, 0, stream>>>(W_head, WheadT, 512, 96, 0L, 0L);
    trans_b_k<<<dim3(16, 16, 1), blk, 0, stream>>>(W_emb, WembT, 512, 512, 0L, 0L);
    trans_b_k<<<dim3(16, 16, 2), blk, 0, stream>>>(Wq, WTq2, 512, 512, 262144L, 262144L);
    trans_b_k<<<dim3(16, 16, 2), blk, 0, stream>>>(Wo, WTo2, 512, 512, 262144L, 262144L);
    f2b_k<<<dim3(1024), blk, 0, stream>>>(W1, W1b2, 2097152L);
    f2b_k<<<dim3(1024), blk, 0, stream>>>(W2, W2b2, 2097152L);
    // TIWob2[l][d,mp] = sum_n WTo2[l][d,n] * TI2b[mp,n]
    sgemm_k<ME_BF16><<<dim3(2, 8, 2), blk, 0, stream>>>(
        WTo2, TI2b, nullptr, TIWob2,
        512, 128, 512, 128, 262144L, 0L, 65536L);

    // trendT bf16 into qT slot, trend head GEMM -> out
    trans_bb_k<<<dim3(16, 16, 32), blk, 0, stream>>>(trendb, qT, 512, 512, 262144L, 262144L);
    sgemm_k<ME_TREND><<<dim3(8, 2, 32), blk, 0, stream>>>(
        WtT, qT, b_trend, out,
        128, 512, 512, 512, 0L, 262144L, 49152L);

    // seasonalT bf16 into qT slot; embedding -> xw bf16
    trans_bb_k<<<dim3(16, 16, 32), blk, 0, stream>>>(seasb, qT, 512, 512, 262144L, 262144L);
    mgemm_k<ME_BIASCOL_BF16><<<dim3(4, 4, 32), blk5, 0, stream>>>(
        qT, WembT, b_emb, nullptr, xw,
        512, 512, 512, 512, 0, 262144L, 0L, 262144L, 0L);

    for (int l = 0; l < 2; ++l) {
        const float* bq_l = bq + (long)l * 512;
        const float* bo_l = bo + (long)l * 512;
        const float* fr_l = fw_r + (long)l * 2097152;
        const float* fi_l = fw_i + (long)l * 2097152;
        const ushort_t* WTq_l   = WTq2 + (long)l * 262144;
        const ushort_t* W1b_l   = W1b2 + (long)l * 1048576;
        const ushort_t* W2b_l   = W2b2 + (long)l * 1048576;
        const ushort_t* TIWob_l = TIWob2 + (long)l * 65536;

        bprep_k<<<dim3(512), blk, 0, stream>>>(fr_l, fi_l, B2);

        // xbT[b,d,n] = xw[b,n,d]^T
        trans_bb_k<<<dim3(16, 16, 32), blk, 0, stream>>>(xw, xbT, 512, 512, 262144L, 262144L);

        // G1: Yb[b,mp,d] = sum_n TFb[mp,n] * xbT[b,d,n]
        sgemm_k<ME_BF16><<<dim3(8, 2, 32), blk, 0, stream>>>(
            TFb, xbT, nullptr, Yb,
            128, 512, 512, 512, 0L, 262144L, 65536L);

        // G2: XFTb[b,c,mp] = sum_d WTq[c,d] * Yb[b,mp,d]  (+512*bq[c] at mp=0)
        sgemm_k<ME_DCBIAS_BF16><<<dim3(2, 8, 32), blk, 0, stream>>>(
            WTq_l, Yb, bq_l, XFTb,
            512, 128, 512, 128, 0L, 65536L, 65536L);

        aprep_k<<<dim3(256), blk, 0, stream>>>(XFTb, A2);
        fmix_k<<<dim3(512), blk, 0, stream>>>(A2, B2, OSELb);

        // xw += OSEL . TIWo^T + bo   (bf16 RMW)
        mgemm_k<ME_BIASCOL_ACCB16><<<dim3(4, 128, 1), blk5, 0, stream>>>(
            OSELb, TIWob_l, bo_l, nullptr, xw,
            16384, 512, 128, 512, 0, 0L, 0L, 0L, 0L);

        // decomp (bf16, vectorized) -> xs (FFN input + FFN2 residual)
        decomp2v_k<<<dim3(512), blk, 0, stream>>>(xw, xs);

        // FFN, full M=16384
        mgemm_k<ME_GELU_BF16><<<dim3(16, 128, 1), blk5, 0, stream>>>(
            xs, W1b_l, nullptr, nullptr, gb,
            16384, 2048, 512, 2048, 0, 0L, 0L, 0L, 0L);
        mgemm_k<ME_RESB_BF16><<<dim3(4, 128, 1), blk5, 0, stream>>>(
            gb, W2b_l, nullptr, xs, T1b,
            16384, 512, 2048, 512, 512, 0L, 0L, 0L, 0L);

        // decomp (bf16, vectorized) -> xw (next layer state / LN input)
        decomp2v_k<<<dim3(512), blk, 0, stream>>>(T1b, xw);
    }

    // my_layernorm (bf16): rows -> T1b, colmean-subtract -> xs
    ln_rows_bb_k<<<dim3(4096), blk, 0, stream>>>(xw, ln_g, ln_b, T1b);
    colmean_bb_k<<<dim3(32, 8), blk, 0, stream>>>(T1b, xs);

    // head
    sgemm_k<ME_F32><<<dim3(2, 256, 1), blk, 0, stream>>>(
        xs, WheadT, nullptr, Thead,
        16384, 128, 512, 128, 0L, 0L, 0L);

    headadd_k<<<dim3(512), blk, 0, stream>>>(Thead, b_head, out);
}

// Round 12
// 546.135 us; speedup vs baseline: 8.7943x; 1.0344x over previous
//
#include <hip/hip_runtime.h>
#include <math.h>

// ---------------------------------------------------------------------------
// Model_24180665876772  Round 12: LDS bank-conflict swizzle (chunk ^= row&3)
// on all MFMA GEMM fragment reads w/ pre-swizzled global_load_lds sources
// (8-way -> 4-way); fmix 16-way -> free (chunk ^= row&15). Start decomp
// writes transposed directly (kills 2x 32MB transpose passes).
// ---------------------------------------------------------------------------

typedef unsigned short ushort_t;
typedef unsigned int uint_t;
using bf16x8_t = __attribute__((ext_vector_type(8))) short;
using f32x4_t  = __attribute__((ext_vector_type(4))) float;
using u16x8_t  = __attribute__((ext_vector_type(8))) unsigned short;

__device__ __forceinline__ unsigned short f2b(float x) {
    union { float f; uint_t u; } c; c.f = x;
    uint_t r = c.u + 0x7fffu + ((c.u >> 16) & 1u);   // RNE
    return (unsigned short)(r >> 16);
}
__device__ __forceinline__ float b2f(unsigned short h) {
    union { uint_t u; float f; } c; c.u = ((uint_t)h) << 16; return c.f;
}
// tanh-form GELU via sigmoid: gelu(x) ~= x * sigmoid(1.59577x + 0.0713548x^3)
__device__ __forceinline__ float gelu_fast(float x) {
    float z = x * (1.5957691216f + 0.0713548163f * x * x);
    return x / (1.f + __expf(-z));
}

#define GCAST(p) ((const __attribute__((address_space(1))) void*)(p))
#define LCAST(p) ((__attribute__((address_space(3))) void*)(p))

enum { ME_F32 = 0, ME_BF16, ME_DCBIAS_BF16, ME_BIASCOL_BF16,
       ME_BIASCOL_ACCB16, ME_GELU_BF16, ME_RESB_BF16, ME_TREND };

// ---------------- 128x128 GEMM, 8 waves, 3-buf, counted vmcnt, swizzled ----
template<int EPI>
__global__ __launch_bounds__(512)
void mgemm_k(const ushort_t* __restrict__ A, const ushort_t* __restrict__ B,
             const float* __restrict__ bias, const ushort_t* __restrict__ Resb,
             void* __restrict__ Cv,
             int M, int N, int K, int ldc, int ldres,
             long sA, long sB, long sC, long sRes)
{
    const int gx = gridDim.x, gy = gridDim.y;
    const int nwg = gx * gy * gridDim.z;
    const int lin = (blockIdx.z * gy + blockIdx.y) * gx + blockIdx.x;
    const int cpx = nwg >> 3;
    const int swz = (nwg & 7) ? lin : ((lin & 7) * cpx + (lin >> 3));
    const int bx = swz % gx;
    const int t2 = swz / gx;
    const int by = t2 % gy;
    const int bz = t2 / gy;

    A += bz * sA;
    B += bz * sB;
    const int m0 = by * 128, n0 = bx * 128;

    __shared__ __align__(16) ushort_t As[3][4096];
    __shared__ __align__(16) ushort_t Bs[3][4096];

    const int tid = threadIdx.x;
    const int wave = tid >> 6, lane = tid & 63;
    const int wr = wave >> 1, wc = wave & 1;

    f32x4_t acc[2][4] = {};

    const int srow = tid >> 2;
    // pre-swizzled k-chunk: chunk' = chunk ^ (row & 3)  (LDS dest stays linear)
    const int skof = (((tid & 3) ^ ((tid >> 2) & 3)) << 3);

    const ushort_t* ga = A + (long)(m0 + srow) * K + skof;
    const ushort_t* gb = B + (long)(n0 + srow) * K + skof;
    const int nt = K >> 5;

#define STG(s, bidx) { const long ko = (long)(s) << 5; \
    __builtin_amdgcn_global_load_lds(GCAST(ga + ko), LCAST(As[bidx] + wave * 512), 16, 0, 0); \
    __builtin_amdgcn_global_load_lds(GCAST(gb + ko), LCAST(Bs[bidx] + wave * 512), 16, 0, 0); }

    STG(0, 0)
    STG(1, 1)

    const int q = lane >> 4;             // k-chunk 0..3
    int cbuf = 0;

    for (int t = 0; t < nt; ++t) {
        if (t + 1 < nt) { asm volatile("s_waitcnt vmcnt(2)" ::: "memory"); }
        else            { asm volatile("s_waitcnt vmcnt(0)" ::: "memory"); }
        __builtin_amdgcn_s_barrier();
        asm volatile("" ::: "memory");
        __builtin_amdgcn_sched_barrier(0);
        if (t + 2 < nt) { int nb = cbuf + 2; if (nb >= 3) nb -= 3; STG(t + 2, nb) }

        bf16x8_t a[2], b[4];
        #pragma unroll
        for (int i = 0; i < 2; ++i) {
            int ra = wr * 32 + i * 16 + (lane & 15);
            a[i] = *(const bf16x8_t*)&As[cbuf][ra * 32 + ((q ^ (ra & 3)) << 3)];
        }
        #pragma unroll
        for (int j = 0; j < 4; ++j) {
            int rb = wc * 64 + j * 16 + (lane & 15);
            b[j] = *(const bf16x8_t*)&Bs[cbuf][rb * 32 + ((q ^ (rb & 3)) << 3)];
        }
        #pragma unroll
        for (int i = 0; i < 2; ++i)
            #pragma unroll
            for (int j = 0; j < 4; ++j)
                acc[i][j] = __builtin_amdgcn_mfma_f32_16x16x32_bf16(a[i], b[j], acc[i][j], 0, 0, 0);
        ++cbuf; if (cbuf >= 3) cbuf = 0;
    }
#undef STG

    float*    Cf  = (float*)Cv + bz * sC;
    ushort_t* Cb  = (ushort_t*)Cv + bz * sC;
    const ushort_t* R = Resb ? Resb + bz * sRes : nullptr;

    #pragma unroll
    for (int i = 0; i < 2; ++i) {
        #pragma unroll
        for (int j = 0; j < 4; ++j) {
            #pragma unroll
            for (int r = 0; r < 4; ++r) {
                int gm = m0 + wr * 32 + i * 16 + (lane >> 4) * 4 + r;
                int gn = n0 + wc * 64 + j * 16 + (lane & 15);
                float v = acc[i][j][r];
                long idx = (long)gm * ldc + gn;
                if (EPI == ME_F32)               Cf[idx] = v;
                else if (EPI == ME_BF16)         Cb[idx] = f2b(v);
                else if (EPI == ME_BIASCOL_BF16) Cb[idx] = f2b(v + bias[gn]);
                else if (EPI == ME_BIASCOL_ACCB16) Cb[idx] = f2b(b2f(Cb[idx]) + v + bias[gn]);
                else if (EPI == ME_GELU_BF16)    Cb[idx] = f2b(gelu_fast(v));
                else if (EPI == ME_RESB_BF16)    Cb[idx] = f2b(v + b2f(R[(long)gm * ldres + gn]));
            }
        }
    }
}

// ---------------- 64x64 GEMM, 4 waves, 3-buf, swizzled ---------------------
template<int EPI>
__global__ __launch_bounds__(256)
void sgemm_k(const ushort_t* __restrict__ A, const ushort_t* __restrict__ B,
             const float* __restrict__ bias, void* __restrict__ Cv,
             int M, int N, int K, int ldc,
             long sA, long sB, long sC)
{
    const int gx = gridDim.x, gy = gridDim.y;
    const int nwg = gx * gy * gridDim.z;
    const int lin = (blockIdx.z * gy + blockIdx.y) * gx + blockIdx.x;
    const int cpx = nwg >> 3;
    const int swz = (nwg & 7) ? lin : ((lin & 7) * cpx + (lin >> 3));
    const int bx = swz % gx;
    const int t2 = swz / gx;
    const int by = t2 % gy;
    const int bz = t2 / gy;

    A += bz * sA;
    B += bz * sB;
    const int m0 = by * 64, n0 = bx * 64;

    __shared__ __align__(16) ushort_t As[3][2048];
    __shared__ __align__(16) ushort_t Bs[3][2048];

    const int tid = threadIdx.x;
    const int wave = tid >> 6, lane = tid & 63;
    const int wr = wave >> 1, wc = wave & 1;

    f32x4_t acc[2][2] = {};

    const int srow = tid >> 2;           // 0..63
    const int skof = (((tid & 3) ^ ((tid >> 2) & 3)) << 3);

    const ushort_t* ga = A + (long)(m0 + srow) * K + skof;
    const ushort_t* gb = B + (long)(n0 + srow) * K + skof;
    const int nt = K >> 5;

#define STG(s, bidx) { const long ko = (long)(s) << 5; \
    __builtin_amdgcn_global_load_lds(GCAST(ga + ko), LCAST(As[bidx] + wave * 512), 16, 0, 0); \
    __builtin_amdgcn_global_load_lds(GCAST(gb + ko), LCAST(Bs[bidx] + wave * 512), 16, 0, 0); }

    STG(0, 0)
    STG(1, 1)

    const int q = lane >> 4;
    int cbuf = 0;

    for (int t = 0; t < nt; ++t) {
        if (t + 1 < nt) { asm volatile("s_waitcnt vmcnt(2)" ::: "memory"); }
        else            { asm volatile("s_waitcnt vmcnt(0)" ::: "memory"); }
        __builtin_amdgcn_s_barrier();
        asm volatile("" ::: "memory");
        __builtin_amdgcn_sched_barrier(0);
        if (t + 2 < nt) { int nb = cbuf + 2; if (nb >= 3) nb -= 3; STG(t + 2, nb) }

        bf16x8_t a[2], b[2];
        #pragma unroll
        for (int i = 0; i < 2; ++i) {
            int ra = wr * 32 + i * 16 + (lane & 15);
            a[i] = *(const bf16x8_t*)&As[cbuf][ra * 32 + ((q ^ (ra & 3)) << 3)];
        }
        #pragma unroll
        for (int j = 0; j < 2; ++j) {
            int rb = wc * 32 + j * 16 + (lane & 15);
            b[j] = *(const bf16x8_t*)&Bs[cbuf][rb * 32 + ((q ^ (rb & 3)) << 3)];
        }
        #pragma unroll
        for (int i = 0; i < 2; ++i)
            #pragma unroll
            for (int j = 0; j < 2; ++j)
                acc[i][j] = __builtin_amdgcn_mfma_f32_16x16x32_bf16(a[i], b[j], acc[i][j], 0, 0, 0);
        ++cbuf; if (cbuf >= 3) cbuf = 0;
    }
#undef STG

    float*    Cf = (float*)Cv + bz * sC;
    ushort_t* Cb = (ushort_t*)Cv + bz * sC;

    #pragma unroll
    for (int i = 0; i < 2; ++i) {
        #pragma unroll
        for (int j = 0; j < 2; ++j) {
            #pragma unroll
            for (int r = 0; r < 4; ++r) {
                int gm = m0 + wr * 32 + i * 16 + (lane >> 4) * 4 + r;
                int gn = n0 + wc * 32 + j * 16 + (lane & 15);
                float v = acc[i][j][r];
                long idx = (long)gm * ldc + gn;
                if (EPI == ME_F32)               Cf[idx] = v;
                else if (EPI == ME_BF16)         Cb[idx] = f2b(v);
                else if (EPI == ME_DCBIAS_BF16)  Cb[idx] = f2b(v + (gn == 0 ? 512.f * bias[gm] : 0.f));
                else if (EPI == ME_TREND) { if (gm < 96) Cf[idx] = v + bias[gm]; }
            }
        }
    }
}

// -------- batched complex mode-mix MFMA (per h,m), swizzled LDS ------------
__global__ __launch_bounds__(256)
void fmix_k(const ushort_t* __restrict__ A2, const ushort_t* __restrict__ B2,
            ushort_t* __restrict__ OS)
{
    const int hm = blockIdx.x;
    const int h = hm >> 6, m = hm & 63;
    __shared__ __align__(16) ushort_t As[32 * 128];
    __shared__ __align__(16) ushort_t Bs[128 * 128];

    const int tid = threadIdx.x;
    const int w = tid >> 6, lane = tid & 63;

    const ushort_t* Ag = A2 + (long)hm * 4096;
    const ushort_t* Bg = B2 + (long)hm * 16384;
    // rows are 128 el (256B): chunk' = chunk ^ (row & 15) -> conflict-free
    #pragma unroll
    for (int r = 0; r < 2; ++r) {
        int rowA = w * 8 + r * 4 + (lane >> 4);
        const ushort_t* src = Ag + rowA * 128 + (((lane & 15) ^ (rowA & 15)) << 3);
        __builtin_amdgcn_global_load_lds(GCAST(src), LCAST(As + w * 1024 + r * 512), 16, 0, 0);
    }
    #pragma unroll
    for (int r = 0; r < 8; ++r) {
        int rowB = w * 32 + r * 4 + (lane >> 4);
        const ushort_t* src = Bg + rowB * 128 + (((lane & 15) ^ (rowB & 15)) << 3);
        __builtin_amdgcn_global_load_lds(GCAST(src), LCAST(Bs + w * 4096 + r * 512), 16, 0, 0);
    }
    __syncthreads();

    f32x4_t acc[2][2] = {};
    #pragma unroll
    for (int kk = 0; kk < 4; ++kk) {
        const int cq = kk * 4 + (lane >> 4);   // 16B-chunk position 0..15
        bf16x8_t a[2], b[2];
        #pragma unroll
        for (int i = 0; i < 2; ++i) {
            int ra = i * 16 + (lane & 15);
            a[i] = *(const bf16x8_t*)&As[ra * 128 + ((cq ^ (ra & 15)) << 3)];
        }
        #pragma unroll
        for (int j = 0; j < 2; ++j) {
            int rb = w * 32 + j * 16 + (lane & 15);
            b[j] = *(const bf16x8_t*)&Bs[rb * 128 + ((cq ^ (rb & 15)) << 3)];
        }
        #pragma unroll
        for (int i = 0; i < 2; ++i)
            #pragma unroll
            for (int j = 0; j < 2; ++j)
                acc[i][j] = __builtin_amdgcn_mfma_f32_16x16x32_bf16(a[i], b[j], acc[i][j], 0, 0, 0);
    }

    #pragma unroll
    for (int i = 0; i < 2; ++i) {
        #pragma unroll
        for (int j = 0; j < 2; ++j) {
            #pragma unroll
            for (int r = 0; r < 4; ++r) {
                int b = i * 16 + (lane >> 4) * 4 + r;
                int n2 = w * 32 + j * 16 + (lane & 15);
                int o = n2 & 63, ri = n2 >> 6;
                OS[((long)b * 512 + h * 64 + o) * 128 + ri * 64 + m] = f2b(acc[i][j][r]);
            }
        }
    }
}

// B2 prep: block per (h,o). Fr/Fi [h][i][o][m] f32 -> B2[h][m][n2][k2] bf16
__global__ __launch_bounds__(256)
void bprep_k(const float* __restrict__ FR, const float* __restrict__ FI,
             ushort_t* __restrict__ B2)
{
    const int bx = blockIdx.x;
    const int h = bx >> 6, o = bx & 63;
    __shared__ float fr_s[64][65];
    __shared__ float fi_s[64][65];
    for (int e = threadIdx.x; e < 4096; e += 256) {
        int i = e >> 6, m = e & 63;
        long src = ((long)(h * 64 + i) * 64 + o) * 64 + m;
        fr_s[i][m] = FR[src];
        fi_s[i][m] = FI[src];
    }
    __syncthreads();
    const int m = threadIdx.x & 63;
    const int kq = threadIdx.x >> 6;
    ushort_t* b0 = B2 + ((long)(h * 64 + m) * 128 + o) * 128;
    ushort_t* b1 = B2 + ((long)(h * 64 + m) * 128 + o + 64) * 128;
    for (int kk = 0; kk < 32; ++kk) {
        int k2 = kq * 32 + kk;
        int ik = k2 & 63, hi = k2 >> 6;
        float fr = fr_s[ik][m], fi = fi_s[ik][m];
        b0[k2] = f2b(hi ? -fi : fr);
        b1[k2] = f2b(hi ?  fr : fi);
    }
}

// A2 prep: block per (b,h). XFTb [b][c=h*64+i][mp] bf16 -> A2[h][m][b][k2] bf16
__global__ __launch_bounds__(256)
void aprep_k(const ushort_t* __restrict__ XFTb, ushort_t* __restrict__ A2)
{
    const int bx = blockIdx.x;
    const int b = bx >> 3, h = bx & 7;
    __shared__ ushort_t xs[64][130];
    for (int e = threadIdx.x; e < 8192; e += 256) {
        int i = e >> 7, mp = e & 127;
        xs[i][mp] = XFTb[((long)b * 512 + h * 64 + i) * 128 + mp];
    }
    __syncthreads();
    const int m = threadIdx.x & 63;
    const int kq = threadIdx.x >> 6;
    ushort_t* dst = A2 + ((long)(h * 64 + m) * 32 + b) * 128;
    for (int kk = 0; kk < 32; ++kk) {
        int k2 = kq * 32 + kk;
        int i = k2 & 63, ri = k2 >> 6;
        dst[k2] = xs[i][ri * 64 + m];
    }
}

// ------- start decomp (k=25), f32 in -> TRANSPOSED bf16 seasonal/trend -----
// outputs [b][c][r] (ready as GEMM B operands)
__global__ __launch_bounds__(256)
void decomp2t_k(const float* __restrict__ X, ushort_t* __restrict__ SbT,
                ushort_t* __restrict__ TrbT)
{
    const int id = blockIdx.x;
    const int ch = id & 1, rc = (id >> 1) & 31, b = id >> 6;
    const int c = ch * 256 + threadIdx.x;
    const int r0 = rc * 16;
    const long base = ((long)b << 18) + c;
    float s = 0.f;
    #pragma unroll
    for (int j = -12; j <= 12; ++j) {
        int rr = r0 + j; rr = rr < 0 ? 0 : (rr > 511 ? 511 : rr);
        s += X[base + ((long)rr << 9)];
    }
    u16x8_t sv0, sv1, tv0, tv1;
    for (int rr = 0; rr < 16; ++rr) {
        int r = r0 + rr;
        float mean = s * (1.f / 25.f);
        float x = X[base + ((long)r << 9)];
        if (rr < 8) { sv0[rr] = f2b(x - mean); tv0[rr] = f2b(mean); }
        else        { sv1[rr - 8] = f2b(x - mean); tv1[rr - 8] = f2b(mean); }
        int rp = r + 13; rp = rp > 511 ? 511 : rp;
        int rm = r - 12; rm = rm < 0 ? 0 : rm;
        s += X[base + ((long)rp << 9)] - X[base + ((long)rm << 9)];
    }
    long obase = (long)b * 262144 + (long)c * 512 + r0;
    *(u16x8_t*)&SbT[obase] = sv0;  *(u16x8_t*)&SbT[obase + 8] = sv1;
    *(u16x8_t*)&TrbT[obase] = tv0; *(u16x8_t*)&TrbT[obase + 8] = tv1;
}

// ------- sliding-window series_decomp (k=25), bf16 in/out, vectorized ------
__global__ __launch_bounds__(256)
void decomp2v_k(const ushort_t* __restrict__ Xb, ushort_t* __restrict__ Sb)
{
    const int id = blockIdx.x;
    const int b = id >> 4, rc = id & 15;
    const int c0 = (threadIdx.x & 63) * 8;
    const int rsub = threadIdx.x >> 6;
    const int r0 = rc * 32 + rsub * 8;
    const ushort_t* base = Xb + ((long)b << 18) + c0;
    ushort_t* obase = Sb + ((long)b << 18) + c0;

    float s[8] = {};
    #pragma unroll
    for (int j = -12; j <= 12; ++j) {
        int rr = r0 + j; rr = rr < 0 ? 0 : (rr > 511 ? 511 : rr);
        u16x8_t v = *(const u16x8_t*)(base + ((long)rr << 9));
        #pragma unroll
        for (int k = 0; k < 8; ++k) s[k] += b2f(v[k]);
    }
    for (int rr = 0; rr < 8; ++rr) {
        int r = r0 + rr;
        u16x8_t xv = *(const u16x8_t*)(base + ((long)r << 9));
        u16x8_t ov;
        #pragma unroll
        for (int k = 0; k < 8; ++k) ov[k] = f2b(b2f(xv[k]) - s[k] * (1.f / 25.f));
        *(u16x8_t*)(obase + ((long)r << 9)) = ov;
        int rp = r + 13; rp = rp > 511 ? 511 : rp;
        int rm = r - 12; rm = rm < 0 ? 0 : rm;
        u16x8_t vp = *(const u16x8_t*)(base + ((long)rp << 9));
        u16x8_t vm = *(const u16x8_t*)(base + ((long)rm << 9));
        #pragma unroll
        for (int k = 0; k < 8; ++k) s[k] += b2f(vp[k]) - b2f(vm[k]);
    }
}

// ----------------------- bf16 DFT tables -----------------------------------
__global__ __launch_bounds__(256)
void init_tables_k(ushort_t* __restrict__ TFb, ushort_t* __restrict__ TI2b)
{
    int t = blockIdx.x * 256 + threadIdx.x;   // 0..131071
    const float w = 6.283185307179586f / 512.f;
    if (t < 65536) {
        int mp = t >> 9, n = t & 511;
        int m = mp & 63;
        float ang = ((m * n) & 511) * w;
        TFb[t] = f2b((mp < 64) ? cosf(ang) : -sinf(ang));
    } else {
        int u = t - 65536;
        int mp = u >> 9, n = u & 511;
        int m = mp & 63;
        float ang = ((m * n) & 511) * w;
        float v;
        if (mp < 64) v = (m == 0) ? (1.f / 512.f) : (2.f / 512.f) * cosf(ang);
        else         v = (m == 0) ? 0.f : -(2.f / 512.f) * sinf(ang);
        TI2b[u] = f2b(v);
    }
}

// ----------------------- fp32 -> bf16 convert (weights) --------------------
__global__ __launch_bounds__(256)
void f2b_k(const float* __restrict__ X, ushort_t* __restrict__ Y, long n)
{
    long i = ((long)blockIdx.x * 256 + threadIdx.x) * 8;
    if (i >= n) return;
    const float4* xp = (const float4*)(X + i);
    float4 v0 = xp[0], v1 = xp[1];
    u16x8_t o;
    o[0] = f2b(v0.x); o[1] = f2b(v0.y); o[2] = f2b(v0.z); o[3] = f2b(v0.w);
    o[4] = f2b(v1.x); o[5] = f2b(v1.y); o[6] = f2b(v1.z); o[7] = f2b(v1.w);
    *(u16x8_t*)(Y + i) = o;
}

// ----------------- fp32 [R,C] -> bf16 transposed [C,R] ---------------------
__global__ __launch_bounds__(256)
void trans_b_k(const float* __restrict__ X, ushort_t* __restrict__ Y,
               int R, int C, long sX, long sY)
{
    __shared__ float t[32][33];
    X += (long)blockIdx.z * sX;
    Y += (long)blockIdx.z * sY;
    int r0 = blockIdx.y * 32, c0 = blockIdx.x * 32;
    int tx = threadIdx.x & 31, ty = threadIdx.x >> 5;
    #pragma unroll
    for (int i = ty; i < 32; i += 8)
        t[i][tx] = X[(long)(r0 + i) * C + c0 + tx];
    __syncthreads();
    #pragma unroll
    for (int i = ty; i < 32; i += 8)
        Y[(long)(c0 + i) * R + r0 + tx] = f2b(t[tx][i]);
}

// ----------------- bf16 [R,C] -> bf16 transposed [C,R] ---------------------
__global__ __launch_bounds__(256)
void trans_bb_k(const ushort_t* __restrict__ X, ushort_t* __restrict__ Y,
                int R, int C, long sX, long sY)
{
    __shared__ ushort_t t[32][34];
    X += (long)blockIdx.z * sX;
    Y += (long)blockIdx.z * sY;
    int r0 = blockIdx.y * 32, c0 = blockIdx.x * 32;
    int tx = threadIdx.x & 31, ty = threadIdx.x >> 5;
    #pragma unroll
    for (int i = ty; i < 32; i += 8)
        t[i][tx] = X[(long)(r0 + i) * C + c0 + tx];
    __syncthreads();
    #pragma unroll
    for (int i = ty; i < 32; i += 8)
        Y[(long)(c0 + i) * R + r0 + tx] = t[tx][i];
}

// --------------------- layernorm (bf16 in/out, f32 math) -------------------
__global__ __launch_bounds__(256)
void ln_rows_bb_k(const ushort_t* __restrict__ Xb, const float* __restrict__ g,
                  const float* __restrict__ bta, ushort_t* __restrict__ Yb)
{
    int wave = threadIdx.x >> 6, lane = threadIdx.x & 63;
    long row = (long)blockIdx.x * 4 + wave;
    const ushort_t* x = Xb + row * 512 + lane * 8;
    u16x8_t v = *(const u16x8_t*)x;
    float f[8];
    float s = 0.f, ss = 0.f;
    #pragma unroll
    for (int j = 0; j < 8; ++j) { f[j] = b2f(v[j]); s += f[j]; ss += f[j] * f[j]; }
    #pragma unroll
    for (int o = 32; o; o >>= 1) { s += __shfl_xor(s, o); ss += __shfl_xor(ss, o); }
    float mu = s * (1.f / 512.f);
    float var = ss * (1.f / 512.f) - mu * mu;
    float inv = rsqrtf(var + 1e-5f);
    u16x8_t ov;
    #pragma unroll
    for (int j = 0; j < 8; ++j)
        ov[j] = f2b((f[j] - mu) * inv * g[lane * 8 + j] + bta[lane * 8 + j]);
    *(u16x8_t*)(Yb + row * 512 + lane * 8) = ov;
}

// subtract per-(b,d) seq-mean, bf16 in/out (4 waves split the t-loop)
__global__ __launch_bounds__(256)
void colmean_bb_k(const ushort_t* __restrict__ Y, ushort_t* __restrict__ O)
{
    __shared__ float ps[4][64];
    int b = blockIdx.x, dg = blockIdx.y;
    int wave = threadIdx.x >> 6, lane = threadIdx.x & 63;
    int d = dg * 64 + lane;
    long base = (long)b * 262144 + d;
    float s = 0.f;
    for (int t = wave * 128; t < wave * 128 + 128; ++t)
        s += b2f(Y[base + ((long)t << 9)]);
    ps[wave][lane] = s;
    __syncthreads();
    float mean = (ps[0][lane] + ps[1][lane] + ps[2][lane] + ps[3][lane]) * (1.f / 512.f);
    for (int t = wave * 128; t < wave * 128 + 128; ++t)
        O[base + ((long)t << 9)] = f2b(b2f(Y[base + ((long)t << 9)]) - mean);
}

// head transpose-add: out[b,p,t] += Thead[(b*512+t)*128+p] + b_head[p]
__global__ __launch_bounds__(256)
void headadd_k(const float* __restrict__ Th, const float* __restrict__ bh,
               float* __restrict__ out)
{
    const int id = blockIdx.x;          // b*16 + tc
    const int b = id >> 4, t0 = (id & 15) * 32;
    __shared__ float tile[32][100];
    for (int e = threadIdx.x; e < 32 * 96; e += 256) {
        int tl = e / 96, p = e - tl * 96;
        tile[tl][p] = Th[((long)(b * 512 + t0 + tl)) * 128 + p];
    }
    __syncthreads();
    for (int e = threadIdx.x; e < 96 * 32; e += 256) {
        int p = e >> 5, tl = e & 31;
        out[(long)b * 49152 + p * 512 + t0 + tl] += tile[tl][p] + bh[p];
    }
}

// ===========================================================================
extern "C" void kernel_launch(void* const* d_in, const int* in_sizes, int n_in,
                              void* d_out, int out_size, void* d_ws, size_t ws_size,
                              hipStream_t stream)
{
    const float* x_enc   = (const float*)d_in[0];
    const float* W_trend = (const float*)d_in[4];
    const float* b_trend = (const float*)d_in[5];
    const float* W_emb   = (const float*)d_in[6];
    const float* b_emb   = (const float*)d_in[7];
    const float* Wq      = (const float*)d_in[8];
    const float* bq      = (const float*)d_in[9];
    const float* fw_r    = (const float*)d_in[14];
    const float* fw_i    = (const float*)d_in[15];
    const float* Wo      = (const float*)d_in[16];
    const float* bo      = (const float*)d_in[17];
    const float* W1      = (const float*)d_in[18];
    const float* W2      = (const float*)d_in[19];
    const float* ln_g    = (const float*)d_in[20];
    const float* ln_b    = (const float*)d_in[21];
    const float* W_head  = (const float*)d_in[22];
    const float* b_head  = (const float*)d_in[23];
    float* out = (float*)d_out;
    float* ws  = (float*)d_ws;

    const long F = 8388608;
    float* G    = ws;
    ushort_t* xw  = (ushort_t*)(ws + 3 * F);           // encoder state bf16
    ushort_t* xs  = (ushort_t*)(ws + 4 * F);           // seasonal / FFN residual
    ushort_t* T1b = xs + 8388608;                      // FFN out / LN out
    ushort_t* qT  = (ushort_t*)(ws + 5 * F);           // seasT at start; xbT src later

    ushort_t* trendT = (ushort_t*)G;                   // [b][n][l] at start
    ushort_t* XFTb  = (ushort_t*)G;                    // [0,4MB)
    ushort_t* Yb    = (ushort_t*)(G + 1048576);        // [4,8MB)
    ushort_t* A2    = (ushort_t*)(G + 2097152);        // [8,12MB)
    ushort_t* OSELb = (ushort_t*)(G + 3145728);        // [12,16MB)
    ushort_t* xbT   = (ushort_t*)(G + 4194304);        // [16,32MB)
    ushort_t* B2    = (ushort_t*)(G + 8388608);        // [32,48MB)
    float*    Thead = G;
    ushort_t* gb    = (ushort_t*)G;                    // FFN-phase 64MB

    ushort_t* WembT  = (ushort_t*)(ws + 6 * F);        // 262144
    ushort_t* WTq2   = WembT + 262144;                 // 2 x 262144
    ushort_t* WTo2   = WTq2 + 524288;                  // 2 x 262144
    ushort_t* W1b2   = WTo2 + 524288;                  // 2 x 1048576
    ushort_t* W2b2   = W1b2 + 2097152;                 // 2 x 1048576
    ushort_t* TFb    = W2b2 + 2097152;                 // 65536
    ushort_t* TI2b   = TFb + 65536;                    // 65536
    ushort_t* WtT    = TI2b + 65536;                   // [128,512] rows<96 valid
    ushort_t* WheadT = WtT + 65536;                    // [128,512] rows<96 valid
    ushort_t* TIWob2 = WheadT + 65536;                 // 2 x 65536

    dim3 blk(256), blk5(512);

    init_tables_k<<<dim3(512), blk, 0, stream>>>(TFb, TI2b);

    // decomp(x_enc) -> TRANSPOSED seasonal (qT) + trend (G)
    decomp2t_k<<<dim3(2048), blk, 0, stream>>>(x_enc, qT, trendT);

    // hoisted weight prep (both layers batched)
    trans_b_k<<<dim3(3, 16, 1), blk, 0, stream>>>(W_trend, WtT, 512, 96, 0L, 0L);
    trans_b_k<<<dim3(3, 16, 1), blk, 0, stream>>>(W_head, WheadT, 512, 96, 0L, 0L);
    trans_b_k<<<dim3(16, 16, 1), blk, 0, stream>>>(W_emb, WembT, 512, 512, 0L, 0L);
    trans_b_k<<<dim3(16, 16, 2), blk, 0, stream>>>(Wq, WTq2, 512, 512, 262144L, 262144L);
    trans_b_k<<<dim3(16, 16, 2), blk, 0, stream>>>(Wo, WTo2, 512, 512, 262144L, 262144L);
    f2b_k<<<dim3(1024), blk, 0, stream>>>(W1, W1b2, 2097152L);
    f2b_k<<<dim3(1024), blk, 0, stream>>>(W2, W2b2, 2097152L);
    // TIWob2[l][d,mp] = sum_n WTo2[l][d,n] * TI2b[mp,n]
    sgemm_k<ME_BF16><<<dim3(2, 8, 2), blk, 0, stream>>>(
        WTo2, TI2b, nullptr, TIWob2,
        512, 128, 512, 128, 262144L, 0L, 65536L);

    // trend head GEMM -> out  (B = trendT in G)
    sgemm_k<ME_TREND><<<dim3(8, 2, 32), blk, 0, stream>>>(
        WtT, trendT, b_trend, out,
        128, 512, 512, 512, 0L, 262144L, 49152L);

    // embedding -> xw bf16  (B = seasT in qT)
    mgemm_k<ME_BIASCOL_BF16><<<dim3(4, 4, 32), blk5, 0, stream>>>(
        qT, WembT, b_emb, nullptr, xw,
        512, 512, 512, 512, 0, 262144L, 0L, 262144L, 0L);

    for (int l = 0; l < 2; ++l) {
        const float* bq_l = bq + (long)l * 512;
        const float* bo_l = bo + (long)l * 512;
        const float* fr_l = fw_r + (long)l * 2097152;
        const float* fi_l = fw_i + (long)l * 2097152;
        const ushort_t* WTq_l   = WTq2 + (long)l * 262144;
        const ushort_t* W1b_l   = W1b2 + (long)l * 1048576;
        const ushort_t* W2b_l   = W2b2 + (long)l * 1048576;
        const ushort_t* TIWob_l = TIWob2 + (long)l * 65536;

        bprep_k<<<dim3(512), blk, 0, stream>>>(fr_l, fi_l, B2);

        // xbT[b,d,n] = xw[b,n,d]^T
        trans_bb_k<<<dim3(16, 16, 32), blk, 0, stream>>>(xw, xbT, 512, 512, 262144L, 262144L);

        // G1: Yb[b,mp,d] = sum_n TFb[mp,n] * xbT[b,d,n]
        sgemm_k<ME_BF16><<<dim3(8, 2, 32), blk, 0, stream>>>(
            TFb, xbT, nullptr, Yb,
            128, 512, 512, 512, 0L, 262144L, 65536L);

        // G2: XFTb[b,c,mp] = sum_d WTq[c,d] * Yb[b,mp,d]  (+512*bq[c] at mp=0)
        sgemm_k<ME_DCBIAS_BF16><<<dim3(2, 8, 32), blk, 0, stream>>>(
            WTq_l, Yb, bq_l, XFTb,
            512, 128, 512, 128, 0L, 65536L, 65536L);

        aprep_k<<<dim3(256), blk, 0, stream>>>(XFTb, A2);
        fmix_k<<<dim3(512), blk, 0, stream>>>(A2, B2, OSELb);

        // xw += OSEL . TIWo^T + bo   (bf16 RMW)
        mgemm_k<ME_BIASCOL_ACCB16><<<dim3(4, 128, 1), blk5, 0, stream>>>(
            OSELb, TIWob_l, bo_l, nullptr, xw,
            16384, 512, 128, 512, 0, 0L, 0L, 0L, 0L);

        // decomp (bf16, vectorized) -> xs (FFN input + FFN2 residual)
        decomp2v_k<<<dim3(512), blk, 0, stream>>>(xw, xs);

        // FFN, full M=16384
        mgemm_k<ME_GELU_BF16><<<dim3(16, 128, 1), blk5, 0, stream>>>(
            xs, W1b_l, nullptr, nullptr, gb,
            16384, 2048, 512, 2048, 0, 0L, 0L, 0L, 0L);
        mgemm_k<ME_RESB_BF16><<<dim3(4, 128, 1), blk5, 0, stream>>>(
            gb, W2b_l, nullptr, xs, T1b,
            16384, 512, 2048, 512, 512, 0L, 0L, 0L, 0L);

        // decomp (bf16, vectorized) -> xw (next layer state / LN input)
        decomp2v_k<<<dim3(512), blk, 0, stream>>>(T1b, xw);
    }

    // my_layernorm (bf16): rows -> T1b, colmean-subtract -> xs
    ln_rows_bb_k<<<dim3(4096), blk, 0, stream>>>(xw, ln_g, ln_b, T1b);
    colmean_bb_k<<<dim3(32, 8), blk, 0, stream>>>(T1b, xs);

    // head
    sgemm_k<ME_F32><<<dim3(2, 256, 1), blk, 0, stream>>>(
        xs, WheadT, nullptr, Thead,
        16384, 128, 512, 128, 0L, 0L, 0L);

    headadd_k<<<dim3(512), blk, 0, stream>>>(Thead, b_head, out);
}